// Round 5
// baseline (3941.706 us; speedup 1.0000x reference)
//
#include <hip/hip_runtime.h>
#include <hip/hip_bf16.h>
#include <cstdint>
#include <cstddef>

// ============================================================================
// FastSpeech2 forward on MI355X. Round 5: fast fp32 encoder GEMM + mel GEMM.
//  - Encoder must stay fp32 (duration round-half-even gap ~2e-4 < bf16 error).
//  - gemm2_k: 128x128 tile, 8x8 micro, BK=16 (~2x FMA density vs gemm_k).
//  - Mel head: gemm_k into dead-ENC scratch + LDS-tiled transpose (was 210us
//    wave-dot).
//  - Decoder bf16 MFMA path unchanged from round 4 (passed, absmax at floor).
// ============================================================================

#define B_ 32
#define T_ 256
#define D_ 256
#define NH_ 4
#define FF_ 1024
#define MAXBUF_ 1024
#define NMEL_ 80

typedef __attribute__((ext_vector_type(8))) short short8;
typedef __attribute__((ext_vector_type(4))) float f32x4;

__device__ __forceinline__ unsigned short f2bf(float x) {
  unsigned int u = __float_as_uint(x);
  return (unsigned short)((u + 0x7fffu + ((u >> 16) & 1u)) >> 16);
}
__device__ __forceinline__ float bf2f(unsigned short h) {
  return __uint_as_float(((unsigned int)h) << 16);
}

#define GLD16(g, s)                                                         \
  __builtin_amdgcn_global_load_lds(                                         \
      (__attribute__((address_space(1))) void*)(g),                         \
      (__attribute__((address_space(3))) void*)(s), 16, 0, 0)

// ---------------------------------------------------------------------------
// fp32 GEMM, 64x64 tile (bounds-safe; used for mel N=80).
// ---------------------------------------------------------------------------
__global__ __launch_bounds__(256) void gemm_k(
    const float* __restrict__ A, const float* __restrict__ W,
    const float* __restrict__ bias, float* __restrict__ C,
    int M, int N, int K, int epi)
{
  __shared__ float As[16][64];
  __shared__ float Ws[16][64];
  const int tid = threadIdx.x;
  const int tx = tid & 15, ty = tid >> 4;
  const int bm = blockIdx.x * 64, bn = blockIdx.y * 64;
  const int lm = tid & 63, lk = tid >> 6;
  float acc[4][4] = {{0.f,0.f,0.f,0.f},{0.f,0.f,0.f,0.f},{0.f,0.f,0.f,0.f},{0.f,0.f,0.f,0.f}};
  const bool aok = (bm + lm) < M;
  const bool wok = (bn + lm) < N;
  const float* Ap = A + (size_t)(bm + lm) * K + lk * 4;
  const float* Wp = W + (size_t)(bn + lm) * K + lk * 4;
  for (int k0 = 0; k0 < K; k0 += 16) {
    float4 av = make_float4(0.f, 0.f, 0.f, 0.f);
    float4 wv = make_float4(0.f, 0.f, 0.f, 0.f);
    if (aok) av = *(const float4*)(Ap + k0);
    if (wok) wv = *(const float4*)(Wp + k0);
    As[lk*4+0][lm] = av.x; As[lk*4+1][lm] = av.y; As[lk*4+2][lm] = av.z; As[lk*4+3][lm] = av.w;
    Ws[lk*4+0][lm] = wv.x; Ws[lk*4+1][lm] = wv.y; Ws[lk*4+2][lm] = wv.z; Ws[lk*4+3][lm] = wv.w;
    __syncthreads();
#pragma unroll
    for (int kk = 0; kk < 16; ++kk) {
      float4 a4 = *(const float4*)&As[kk][ty * 4];
      float4 b4 = *(const float4*)&Ws[kk][tx * 4];
      float aa[4] = {a4.x, a4.y, a4.z, a4.w};
      float bb[4] = {b4.x, b4.y, b4.z, b4.w};
#pragma unroll
      for (int i = 0; i < 4; ++i)
#pragma unroll
        for (int j = 0; j < 4; ++j)
          acc[i][j] += aa[i] * bb[j];
    }
    __syncthreads();
  }
#pragma unroll
  for (int i = 0; i < 4; ++i) {
    int gm = bm + ty * 4 + i;
    if (gm >= M) continue;
#pragma unroll
    for (int j = 0; j < 4; ++j) {
      int gn = bn + tx * 4 + j;
      if (gn >= N) continue;
      float v = acc[i][j] + bias[gn];
      if (epi == 1) v = 0.5f * v * (1.0f + erff(v * 0.70710678118654752f));
      C[(size_t)gm * N + gn] = v;
    }
  }
}

// ---------------------------------------------------------------------------
// fp32 GEMM, 128x128 tile, 8x8 micro, BK=16. Requires M%128==0, N%128==0,
// K%16==0 (encoder shapes). k-major LDS: fragment reads contiguous b128;
// a-reads broadcast within wave.
// ---------------------------------------------------------------------------
__global__ __launch_bounds__(256) void gemm2_k(
    const float* __restrict__ A, const float* __restrict__ W,
    const float* __restrict__ bias, float* __restrict__ C,
    int M, int N, int K, int epi)
{
  __shared__ float As[16][128];
  __shared__ float Bs[16][128];
  const int tid = threadIdx.x;
  const int tx = tid & 15, ty = tid >> 4;
  const int bm = blockIdx.x * 128, bn = blockIdx.y * 128;
  const int r = tid & 127, ks = (tid >> 7) * 8;
  float acc[8][8];
#pragma unroll
  for (int i = 0; i < 8; ++i)
#pragma unroll
    for (int j = 0; j < 8; ++j) acc[i][j] = 0.f;
  const float* Ap = A + (size_t)(bm + r) * K + ks;
  const float* Wp = W + (size_t)(bn + r) * K + ks;
  for (int k0 = 0; k0 < K; k0 += 16) {
    float4 a0 = *(const float4*)(Ap + k0);
    float4 a1 = *(const float4*)(Ap + k0 + 4);
    float4 w0 = *(const float4*)(Wp + k0);
    float4 w1 = *(const float4*)(Wp + k0 + 4);
    __syncthreads();
    As[ks+0][r] = a0.x; As[ks+1][r] = a0.y; As[ks+2][r] = a0.z; As[ks+3][r] = a0.w;
    As[ks+4][r] = a1.x; As[ks+5][r] = a1.y; As[ks+6][r] = a1.z; As[ks+7][r] = a1.w;
    Bs[ks+0][r] = w0.x; Bs[ks+1][r] = w0.y; Bs[ks+2][r] = w0.z; Bs[ks+3][r] = w0.w;
    Bs[ks+4][r] = w1.x; Bs[ks+5][r] = w1.y; Bs[ks+6][r] = w1.z; Bs[ks+7][r] = w1.w;
    __syncthreads();
#pragma unroll 4
    for (int kk = 0; kk < 16; ++kk) {
      float4 a_0 = *(const float4*)&As[kk][ty * 8];
      float4 a_1 = *(const float4*)&As[kk][ty * 8 + 4];
      float4 b_0 = *(const float4*)&Bs[kk][tx * 8];
      float4 b_1 = *(const float4*)&Bs[kk][tx * 8 + 4];
      float av[8] = {a_0.x, a_0.y, a_0.z, a_0.w, a_1.x, a_1.y, a_1.z, a_1.w};
      float bv[8] = {b_0.x, b_0.y, b_0.z, b_0.w, b_1.x, b_1.y, b_1.z, b_1.w};
#pragma unroll
      for (int i = 0; i < 8; ++i)
#pragma unroll
        for (int j = 0; j < 8; ++j)
          acc[i][j] += av[i] * bv[j];
    }
  }
#pragma unroll
  for (int i = 0; i < 8; ++i) {
    int gm = bm + ty * 8 + i;
#pragma unroll
    for (int j = 0; j < 8; ++j) {
      int gn = bn + tx * 8 + j;
      float v = acc[i][j] + bias[gn];
      if (epi == 1) v = 0.5f * v * (1.0f + erff(v * 0.70710678118654752f));
      C[(size_t)gm * N + gn] = v;
    }
  }
}

// ---------------------------------------------------------------------------
// fp32 flash attention (encoder only) — unchanged.
// ---------------------------------------------------------------------------
__global__ __launch_bounds__(256) void attn_k(
    const float* __restrict__ Qp, int qStride,
    const float* __restrict__ Kp, int kStride,
    const float* __restrict__ Vp, int vStride,
    float* __restrict__ Op, int Tq, int Tkv,
    const int* __restrict__ lengths)
{
  const int b = blockIdx.z, h = blockIdx.y, qt = blockIdx.x;
  const int tid = threadIdx.x;
  const int tx = tid & 15, ty = tid >> 4;
  const int lr = tid & 63, lq = tid >> 6;

  __shared__ float Qs[64][64];
  __shared__ float KT[64][64];
  __shared__ float Sm[64][65];

  {
    const float* q = Qp + (size_t)(b * Tq + qt * 64 + lr) * qStride + h * 64 + lq * 16;
    float4 v0 = ((const float4*)q)[0];
    float4 v1 = ((const float4*)q)[1];
    float4 v2 = ((const float4*)q)[2];
    float4 v3 = ((const float4*)q)[3];
    *(float4*)&Qs[lr][lq*16 + 0]  = v0;
    *(float4*)&Qs[lr][lq*16 + 4]  = v1;
    *(float4*)&Qs[lr][lq*16 + 8]  = v2;
    *(float4*)&Qs[lr][lq*16 + 12] = v3;
  }

  float m_reg[4], l_reg[4], o[4][4];
#pragma unroll
  for (int i = 0; i < 4; ++i) {
    m_reg[i] = -INFINITY; l_reg[i] = 0.f;
#pragma unroll
    for (int j = 0; j < 4; ++j) o[i][j] = 0.f;
  }

  const int len_b = lengths ? lengths[b] : 0x7fffffff;
  const int nkt = Tkv >> 6;

  for (int kt = 0; kt < nkt; ++kt) {
    __syncthreads();
    {
      const float* kp = Kp + (size_t)(b * Tkv + kt * 64 + lr) * kStride + h * 64 + lq * 16;
      float4 v[4];
      v[0] = ((const float4*)kp)[0]; v[1] = ((const float4*)kp)[1];
      v[2] = ((const float4*)kp)[2]; v[3] = ((const float4*)kp)[3];
#pragma unroll
      for (int u = 0; u < 4; ++u) {
        KT[lq*16 + u*4 + 0][lr] = v[u].x;
        KT[lq*16 + u*4 + 1][lr] = v[u].y;
        KT[lq*16 + u*4 + 2][lr] = v[u].z;
        KT[lq*16 + u*4 + 3][lr] = v[u].w;
      }
    }
    __syncthreads();

    float s[4][4] = {{0.f,0.f,0.f,0.f},{0.f,0.f,0.f,0.f},{0.f,0.f,0.f,0.f},{0.f,0.f,0.f,0.f}};
#pragma unroll
    for (int d4 = 0; d4 < 16; ++d4) {
      float4 qv[4], kv[4];
#pragma unroll
      for (int i = 0; i < 4; ++i) qv[i] = *(const float4*)&Qs[ty*4 + i][d4*4];
#pragma unroll
      for (int dd = 0; dd < 4; ++dd) kv[dd] = *(const float4*)&KT[d4*4 + dd][tx*4];
#pragma unroll
      for (int i = 0; i < 4; ++i) {
        s[i][0] += qv[i].x*kv[0].x + qv[i].y*kv[1].x + qv[i].z*kv[2].x + qv[i].w*kv[3].x;
        s[i][1] += qv[i].x*kv[0].y + qv[i].y*kv[1].y + qv[i].z*kv[2].y + qv[i].w*kv[3].y;
        s[i][2] += qv[i].x*kv[0].z + qv[i].y*kv[1].z + qv[i].z*kv[2].z + qv[i].w*kv[3].z;
        s[i][3] += qv[i].x*kv[0].w + qv[i].y*kv[1].w + qv[i].z*kv[2].w + qv[i].w*kv[3].w;
      }
    }

    float alpha[4];
#pragma unroll
    for (int i = 0; i < 4; ++i) {
      float pm = -INFINITY;
#pragma unroll
      for (int j = 0; j < 4; ++j) {
        int kg = kt * 64 + tx * 4 + j;
        float v = s[i][j] * 0.125f;
        if (kg >= len_b) v = -1e9f;
        s[i][j] = v;
        pm = fmaxf(pm, v);
      }
#pragma unroll
      for (int off = 1; off < 16; off <<= 1) pm = fmaxf(pm, __shfl_xor(pm, off));
      float mn = fmaxf(m_reg[i], pm);
      alpha[i] = expf(m_reg[i] - mn);
      float ls = 0.f;
#pragma unroll
      for (int j = 0; j < 4; ++j) {
        float p = expf(s[i][j] - mn);
        Sm[ty*4 + i][tx*4 + j] = p;
        ls += p;
      }
#pragma unroll
      for (int off = 1; off < 16; off <<= 1) ls += __shfl_xor(ls, off);
      l_reg[i] = l_reg[i] * alpha[i] + ls;
      m_reg[i] = mn;
    }
    __syncthreads();

    {
      const float* vp = Vp + (size_t)(b * Tkv + kt * 64 + lr) * vStride + h * 64 + lq * 16;
      float4 v0 = ((const float4*)vp)[0];
      float4 v1 = ((const float4*)vp)[1];
      float4 v2 = ((const float4*)vp)[2];
      float4 v3 = ((const float4*)vp)[3];
      *(float4*)&KT[lr][lq*16 + 0]  = v0;
      *(float4*)&KT[lr][lq*16 + 4]  = v1;
      *(float4*)&KT[lr][lq*16 + 8]  = v2;
      *(float4*)&KT[lr][lq*16 + 12] = v3;
    }
    __syncthreads();

#pragma unroll
    for (int i = 0; i < 4; ++i) {
      o[i][0] *= alpha[i]; o[i][1] *= alpha[i]; o[i][2] *= alpha[i]; o[i][3] *= alpha[i];
    }
#pragma unroll 8
    for (int c = 0; c < 64; ++c) {
      float4 vv = *(const float4*)&KT[c][tx * 4];
#pragma unroll
      for (int i = 0; i < 4; ++i) {
        float p = Sm[ty*4 + i][c];
        o[i][0] += p * vv.x; o[i][1] += p * vv.y; o[i][2] += p * vv.z; o[i][3] += p * vv.w;
      }
    }
  }

#pragma unroll
  for (int i = 0; i < 4; ++i) {
    float inv = 1.f / l_reg[i];
    float4 r;
    r.x = o[i][0] * inv; r.y = o[i][1] * inv; r.z = o[i][2] * inv; r.w = o[i][3] * inv;
    *(float4*)(Op + (size_t)(b * Tq + qt * 64 + ty * 4 + i) * 256 + h * 64 + tx * 4) = r;
  }
}

// ---------------------------------------------------------------------------
// bf16 MFMA GEMM — unchanged from round 4.
// ---------------------------------------------------------------------------
__global__ __launch_bounds__(256) void gemm_bf_k(
    const unsigned short* __restrict__ A, const unsigned short* __restrict__ W,
    const float* __restrict__ bias, unsigned short* __restrict__ C,
    int M, int N, int K, int epi)
{
  __shared__ __align__(16) short As[128 * 32];
  __shared__ __align__(16) short Bs[128 * 32];
  const int tid = threadIdx.x;
  const int lane = tid & 63, w = tid >> 6;
  const int g = lane >> 4, li = lane & 15;
  const int wr = (w >> 1) * 64, wc = (w & 1) * 64;
  const int bm = blockIdx.x * 128, bn = blockIdx.y * 128;

  f32x4 acc[4][4];
#pragma unroll
  for (int m = 0; m < 4; ++m)
#pragma unroll
    for (int n = 0; n < 4; ++n)
      acc[m][n] = (f32x4){0.f, 0.f, 0.f, 0.f};

  const int srow = tid >> 2, scol = (tid & 3) * 8;
  const unsigned short* Ag = A + (size_t)(bm + srow) * K + scol;
  const unsigned short* Wg = W + (size_t)(bn + srow) * K + scol;

  for (int k0 = 0; k0 < K; k0 += 32) {
    __syncthreads();
    GLD16(Ag + k0, &As[tid * 8]);
    GLD16(Ag + k0 + (size_t)64 * K, &As[tid * 8 + 2048]);
    GLD16(Wg + k0, &Bs[tid * 8]);
    GLD16(Wg + k0 + (size_t)64 * K, &Bs[tid * 8 + 2048]);
    __syncthreads();
    short8 af[4], bf[4];
#pragma unroll
    for (int m = 0; m < 4; ++m) af[m] = *(const short8*)&As[(wr + m * 16 + li) * 32 + g * 8];
#pragma unroll
    for (int n = 0; n < 4; ++n) bf[n] = *(const short8*)&Bs[(wc + n * 16 + li) * 32 + g * 8];
#pragma unroll
    for (int m = 0; m < 4; ++m)
#pragma unroll
      for (int n = 0; n < 4; ++n)
        acc[m][n] = __builtin_amdgcn_mfma_f32_16x16x32_bf16(af[m], bf[n], acc[m][n], 0, 0, 0);
  }

#pragma unroll
  for (int m = 0; m < 4; ++m) {
#pragma unroll
    for (int n = 0; n < 4; ++n) {
      int col = bn + wc + n * 16 + li;
      float bv = bias[col];
#pragma unroll
      for (int r = 0; r < 4; ++r) {
        int row = bm + wr + m * 16 + g * 4 + r;
        float v = acc[m][n][r] + bv;
        if (epi == 1) v = 0.5f * v * (1.0f + erff(v * 0.70710678118654752f));
        C[(size_t)row * N + col] = f2bf(v);
      }
    }
  }
}

// ---------------------------------------------------------------------------
// bf16 MFMA flash attention — unchanged from round 4.
// ---------------------------------------------------------------------------
__global__ __launch_bounds__(256) void attn_bf_k(
    const unsigned short* __restrict__ Qp, int qStride,
    const unsigned short* __restrict__ Kp, int kStride,
    const unsigned short* __restrict__ Vp, int vStride,
    unsigned short* __restrict__ Op, int Tq, int Tkv)
{
  const int b = blockIdx.z, h = blockIdx.y, qt = blockIdx.x;
  const int tid = threadIdx.x;
  const int lane = tid & 63, w = tid >> 6;
  const int g = lane >> 4, li = lane & 15;

  __shared__ __align__(16) short Qs[64 * 64];
  __shared__ __align__(16) short Ks[64 * 64];
  __shared__ __align__(16) short VT[64 * 64];
  __shared__ __align__(16) short Ps[64 * 64];

  {
    const int r0 = tid >> 3, seg = tid & 7;
#pragma unroll
    for (int i = 0; i < 2; ++i) {
      int r = r0 + i * 32;
      short8 v = *(const short8*)(Qp + (size_t)(b * Tq + qt * 64 + r) * qStride + h * 64 + seg * 8);
      *(short8*)&Qs[r * 64 + ((seg ^ (r & 7)) << 3)] = v;
    }
  }
  __syncthreads();

  short8 aq[2];
#pragma unroll
  for (int ks = 0; ks < 2; ++ks) {
    int row = w * 16 + li;
    aq[ks] = *(const short8*)&Qs[row * 64 + (((ks * 4 + g) ^ (row & 7)) << 3)];
  }

  float m_reg[4], l_reg[4];
  f32x4 o[4];
#pragma unroll
  for (int r = 0; r < 4; ++r) { m_reg[r] = -INFINITY; l_reg[r] = 0.f; }
#pragma unroll
  for (int n = 0; n < 4; ++n) o[n] = (f32x4){0.f, 0.f, 0.f, 0.f};

  const int nkt = Tkv >> 6;
  for (int kt = 0; kt < nkt; ++kt) {
    __syncthreads();
    {
      const int r0 = tid >> 3, seg = tid & 7;
#pragma unroll
      for (int i = 0; i < 2; ++i) {
        int r = r0 + i * 32;
        short8 kv = *(const short8*)(Kp + (size_t)(b * Tkv + kt * 64 + r) * kStride + h * 64 + seg * 8);
        *(short8*)&Ks[r * 64 + ((seg ^ (r & 7)) << 3)] = kv;
        short8 vv = *(const short8*)(Vp + (size_t)(b * Tkv + kt * 64 + r) * vStride + h * 64 + seg * 8);
#pragma unroll
        for (int j = 0; j < 8; ++j) {
          int d = seg * 8 + j;
          VT[d * 64 + (r ^ ((d & 7) << 3))] = vv[j];
        }
      }
    }
    __syncthreads();

    f32x4 s[4];
#pragma unroll
    for (int n = 0; n < 4; ++n) {
      f32x4 acc = (f32x4){0.f, 0.f, 0.f, 0.f};
#pragma unroll
      for (int ks = 0; ks < 2; ++ks) {
        int key = n * 16 + li;
        short8 bk = *(const short8*)&Ks[key * 64 + (((ks * 4 + g) ^ (key & 7)) << 3)];
        acc = __builtin_amdgcn_mfma_f32_16x16x32_bf16(aq[ks], bk, acc, 0, 0, 0);
      }
      s[n] = acc * 0.125f;
    }

    float alpha[4];
#pragma unroll
    for (int r = 0; r < 4; ++r) {
      float pm = fmaxf(fmaxf(s[0][r], s[1][r]), fmaxf(s[2][r], s[3][r]));
#pragma unroll
      for (int off = 1; off < 16; off <<= 1) pm = fmaxf(pm, __shfl_xor(pm, off));
      float mn = fmaxf(m_reg[r], pm);
      alpha[r] = expf(m_reg[r] - mn);
      float ls = 0.f;
      int row = w * 16 + g * 4 + r;
#pragma unroll
      for (int n = 0; n < 4; ++n) {
        float p = expf(s[n][r] - mn);
        ls += p;
        int col = n * 16 + li;
        Ps[row * 64 + (col ^ ((row & 7) << 3))] = (short)f2bf(p);
      }
#pragma unroll
      for (int off = 1; off < 16; off <<= 1) ls += __shfl_xor(ls, off);
      l_reg[r] = l_reg[r] * alpha[r] + ls;
      m_reg[r] = mn;
    }

    f32x4 al = (f32x4){alpha[0], alpha[1], alpha[2], alpha[3]};
#pragma unroll
    for (int n = 0; n < 4; ++n) o[n] *= al;
    short8 ap[2];
#pragma unroll
    for (int ks = 0; ks < 2; ++ks) {
      int row = w * 16 + li;
      ap[ks] = *(const short8*)&Ps[row * 64 + (((ks * 4 + g) ^ (row & 7)) << 3)];
    }
#pragma unroll
    for (int n = 0; n < 4; ++n) {
#pragma unroll
      for (int ks = 0; ks < 2; ++ks) {
        int d = n * 16 + li;
        short8 bv = *(const short8*)&VT[d * 64 + (((ks * 4 + g) ^ (d & 7)) << 3)];
        o[n] = __builtin_amdgcn_mfma_f32_16x16x32_bf16(ap[ks], bv, o[n], 0, 0, 0);
      }
    }
  }

#pragma unroll
  for (int n = 0; n < 4; ++n) {
#pragma unroll
    for (int r = 0; r < 4; ++r) {
      float v = o[n][r] / l_reg[r];
      Op[(size_t)(b * Tq + qt * 64 + w * 16 + g * 4 + r) * 256 + h * 64 + n * 16 + li] = f2bf(v);
    }
  }
}

// LayerNorm f32 — unchanged.
__global__ __launch_bounds__(256) void addln_k(
    const float* __restrict__ X, const float* __restrict__ R,
    const float* __restrict__ w, const float* __restrict__ bias,
    float* __restrict__ Out, int rows)
{
  int tid = threadIdx.x, wv = tid >> 6, ln = tid & 63;
  int row = blockIdx.x * 4 + wv;
  if (row >= rows) return;
  const float* xp = X + (size_t)row * 256;
  float v[4];
#pragma unroll
  for (int u = 0; u < 4; ++u) v[u] = xp[u * 64 + ln];
  if (R) {
    const float* rp = R + (size_t)row * 256;
#pragma unroll
    for (int u = 0; u < 4; ++u) v[u] += rp[u * 64 + ln];
  }
  float s = v[0] + v[1] + v[2] + v[3];
#pragma unroll
  for (int off = 1; off < 64; off <<= 1) s += __shfl_xor(s, off);
  float mean = s * (1.f / 256.f);
  float c[4], sq = 0.f;
#pragma unroll
  for (int u = 0; u < 4; ++u) { c[u] = v[u] - mean; sq += c[u] * c[u]; }
#pragma unroll
  for (int off = 1; off < 64; off <<= 1) sq += __shfl_xor(sq, off);
  float rs = 1.f / sqrtf(sq * (1.f / 256.f) + 1e-5f);
  float* op = Out + (size_t)row * 256;
#pragma unroll
  for (int u = 0; u < 4; ++u)
    op[u * 64 + ln] = c[u] * rs * w[u * 64 + ln] + bias[u * 64 + ln];
}

// LayerNorm + bf16 residual; writes f32 state + bf16 mirror — unchanged.
__global__ __launch_bounds__(256) void addln2_k(
    const float* __restrict__ X, const unsigned short* __restrict__ Rbf,
    const float* __restrict__ w, const float* __restrict__ bias,
    float* __restrict__ Out, unsigned short* __restrict__ OutBf, int rows)
{
  int tid = threadIdx.x, wv = tid >> 6, ln = tid & 63;
  int row = blockIdx.x * 4 + wv;
  if (row >= rows) return;
  const float* xp = X + (size_t)row * 256;
  const unsigned short* rp = Rbf + (size_t)row * 256;
  float v[4];
#pragma unroll
  for (int u = 0; u < 4; ++u) v[u] = xp[u * 64 + ln] + bf2f(rp[u * 64 + ln]);
  float s = v[0] + v[1] + v[2] + v[3];
#pragma unroll
  for (int off = 1; off < 64; off <<= 1) s += __shfl_xor(s, off);
  float mean = s * (1.f / 256.f);
  float c[4], sq = 0.f;
#pragma unroll
  for (int u = 0; u < 4; ++u) { c[u] = v[u] - mean; sq += c[u] * c[u]; }
#pragma unroll
  for (int off = 1; off < 64; off <<= 1) sq += __shfl_xor(sq, off);
  float rs = 1.f / sqrtf(sq * (1.f / 256.f) + 1e-5f);
  float* op = Out + (size_t)row * 256;
  unsigned short* ob = OutBf + (size_t)row * 256;
#pragma unroll
  for (int u = 0; u < 4; ++u) {
    float y = c[u] * rs * w[u * 64 + ln] + bias[u * 64 + ln];
    op[u * 64 + ln] = y;
    ob[u * 64 + ln] = f2bf(y);
  }
}

__global__ void cvt_k(const float* __restrict__ in, unsigned short* __restrict__ out, int n)
{
  int i = (blockIdx.x * 256 + threadIdx.x) * 4;
  if (i >= n) return;
  float4 v = *(const float4*)(in + i);
  unsigned short o[4] = {f2bf(v.x), f2bf(v.y), f2bf(v.z), f2bf(v.w)};
  *(ushort4*)(out + i) = *(ushort4*)o;
}

// Conv1d k=3 pad=1 — unchanged.
__global__ __launch_bounds__(256) void conv_k(
    const float* __restrict__ X, const float* __restrict__ Wt,
    const float* __restrict__ bias, float* __restrict__ Yo, int relu)
{
  const int b = blockIdx.z;
  const int o0 = blockIdx.y * 64, t0 = blockIdx.x * 64;
  const int tid = threadIdx.x, tx = tid & 15, ty = tid >> 4;
  __shared__ float xs[16][66];
  __shared__ float ws_s[64][48];
  float acc[4][4] = {{0.f,0.f,0.f,0.f},{0.f,0.f,0.f,0.f},{0.f,0.f,0.f,0.f},{0.f,0.f,0.f,0.f}};
  for (int i0 = 0; i0 < 256; i0 += 16) {
    for (int idx = tid; idx < 16 * 66; idx += 256) {
      int ic = idx / 66, tt = idx - ic * 66;
      int t = t0 + tt - 1;
      xs[ic][tt] = (t >= 0 && t < 256) ? X[((size_t)b * 256 + (i0 + ic)) * 256 + t] : 0.f;
    }
    for (int f4 = tid; f4 < 768; f4 += 256) {
      int oo = f4 / 12, seg = f4 - oo * 12;
      float4 v = *(const float4*)(Wt + (size_t)(o0 + oo) * 768 + i0 * 3 + seg * 4);
      *(float4*)&ws_s[oo][seg * 4] = v;
    }
    __syncthreads();
#pragma unroll
    for (int ic = 0; ic < 16; ++ic) {
      float xr[6];
#pragma unroll
      for (int u = 0; u < 6; ++u) xr[u] = xs[ic][tx * 4 + u];
#pragma unroll
      for (int i = 0; i < 4; ++i) {
        const float* wr = &ws_s[ty * 4 + i][ic * 3];
        float w0 = wr[0], w1 = wr[1], w2 = wr[2];
#pragma unroll
        for (int j = 0; j < 4; ++j)
          acc[i][j] += w0 * xr[j] + w1 * xr[j + 1] + w2 * xr[j + 2];
      }
    }
    __syncthreads();
  }
#pragma unroll
  for (int i = 0; i < 4; ++i) {
    int oo = o0 + ty * 4 + i;
    float bv = bias[oo];
#pragma unroll
    for (int j = 0; j < 4; ++j) {
      float v = acc[i][j] + bv;
      if (relu) v = fmaxf(v, 0.f);
      Yo[((size_t)b * 256 + oo) * 256 + t0 + tx * 4 + j] = v;
    }
  }
}

__global__ void transp_k(const float* __restrict__ In, float* __restrict__ Out)
{
  int b = blockIdx.z, t0 = blockIdx.x * 32, d0 = blockIdx.y * 32;
  __shared__ float tile[32][33];
  int tx = threadIdx.x, ty = threadIdx.y;
#pragma unroll
  for (int q = 0; q < 4; ++q)
    tile[ty + q * 8][tx] = In[((size_t)b * 256 + t0 + ty + q * 8) * 256 + d0 + tx];
  __syncthreads();
#pragma unroll
  for (int q = 0; q < 4; ++q)
    Out[((size_t)b * 256 + d0 + ty + q * 8) * 256 + t0 + tx] = tile[tx][ty + q * 8];
}

__global__ __launch_bounds__(256) void rowdot_k(
    const float* __restrict__ H, const float* __restrict__ lw,
    const float* __restrict__ lb, float* __restrict__ of32,
    float* __restrict__ oout, int rows)
{
  int tid = threadIdx.x, wv = tid >> 6, ln = tid & 63;
  int row = blockIdx.x * 4 + wv;
  if (row >= rows) return;
  const float* hp = H + (size_t)row * 256;
  float s = 0.f;
#pragma unroll
  for (int u = 0; u < 4; ++u) s += hp[u * 64 + ln] * lw[u * 64 + ln];
#pragma unroll
  for (int off = 1; off < 64; off <<= 1) s += __shfl_xor(s, off);
  if (ln == 0) {
    float v = s + lb[0];
    of32[row] = v;
    oout[row] = v;
  }
}

__global__ void maxlen_k(const float* __restrict__ dur, int* __restrict__ ml)
{
  __shared__ float rnds[32];
  int tid = threadIdx.x, wv = tid >> 6, ln = tid & 63;
  for (int b = wv; b < 32; b += 4) {
    const float* dp = dur + (size_t)b * 256;
    float s = dp[ln] + dp[64 + ln] + dp[128 + ln] + dp[192 + ln];
#pragma unroll
    for (int off = 1; off < 64; off <<= 1) s += __shfl_xor(s, off);
    if (ln == 0) rnds[b] = rintf(s);
  }
  __syncthreads();
  if (tid == 0) {
    float m = rnds[0];
    for (int b = 1; b < 32; ++b) m = fmaxf(m, rnds[b]);
    int v = (int)m;
    v = v < 0 ? 0 : (v > MAXBUF_ ? MAXBUF_ : v);
    *ml = v;
  }
}

__global__ void reg_k(const float* __restrict__ dur, const int* __restrict__ lens,
                      const int* __restrict__ ml, int* __restrict__ tok)
{
  int b = blockIdx.x;
  __shared__ float sdur[256];
  __shared__ int ends[256];
  int tid = threadIdx.x;
  sdur[tid] = dur[(size_t)b * 256 + tid];
  __syncthreads();
  if (tid == 0) {
    int maxlen = *ml, len = lens[b], pos = 0;
    for (int t = 0; t < 256; ++t) {
      int d = (int)rintf(sdur[t]);
      bool ok = (t < len) && (d > 0) && (pos + d <= maxlen);
      if (ok) pos += d;
      ends[t] = pos;
    }
  }
  __syncthreads();
  int total = ends[255];
  for (int f = tid; f < MAXBUF_; f += 256) {
    int lo = 0, hi = 256;
    while (lo < hi) { int mid = (lo + hi) >> 1; if (ends[mid] <= f) lo = mid + 1; else hi = mid; }
    int tc = lo > 255 ? 255 : lo;
    tok[(size_t)b * MAXBUF_ + f] = (f < total) ? tc : -1;
  }
}

__global__ void gather_k(const float* __restrict__ enc, const int* __restrict__ tok,
                         float* __restrict__ Y)
{
  int rf = blockIdx.x;
  int b = rf >> 10;
  int t = tok[rf];
  float4* dst = (float4*)(Y + (size_t)rf * 256);
  int ln = threadIdx.x;
  if (t >= 0) {
    const float4* src = (const float4*)(enc + ((size_t)b * 256 + t) * 256);
    dst[ln] = src[ln];
  } else {
    dst[ln] = make_float4(0.f, 0.f, 0.f, 0.f);
  }
}

// MEL (B*1024, 80) -> out (B, 80, 1024) via LDS tile transpose
__global__ __launch_bounds__(256) void meltr_k(
    const float* __restrict__ MEL, float* __restrict__ out)
{
  int b = blockIdx.z, m0 = blockIdx.y * 16, f0 = blockIdx.x * 64;
  __shared__ float t[16][65];
  int tid = threadIdx.x;
  {
    int f_i = tid >> 4, m_i = tid & 15;
#pragma unroll
    for (int q = 0; q < 4; ++q)
      t[m_i][f_i + q * 16] = MEL[((size_t)b * 1024 + f0 + f_i + q * 16) * 80 + m0 + m_i];
  }
  __syncthreads();
  {
    int f = tid & 63, my = tid >> 6;
#pragma unroll
    for (int q = 0; q < 4; ++q) {
      int m = my * 4 + q;
      out[((size_t)b * NMEL_ + m0 + m) * MAXBUF_ + f0 + f] = t[m][f];
    }
  }
}

// ============================================================================
extern "C" void kernel_launch(void* const* d_in, const int* in_sizes, int n_in,
                              void* d_out, int out_size, void* d_ws, size_t ws_size,
                              hipStream_t stream)
{
  (void)in_sizes; (void)n_in; (void)out_size;

  const float* te   = (const float*)d_in[0];
  const int*   lens = (const int*)d_in[1];
  const float* e_qkv_w = (const float*)d_in[2];
  const float* e_qkv_b = (const float*)d_in[3];
  const float* e_out_w = (const float*)d_in[4];
  const float* e_out_b = (const float*)d_in[5];
  const float* e_ln1_w = (const float*)d_in[6];
  const float* e_ln1_b = (const float*)d_in[7];
  const float* e_ff1_w = (const float*)d_in[8];
  const float* e_ff1_b = (const float*)d_in[9];
  const float* e_ff2_w = (const float*)d_in[10];
  const float* e_ff2_b = (const float*)d_in[11];
  const float* e_ln2_w = (const float*)d_in[12];
  const float* e_ln2_b = (const float*)d_in[13];
  const float* c1w = (const float*)d_in[14];
  const float* c1b = (const float*)d_in[15];
  const float* l1w = (const float*)d_in[16];
  const float* l1b = (const float*)d_in[17];
  const float* c2w = (const float*)d_in[18];
  const float* c2b = (const float*)d_in[19];
  const float* l2w = (const float*)d_in[20];
  const float* l2b = (const float*)d_in[21];
  const float* linw = (const float*)d_in[22];
  const float* linb = (const float*)d_in[23];
  const float* d_sa_qkv_w = (const float*)d_in[24];
  const float* d_sa_qkv_b = (const float*)d_in[25];
  const float* d_sa_out_w = (const float*)d_in[26];
  const float* d_sa_out_b = (const float*)d_in[27];
  const float* d_ca_qkv_w = (const float*)d_in[28];
  const float* d_ca_qkv_b = (const float*)d_in[29];
  const float* d_ca_out_w = (const float*)d_in[30];
  const float* d_ca_out_b = (const float*)d_in[31];
  const float* d_ln1_w = (const float*)d_in[32];
  const float* d_ln1_b = (const float*)d_in[33];
  const float* d_ln2_w = (const float*)d_in[34];
  const float* d_ln2_b = (const float*)d_in[35];
  const float* d_ln3_w = (const float*)d_in[36];
  const float* d_ln3_b = (const float*)d_in[37];
  const float* d_ff1_w = (const float*)d_in[38];
  const float* d_ff1_b = (const float*)d_in[39];
  const float* d_ff2_w = (const float*)d_in[40];
  const float* d_ff2_b = (const float*)d_in[41];
  const float* melw = (const float*)d_in[42];
  const float* melb = (const float*)d_in[43];
  float* out = (float*)d_out;   // f32: mel | duration | pitch | energy

  // ---- arena ----
  char* p = (char*)d_ws;
  float* Y   = (float*)p;            p += 8388608ull * 4;    // (B,1024,256) f32
  float* ENC = (float*)p;            p += 2097152ull * 4;    // (B,256,256) f32
  unsigned short* ENCbf = (unsigned short*)p; p += 2097152ull * 2;
  unsigned short* Wsaqkv = (unsigned short*)p; p += 786432ull * 2;
  unsigned short* Wsaout = (unsigned short*)p; p += 262144ull * 2;
  unsigned short* Wcaqkv = (unsigned short*)p; p += 786432ull * 2;
  unsigned short* Wcaout = (unsigned short*)p; p += 262144ull * 2;
  unsigned short* Wff1   = (unsigned short*)p; p += 1048576ull * 2;
  unsigned short* Wff2   = (unsigned short*)p; p += 1048576ull * 2;
  float* DUR = (float*)p;            p += 24576ull * 4;
  int* TOK   = (int*)p;              p += 32768ull * 4;
  int* MAXL  = (int*)p;              p += 4096;
  size_t fixed_b = (size_t)(p - (char*)d_ws);

  int grp = 1;
  {
    const int cand[6] = {32, 16, 8, 4, 2, 1};
    for (int c = 0; c < 6; ++c) {
      if (fixed_b + (size_t)cand[c] * 1835008ull * 2 <= ws_size) { grp = cand[c]; break; }
    }
  }
  unsigned short* REG = (unsigned short*)p;            // grouped region (bf16)
  unsigned short* Ybf   = REG;
  unsigned short* ADDbf = REG + (size_t)grp * 262144;
  unsigned short* AObf  = REG + (size_t)grp * 524288;
  unsigned short* UN    = REG + (size_t)grp * 786432;
  int grp_e = grp * 2 > 32 ? 32 : grp * 2;
  float* P0e = (float*)REG;
  float* P1e = P0e + (size_t)grp_e * 262144;
  float* P2e = P1e + (size_t)grp_e * 65536;
  float* ENCT = Y;            // vpred scratch in dead Y region
  float* H1   = Y + 2097152;
  float* H2   = Y + 4194304;
  float* MEL  = ENC;          // (B*1024, 80) f32 — ENC+ENCbf dead at mel time

  auto gemm = [&](const float* A, const float* W, const float* bias, float* C,
                  int M, int N, int K, int epi) {
    dim3 g((M + 63) / 64, (N + 63) / 64);
    gemm_k<<<g, dim3(256), 0, stream>>>(A, W, bias, C, M, N, K, epi);
  };
  auto gemm2 = [&](const float* A, const float* W, const float* bias, float* C,
                   int M, int N, int K, int epi) {
    dim3 g(M / 128, N / 128);
    gemm2_k<<<g, dim3(256), 0, stream>>>(A, W, bias, C, M, N, K, epi);
  };
  auto gemm_bf = [&](const unsigned short* A, const unsigned short* W, const float* bias,
                     unsigned short* C, int M, int N, int K, int epi) {
    dim3 g(M / 128, N / 128);
    gemm_bf_k<<<g, dim3(256), 0, stream>>>(A, W, bias, C, M, N, K, epi);
  };
  auto addln = [&](const float* X, const float* R, const float* w, const float* b,
                   float* O, int rows) {
    addln_k<<<dim3((rows + 3) / 4), dim3(256), 0, stream>>>(X, R, w, b, O, rows);
  };
  auto addln2 = [&](const float* X, const unsigned short* Rbf, const float* w, const float* b,
                    float* O, unsigned short* Obf, int rows) {
    addln2_k<<<dim3((rows + 3) / 4), dim3(256), 0, stream>>>(X, Rbf, w, b, O, Obf, rows);
  };
  auto cvt = [&](const float* in, unsigned short* o, int n) {
    cvt_k<<<dim3(n / 1024), dim3(256), 0, stream>>>(in, o, n);
  };

  // ---- convert decoder weights to bf16 (once) ----
  cvt(d_sa_qkv_w, Wsaqkv, 786432);
  cvt(d_sa_out_w, Wsaout, 262144);
  cvt(d_ca_qkv_w, Wcaqkv, 786432);
  cvt(d_ca_out_w, Wcaout, 262144);
  cvt(d_ff1_w, Wff1, 1048576);
  cvt(d_ff2_w, Wff2, 1048576);

  // ================= encoder (fp32, gemm2) =================
  for (int i = 0; i < 4; ++i) {
    for (int g0 = 0; g0 < B_; g0 += grp_e) {
      int rows = grp_e * T_;
      const size_t off = (size_t)g0 * T_ * D_;
      const float* xin = (i == 0) ? te + off : ENC + off;
      gemm2(xin, e_qkv_w + (size_t)i * 196608, e_qkv_b + i * 768, P0e, rows, 768, 256, 0);
      attn_k<<<dim3(T_ / 64, NH_, grp_e), dim3(256), 0, stream>>>(
          P0e, 768, P0e + 256, 768, P0e + 512, 768, P1e, T_, T_, lens + g0);
      gemm2(P1e, e_out_w + (size_t)i * 65536, e_out_b + i * 256, P2e, rows, 256, 256, 0);
      addln(xin, P2e, e_ln1_w + i * 256, e_ln1_b + i * 256, ENC + off, rows);
      gemm2(ENC + off, e_ff1_w + (size_t)i * 262144, e_ff1_b + i * 1024, P0e, rows, 1024, 256, 1);
      gemm2(P0e, e_ff2_w + (size_t)i * 262144, e_ff2_b + i * 256, P2e, rows, 256, 1024, 0);
      addln(ENC + off, P2e, e_ln2_w + i * 256, e_ln2_b + i * 256, ENC + off, rows);
    }
  }
  cvt(ENC, ENCbf, 2097152);

  // ================= variance predictors (fp32) =================
  transp_k<<<dim3(8, 8, B_), dim3(32, 8), 0, stream>>>(ENC, ENCT);
  for (int j = 0; j < 3; ++j) {
    conv_k<<<dim3(4, 4, B_), dim3(256), 0, stream>>>(
        ENCT, c1w + (size_t)j * 196608, c1b + j * 256, H1, 1);
    addln(H1, nullptr, l1w + j * 256, l1b + j * 256, H1, B_ * T_);
    conv_k<<<dim3(4, 4, B_), dim3(256), 0, stream>>>(
        H1, c2w + (size_t)j * 196608, c2b + j * 256, H2, 1);
    addln(H2, nullptr, l2w + j * 256, l2b + j * 256, H2, B_ * T_);
    rowdot_k<<<dim3(B_ * T_ / 4), dim3(256), 0, stream>>>(
        H2, linw + j * 256, linb + j, DUR + (size_t)j * 8192,
        out + 2621440 + (size_t)j * 8192, B_ * T_);
  }

  // ================= length regulator =================
  maxlen_k<<<dim3(1), dim3(256), 0, stream>>>(DUR, MAXL);
  reg_k<<<dim3(B_), dim3(256), 0, stream>>>(DUR, lens, MAXL, TOK);
  gather_k<<<dim3(B_ * MAXBUF_), dim3(64), 0, stream>>>(ENC, TOK, Y);

  // ================= decoder (bf16 MFMA) =================
  for (int i = 0; i < 4; ++i) {
    for (int g0 = 0; g0 < B_; g0 += grp) {
      int rows = grp * MAXBUF_;
      float* Yg = Y + (size_t)g0 * MAXBUF_ * D_;
      cvt(Yg, Ybf, rows * 256);
      // self-attention
      gemm_bf(Ybf, Wsaqkv + (size_t)i * 196608, d_sa_qkv_b + i * 768, UN, rows, 768, 256, 0);
      attn_bf_k<<<dim3(MAXBUF_ / 64, NH_, grp), dim3(256), 0, stream>>>(
          UN, 768, UN + 256, 768, UN + 512, 768, AObf, MAXBUF_, MAXBUF_);
      gemm_bf(AObf, Wsaout + (size_t)i * 65536, d_sa_out_b + i * 256, ADDbf, rows, 256, 256, 0);
      addln2(Yg, ADDbf, d_ln1_w + i * 256, d_ln1_b + i * 256, Yg, Ybf, rows);
      // cross-attention
      gemm_bf(Ybf, Wcaqkv + (size_t)i * 196608, d_ca_qkv_b + i * 768, UN, rows, 256, 256, 0);
      gemm_bf(ENCbf + (size_t)g0 * 65536, Wcaqkv + (size_t)i * 196608 + 65536,
              d_ca_qkv_b + i * 768 + 256, UN + (size_t)grp * 262144, grp * T_, 512, 256, 0);
      attn_bf_k<<<dim3(MAXBUF_ / 64, NH_, grp), dim3(256), 0, stream>>>(
          UN, 256, UN + (size_t)grp * 262144, 512, UN + (size_t)grp * 262144 + 256, 512,
          AObf, MAXBUF_, T_);
      gemm_bf(AObf, Wcaout + (size_t)i * 65536, d_ca_out_b + i * 256, ADDbf, rows, 256, 256, 0);
      addln2(Yg, ADDbf, d_ln2_w + i * 256, d_ln2_b + i * 256, Yg, Ybf, rows);
      // feed-forward
      gemm_bf(Ybf, Wff1 + (size_t)i * 262144, d_ff1_b + i * 1024, UN, rows, 1024, 256, 1);
      gemm_bf(UN, Wff2 + (size_t)i * 262144, d_ff2_b + i * 256, ADDbf, rows, 256, 1024, 0);
      addln2(Yg, ADDbf, d_ln3_w + i * 256, d_ln3_b + i * 256, Yg, Ybf, rows);
    }
  }

  // ================= mel head: gemm + transpose =================
  gemm(Y, melw, melb, MEL, B_ * MAXBUF_, NMEL_, 256, 0);
  meltr_k<<<dim3(16, 5, B_), dim3(256), 0, stream>>>(MEL, out);
}

// Round 6
// 3891.586 us; speedup vs baseline: 1.0129x; 1.0129x over previous
//
#include <hip/hip_runtime.h>
#include <hip/hip_bf16.h>
#include <cstdint>
#include <cstddef>

// ============================================================================
// FastSpeech2 forward on MI355X. Round 6: LDS-conflict fixes + XCD swizzle.
//  - gemm2_k: split 8-wide fragments into 2x4-wide (tx*4, tx*4+64) -> LDS
//    reads 256B-contiguous across 16 lanes (r5's tx*8 left half the banks
//    idle; encoder regressed +400us).
//  - attn_bf_k: V-transpose staging re-indexed r=tid&63 (was 16-way bank
//    conflict: only 8 rows/wave and d&7 constant per step -> 4 banks).
//    + XCD-aware block remap (consecutive qt blocks share K/V; round-robin
//    XCD dispatch refetched per-XCD L2: FETCH 139MB vs 48MB unique).
//  - Encoder/vpred stay fp32 (duration round-half-even must match np ref).
// ============================================================================

#define B_ 32
#define T_ 256
#define D_ 256
#define NH_ 4
#define FF_ 1024
#define MAXBUF_ 1024
#define NMEL_ 80

typedef __attribute__((ext_vector_type(8))) short short8;
typedef __attribute__((ext_vector_type(4))) float f32x4;

__device__ __forceinline__ unsigned short f2bf(float x) {
  unsigned int u = __float_as_uint(x);
  return (unsigned short)((u + 0x7fffu + ((u >> 16) & 1u)) >> 16);
}
__device__ __forceinline__ float bf2f(unsigned short h) {
  return __uint_as_float(((unsigned int)h) << 16);
}

#define GLD16(g, s)                                                         \
  __builtin_amdgcn_global_load_lds(                                         \
      (__attribute__((address_space(1))) void*)(g),                         \
      (__attribute__((address_space(3))) void*)(s), 16, 0, 0)

// ---------------------------------------------------------------------------
// fp32 GEMM, 64x64 tile (bounds-safe; used for mel N=80).
// ---------------------------------------------------------------------------
__global__ __launch_bounds__(256) void gemm_k(
    const float* __restrict__ A, const float* __restrict__ W,
    const float* __restrict__ bias, float* __restrict__ C,
    int M, int N, int K, int epi)
{
  __shared__ float As[16][64];
  __shared__ float Ws[16][64];
  const int tid = threadIdx.x;
  const int tx = tid & 15, ty = tid >> 4;
  const int bm = blockIdx.x * 64, bn = blockIdx.y * 64;
  const int lm = tid & 63, lk = tid >> 6;
  float acc[4][4] = {{0.f,0.f,0.f,0.f},{0.f,0.f,0.f,0.f},{0.f,0.f,0.f,0.f},{0.f,0.f,0.f,0.f}};
  const bool aok = (bm + lm) < M;
  const bool wok = (bn + lm) < N;
  const float* Ap = A + (size_t)(bm + lm) * K + lk * 4;
  const float* Wp = W + (size_t)(bn + lm) * K + lk * 4;
  for (int k0 = 0; k0 < K; k0 += 16) {
    float4 av = make_float4(0.f, 0.f, 0.f, 0.f);
    float4 wv = make_float4(0.f, 0.f, 0.f, 0.f);
    if (aok) av = *(const float4*)(Ap + k0);
    if (wok) wv = *(const float4*)(Wp + k0);
    As[lk*4+0][lm] = av.x; As[lk*4+1][lm] = av.y; As[lk*4+2][lm] = av.z; As[lk*4+3][lm] = av.w;
    Ws[lk*4+0][lm] = wv.x; Ws[lk*4+1][lm] = wv.y; Ws[lk*4+2][lm] = wv.z; Ws[lk*4+3][lm] = wv.w;
    __syncthreads();
#pragma unroll
    for (int kk = 0; kk < 16; ++kk) {
      float4 a4 = *(const float4*)&As[kk][ty * 4];
      float4 b4 = *(const float4*)&Ws[kk][tx * 4];
      float aa[4] = {a4.x, a4.y, a4.z, a4.w};
      float bb[4] = {b4.x, b4.y, b4.z, b4.w};
#pragma unroll
      for (int i = 0; i < 4; ++i)
#pragma unroll
        for (int j = 0; j < 4; ++j)
          acc[i][j] += aa[i] * bb[j];
    }
    __syncthreads();
  }
#pragma unroll
  for (int i = 0; i < 4; ++i) {
    int gm = bm + ty * 4 + i;
    if (gm >= M) continue;
#pragma unroll
    for (int j = 0; j < 4; ++j) {
      int gn = bn + tx * 4 + j;
      if (gn >= N) continue;
      float v = acc[i][j] + bias[gn];
      if (epi == 1) v = 0.5f * v * (1.0f + erff(v * 0.70710678118654752f));
      C[(size_t)gm * N + gn] = v;
    }
  }
}

// ---------------------------------------------------------------------------
// fp32 GEMM, 128x128 tile, 8x8 micro via 2x(4-wide) split fragments.
// Requires M%128==0, N%128==0, K%16==0.  Fragment reads: 16 lanes at 16B
// stride -> 256B contiguous, conflict-free (fix of r5's half-banks-idle).
// ---------------------------------------------------------------------------
__global__ __launch_bounds__(256) void gemm2_k(
    const float* __restrict__ A, const float* __restrict__ W,
    const float* __restrict__ bias, float* __restrict__ C,
    int M, int N, int K, int epi)
{
  __shared__ float As[16][128];
  __shared__ float Bs[16][128];
  const int tid = threadIdx.x;
  const int tx = tid & 15, ty = tid >> 4;
  const int bm = blockIdx.x * 128, bn = blockIdx.y * 128;
  const int r = tid & 127, ks = (tid >> 7) * 8;
  float acc[8][8];
#pragma unroll
  for (int i = 0; i < 8; ++i)
#pragma unroll
    for (int j = 0; j < 8; ++j) acc[i][j] = 0.f;
  const float* Ap = A + (size_t)(bm + r) * K + ks;
  const float* Wp = W + (size_t)(bn + r) * K + ks;
  for (int k0 = 0; k0 < K; k0 += 16) {
    float4 a0 = *(const float4*)(Ap + k0);
    float4 a1 = *(const float4*)(Ap + k0 + 4);
    float4 w0 = *(const float4*)(Wp + k0);
    float4 w1 = *(const float4*)(Wp + k0 + 4);
    __syncthreads();
    As[ks+0][r] = a0.x; As[ks+1][r] = a0.y; As[ks+2][r] = a0.z; As[ks+3][r] = a0.w;
    As[ks+4][r] = a1.x; As[ks+5][r] = a1.y; As[ks+6][r] = a1.z; As[ks+7][r] = a1.w;
    Bs[ks+0][r] = w0.x; Bs[ks+1][r] = w0.y; Bs[ks+2][r] = w0.z; Bs[ks+3][r] = w0.w;
    Bs[ks+4][r] = w1.x; Bs[ks+5][r] = w1.y; Bs[ks+6][r] = w1.z; Bs[ks+7][r] = w1.w;
    __syncthreads();
#pragma unroll 4
    for (int kk = 0; kk < 16; ++kk) {
      float4 aA = *(const float4*)&As[kk][ty * 4];
      float4 aB = *(const float4*)&As[kk][ty * 4 + 64];
      float4 bA = *(const float4*)&Bs[kk][tx * 4];
      float4 bB = *(const float4*)&Bs[kk][tx * 4 + 64];
      float av[8] = {aA.x, aA.y, aA.z, aA.w, aB.x, aB.y, aB.z, aB.w};
      float bv[8] = {bA.x, bA.y, bA.z, bA.w, bB.x, bB.y, bB.z, bB.w};
#pragma unroll
      for (int i = 0; i < 8; ++i)
#pragma unroll
        for (int j = 0; j < 8; ++j)
          acc[i][j] += av[i] * bv[j];
    }
  }
#pragma unroll
  for (int i = 0; i < 8; ++i) {
    int gm = bm + (i >> 2) * 64 + ty * 4 + (i & 3);
#pragma unroll
    for (int j = 0; j < 8; ++j) {
      int gn = bn + (j >> 2) * 64 + tx * 4 + (j & 3);
      float v = acc[i][j] + bias[gn];
      if (epi == 1) v = 0.5f * v * (1.0f + erff(v * 0.70710678118654752f));
      C[(size_t)gm * N + gn] = v;
    }
  }
}

// ---------------------------------------------------------------------------
// fp32 flash attention (encoder only) — unchanged.
// ---------------------------------------------------------------------------
__global__ __launch_bounds__(256) void attn_k(
    const float* __restrict__ Qp, int qStride,
    const float* __restrict__ Kp, int kStride,
    const float* __restrict__ Vp, int vStride,
    float* __restrict__ Op, int Tq, int Tkv,
    const int* __restrict__ lengths)
{
  const int b = blockIdx.z, h = blockIdx.y, qt = blockIdx.x;
  const int tid = threadIdx.x;
  const int tx = tid & 15, ty = tid >> 4;
  const int lr = tid & 63, lq = tid >> 6;

  __shared__ float Qs[64][64];
  __shared__ float KT[64][64];
  __shared__ float Sm[64][65];

  {
    const float* q = Qp + (size_t)(b * Tq + qt * 64 + lr) * qStride + h * 64 + lq * 16;
    float4 v0 = ((const float4*)q)[0];
    float4 v1 = ((const float4*)q)[1];
    float4 v2 = ((const float4*)q)[2];
    float4 v3 = ((const float4*)q)[3];
    *(float4*)&Qs[lr][lq*16 + 0]  = v0;
    *(float4*)&Qs[lr][lq*16 + 4]  = v1;
    *(float4*)&Qs[lr][lq*16 + 8]  = v2;
    *(float4*)&Qs[lr][lq*16 + 12] = v3;
  }

  float m_reg[4], l_reg[4], o[4][4];
#pragma unroll
  for (int i = 0; i < 4; ++i) {
    m_reg[i] = -INFINITY; l_reg[i] = 0.f;
#pragma unroll
    for (int j = 0; j < 4; ++j) o[i][j] = 0.f;
  }

  const int len_b = lengths ? lengths[b] : 0x7fffffff;
  const int nkt = Tkv >> 6;

  for (int kt = 0; kt < nkt; ++kt) {
    __syncthreads();
    {
      const float* kp = Kp + (size_t)(b * Tkv + kt * 64 + lr) * kStride + h * 64 + lq * 16;
      float4 v[4];
      v[0] = ((const float4*)kp)[0]; v[1] = ((const float4*)kp)[1];
      v[2] = ((const float4*)kp)[2]; v[3] = ((const float4*)kp)[3];
#pragma unroll
      for (int u = 0; u < 4; ++u) {
        KT[lq*16 + u*4 + 0][lr] = v[u].x;
        KT[lq*16 + u*4 + 1][lr] = v[u].y;
        KT[lq*16 + u*4 + 2][lr] = v[u].z;
        KT[lq*16 + u*4 + 3][lr] = v[u].w;
      }
    }
    __syncthreads();

    float s[4][4] = {{0.f,0.f,0.f,0.f},{0.f,0.f,0.f,0.f},{0.f,0.f,0.f,0.f},{0.f,0.f,0.f,0.f}};
#pragma unroll
    for (int d4 = 0; d4 < 16; ++d4) {
      float4 qv[4], kv[4];
#pragma unroll
      for (int i = 0; i < 4; ++i) qv[i] = *(const float4*)&Qs[ty*4 + i][d4*4];
#pragma unroll
      for (int dd = 0; dd < 4; ++dd) kv[dd] = *(const float4*)&KT[d4*4 + dd][tx*4];
#pragma unroll
      for (int i = 0; i < 4; ++i) {
        s[i][0] += qv[i].x*kv[0].x + qv[i].y*kv[1].x + qv[i].z*kv[2].x + qv[i].w*kv[3].x;
        s[i][1] += qv[i].x*kv[0].y + qv[i].y*kv[1].y + qv[i].z*kv[2].y + qv[i].w*kv[3].y;
        s[i][2] += qv[i].x*kv[0].z + qv[i].y*kv[1].z + qv[i].z*kv[2].z + qv[i].w*kv[3].z;
        s[i][3] += qv[i].x*kv[0].w + qv[i].y*kv[1].w + qv[i].z*kv[2].w + qv[i].w*kv[3].w;
      }
    }

    float alpha[4];
#pragma unroll
    for (int i = 0; i < 4; ++i) {
      float pm = -INFINITY;
#pragma unroll
      for (int j = 0; j < 4; ++j) {
        int kg = kt * 64 + tx * 4 + j;
        float v = s[i][j] * 0.125f;
        if (kg >= len_b) v = -1e9f;
        s[i][j] = v;
        pm = fmaxf(pm, v);
      }
#pragma unroll
      for (int off = 1; off < 16; off <<= 1) pm = fmaxf(pm, __shfl_xor(pm, off));
      float mn = fmaxf(m_reg[i], pm);
      alpha[i] = expf(m_reg[i] - mn);
      float ls = 0.f;
#pragma unroll
      for (int j = 0; j < 4; ++j) {
        float p = expf(s[i][j] - mn);
        Sm[ty*4 + i][tx*4 + j] = p;
        ls += p;
      }
#pragma unroll
      for (int off = 1; off < 16; off <<= 1) ls += __shfl_xor(ls, off);
      l_reg[i] = l_reg[i] * alpha[i] + ls;
      m_reg[i] = mn;
    }
    __syncthreads();

    {
      const float* vp = Vp + (size_t)(b * Tkv + kt * 64 + lr) * vStride + h * 64 + lq * 16;
      float4 v0 = ((const float4*)vp)[0];
      float4 v1 = ((const float4*)vp)[1];
      float4 v2 = ((const float4*)vp)[2];
      float4 v3 = ((const float4*)vp)[3];
      *(float4*)&KT[lr][lq*16 + 0]  = v0;
      *(float4*)&KT[lr][lq*16 + 4]  = v1;
      *(float4*)&KT[lr][lq*16 + 8]  = v2;
      *(float4*)&KT[lr][lq*16 + 12] = v3;
    }
    __syncthreads();

#pragma unroll
    for (int i = 0; i < 4; ++i) {
      o[i][0] *= alpha[i]; o[i][1] *= alpha[i]; o[i][2] *= alpha[i]; o[i][3] *= alpha[i];
    }
#pragma unroll 8
    for (int c = 0; c < 64; ++c) {
      float4 vv = *(const float4*)&KT[c][tx * 4];
#pragma unroll
      for (int i = 0; i < 4; ++i) {
        float p = Sm[ty*4 + i][c];
        o[i][0] += p * vv.x; o[i][1] += p * vv.y; o[i][2] += p * vv.z; o[i][3] += p * vv.w;
      }
    }
  }

#pragma unroll
  for (int i = 0; i < 4; ++i) {
    float inv = 1.f / l_reg[i];
    float4 r;
    r.x = o[i][0] * inv; r.y = o[i][1] * inv; r.z = o[i][2] * inv; r.w = o[i][3] * inv;
    *(float4*)(Op + (size_t)(b * Tq + qt * 64 + ty * 4 + i) * 256 + h * 64 + tx * 4) = r;
  }
}

// ---------------------------------------------------------------------------
// bf16 MFMA GEMM — unchanged from round 4.
// ---------------------------------------------------------------------------
__global__ __launch_bounds__(256) void gemm_bf_k(
    const unsigned short* __restrict__ A, const unsigned short* __restrict__ W,
    const float* __restrict__ bias, unsigned short* __restrict__ C,
    int M, int N, int K, int epi)
{
  __shared__ __align__(16) short As[128 * 32];
  __shared__ __align__(16) short Bs[128 * 32];
  const int tid = threadIdx.x;
  const int lane = tid & 63, w = tid >> 6;
  const int g = lane >> 4, li = lane & 15;
  const int wr = (w >> 1) * 64, wc = (w & 1) * 64;
  const int bm = blockIdx.x * 128, bn = blockIdx.y * 128;

  f32x4 acc[4][4];
#pragma unroll
  for (int m = 0; m < 4; ++m)
#pragma unroll
    for (int n = 0; n < 4; ++n)
      acc[m][n] = (f32x4){0.f, 0.f, 0.f, 0.f};

  const int srow = tid >> 2, scol = (tid & 3) * 8;
  const unsigned short* Ag = A + (size_t)(bm + srow) * K + scol;
  const unsigned short* Wg = W + (size_t)(bn + srow) * K + scol;

  for (int k0 = 0; k0 < K; k0 += 32) {
    __syncthreads();
    GLD16(Ag + k0, &As[tid * 8]);
    GLD16(Ag + k0 + (size_t)64 * K, &As[tid * 8 + 2048]);
    GLD16(Wg + k0, &Bs[tid * 8]);
    GLD16(Wg + k0 + (size_t)64 * K, &Bs[tid * 8 + 2048]);
    __syncthreads();
    short8 af[4], bf[4];
#pragma unroll
    for (int m = 0; m < 4; ++m) af[m] = *(const short8*)&As[(wr + m * 16 + li) * 32 + g * 8];
#pragma unroll
    for (int n = 0; n < 4; ++n) bf[n] = *(const short8*)&Bs[(wc + n * 16 + li) * 32 + g * 8];
#pragma unroll
    for (int m = 0; m < 4; ++m)
#pragma unroll
      for (int n = 0; n < 4; ++n)
        acc[m][n] = __builtin_amdgcn_mfma_f32_16x16x32_bf16(af[m], bf[n], acc[m][n], 0, 0, 0);
  }

#pragma unroll
  for (int m = 0; m < 4; ++m) {
#pragma unroll
    for (int n = 0; n < 4; ++n) {
      int col = bn + wc + n * 16 + li;
      float bv = bias[col];
#pragma unroll
      for (int r = 0; r < 4; ++r) {
        int row = bm + wr + m * 16 + g * 4 + r;
        float v = acc[m][n][r] + bv;
        if (epi == 1) v = 0.5f * v * (1.0f + erff(v * 0.70710678118654752f));
        C[(size_t)row * N + col] = f2bf(v);
      }
    }
  }
}

// ---------------------------------------------------------------------------
// bf16 MFMA flash attention. V staging conflict-fixed (r = lane), XCD-aware
// block remap so blocks sharing (b,h) K/V land on one XCD's L2.
// ---------------------------------------------------------------------------
__global__ __launch_bounds__(256) void attn_bf_k(
    const unsigned short* __restrict__ Qp, int qStride,
    const unsigned short* __restrict__ Kp, int kStride,
    const unsigned short* __restrict__ Vp, int vStride,
    unsigned short* __restrict__ Op, int Tq, int Tkv)
{
  int b, h, qt;
  {
    const int nqt = gridDim.x, nh = gridDim.y, nbh = gridDim.y * gridDim.z;
    if ((nbh & 7) == 0) {
      int linear = blockIdx.x + nqt * (blockIdx.y + gridDim.y * blockIdx.z);
      int xcd = linear & 7, idx = linear >> 3;
      int bh = xcd * (nbh >> 3) + idx / nqt;
      qt = idx - (idx / nqt) * nqt;
      h = bh % nh; b = bh / nh;
    } else { qt = blockIdx.x; h = blockIdx.y; b = blockIdx.z; }
  }
  const int tid = threadIdx.x;
  const int lane = tid & 63, w = tid >> 6;
  const int g = lane >> 4, li = lane & 15;

  __shared__ __align__(16) short Qs[64 * 64];
  __shared__ __align__(16) short Ks[64 * 64];
  __shared__ __align__(16) short VT[64 * 64];
  __shared__ __align__(16) short Ps[64 * 64];

  {
    const int r0 = tid >> 3, seg = tid & 7;
#pragma unroll
    for (int i = 0; i < 2; ++i) {
      int r = r0 + i * 32;
      short8 v = *(const short8*)(Qp + (size_t)(b * Tq + qt * 64 + r) * qStride + h * 64 + seg * 8);
      *(short8*)&Qs[r * 64 + ((seg ^ (r & 7)) << 3)] = v;
    }
  }
  __syncthreads();

  short8 aq[2];
#pragma unroll
  for (int ks = 0; ks < 2; ++ks) {
    int row = w * 16 + li;
    aq[ks] = *(const short8*)&Qs[row * 64 + (((ks * 4 + g) ^ (row & 7)) << 3)];
  }

  float m_reg[4], l_reg[4];
  f32x4 o[4];
#pragma unroll
  for (int r = 0; r < 4; ++r) { m_reg[r] = -INFINITY; l_reg[r] = 0.f; }
#pragma unroll
  for (int n = 0; n < 4; ++n) o[n] = (f32x4){0.f, 0.f, 0.f, 0.f};

  const int nkt = Tkv >> 6;
  for (int kt = 0; kt < nkt; ++kt) {
    __syncthreads();
    { // K: coalesced rows (r0=tid>>3); stores ~min-cycle
      const int r0 = tid >> 3, seg = tid & 7;
#pragma unroll
      for (int i = 0; i < 2; ++i) {
        int r = r0 + i * 32;
        short8 kv = *(const short8*)(Kp + (size_t)(b * Tkv + kt * 64 + r) * kStride + h * 64 + seg * 8);
        *(short8*)&Ks[r * 64 + ((seg ^ (r & 7)) << 3)] = kv;
      }
    }
    { // V transpose: r = lane (64 distinct rows/wave) -> VT stores 2-way max
      const int rv = tid & 63, wv_ = tid >> 6;
#pragma unroll
      for (int i = 0; i < 2; ++i) {
        int seg = wv_ * 2 + i;
        short8 vv = *(const short8*)(Vp + (size_t)(b * Tkv + kt * 64 + rv) * vStride + h * 64 + seg * 8);
#pragma unroll
        for (int j = 0; j < 8; ++j) {
          int d = seg * 8 + j;
          VT[d * 64 + (rv ^ ((d & 7) << 3))] = vv[j];
        }
      }
    }
    __syncthreads();

    f32x4 s[4];
#pragma unroll
    for (int n = 0; n < 4; ++n) {
      f32x4 acc = (f32x4){0.f, 0.f, 0.f, 0.f};
#pragma unroll
      for (int ks = 0; ks < 2; ++ks) {
        int key = n * 16 + li;
        short8 bk = *(const short8*)&Ks[key * 64 + (((ks * 4 + g) ^ (key & 7)) << 3)];
        acc = __builtin_amdgcn_mfma_f32_16x16x32_bf16(aq[ks], bk, acc, 0, 0, 0);
      }
      s[n] = acc * 0.125f;
    }

    float alpha[4];
#pragma unroll
    for (int r = 0; r < 4; ++r) {
      float pm = fmaxf(fmaxf(s[0][r], s[1][r]), fmaxf(s[2][r], s[3][r]));
#pragma unroll
      for (int off = 1; off < 16; off <<= 1) pm = fmaxf(pm, __shfl_xor(pm, off));
      float mn = fmaxf(m_reg[r], pm);
      alpha[r] = expf(m_reg[r] - mn);
      float ls = 0.f;
      int row = w * 16 + g * 4 + r;
#pragma unroll
      for (int n = 0; n < 4; ++n) {
        float p = expf(s[n][r] - mn);
        ls += p;
        int col = n * 16 + li;
        Ps[row * 64 + (col ^ ((row & 7) << 3))] = (short)f2bf(p);
      }
#pragma unroll
      for (int off = 1; off < 16; off <<= 1) ls += __shfl_xor(ls, off);
      l_reg[r] = l_reg[r] * alpha[r] + ls;
      m_reg[r] = mn;
    }

    f32x4 al = (f32x4){alpha[0], alpha[1], alpha[2], alpha[3]};
#pragma unroll
    for (int n = 0; n < 4; ++n) o[n] *= al;
    short8 ap[2];
#pragma unroll
    for (int ks = 0; ks < 2; ++ks) {
      int row = w * 16 + li;
      ap[ks] = *(const short8*)&Ps[row * 64 + (((ks * 4 + g) ^ (row & 7)) << 3)];
    }
#pragma unroll
    for (int n = 0; n < 4; ++n) {
#pragma unroll
      for (int ks = 0; ks < 2; ++ks) {
        int d = n * 16 + li;
        short8 bv = *(const short8*)&VT[d * 64 + (((ks * 4 + g) ^ (d & 7)) << 3)];
        o[n] = __builtin_amdgcn_mfma_f32_16x16x32_bf16(ap[ks], bv, o[n], 0, 0, 0);
      }
    }
  }

#pragma unroll
  for (int n = 0; n < 4; ++n) {
#pragma unroll
    for (int r = 0; r < 4; ++r) {
      float v = o[n][r] / l_reg[r];
      Op[(size_t)(b * Tq + qt * 64 + w * 16 + g * 4 + r) * 256 + h * 64 + n * 16 + li] = f2bf(v);
    }
  }
}

// LayerNorm f32 — unchanged.
__global__ __launch_bounds__(256) void addln_k(
    const float* __restrict__ X, const float* __restrict__ R,
    const float* __restrict__ w, const float* __restrict__ bias,
    float* __restrict__ Out, int rows)
{
  int tid = threadIdx.x, wv = tid >> 6, ln = tid & 63;
  int row = blockIdx.x * 4 + wv;
  if (row >= rows) return;
  const float* xp = X + (size_t)row * 256;
  float v[4];
#pragma unroll
  for (int u = 0; u < 4; ++u) v[u] = xp[u * 64 + ln];
  if (R) {
    const float* rp = R + (size_t)row * 256;
#pragma unroll
    for (int u = 0; u < 4; ++u) v[u] += rp[u * 64 + ln];
  }
  float s = v[0] + v[1] + v[2] + v[3];
#pragma unroll
  for (int off = 1; off < 64; off <<= 1) s += __shfl_xor(s, off);
  float mean = s * (1.f / 256.f);
  float c[4], sq = 0.f;
#pragma unroll
  for (int u = 0; u < 4; ++u) { c[u] = v[u] - mean; sq += c[u] * c[u]; }
#pragma unroll
  for (int off = 1; off < 64; off <<= 1) sq += __shfl_xor(sq, off);
  float rs = 1.f / sqrtf(sq * (1.f / 256.f) + 1e-5f);
  float* op = Out + (size_t)row * 256;
#pragma unroll
  for (int u = 0; u < 4; ++u)
    op[u * 64 + ln] = c[u] * rs * w[u * 64 + ln] + bias[u * 64 + ln];
}

// LayerNorm + bf16 residual; writes f32 state + bf16 mirror — unchanged.
__global__ __launch_bounds__(256) void addln2_k(
    const float* __restrict__ X, const unsigned short* __restrict__ Rbf,
    const float* __restrict__ w, const float* __restrict__ bias,
    float* __restrict__ Out, unsigned short* __restrict__ OutBf, int rows)
{
  int tid = threadIdx.x, wv = tid >> 6, ln = tid & 63;
  int row = blockIdx.x * 4 + wv;
  if (row >= rows) return;
  const float* xp = X + (size_t)row * 256;
  const unsigned short* rp = Rbf + (size_t)row * 256;
  float v[4];
#pragma unroll
  for (int u = 0; u < 4; ++u) v[u] = xp[u * 64 + ln] + bf2f(rp[u * 64 + ln]);
  float s = v[0] + v[1] + v[2] + v[3];
#pragma unroll
  for (int off = 1; off < 64; off <<= 1) s += __shfl_xor(s, off);
  float mean = s * (1.f / 256.f);
  float c[4], sq = 0.f;
#pragma unroll
  for (int u = 0; u < 4; ++u) { c[u] = v[u] - mean; sq += c[u] * c[u]; }
#pragma unroll
  for (int off = 1; off < 64; off <<= 1) sq += __shfl_xor(sq, off);
  float rs = 1.f / sqrtf(sq * (1.f / 256.f) + 1e-5f);
  float* op = Out + (size_t)row * 256;
  unsigned short* ob = OutBf + (size_t)row * 256;
#pragma unroll
  for (int u = 0; u < 4; ++u) {
    float y = c[u] * rs * w[u * 64 + ln] + bias[u * 64 + ln];
    op[u * 64 + ln] = y;
    ob[u * 64 + ln] = f2bf(y);
  }
}

__global__ void cvt_k(const float* __restrict__ in, unsigned short* __restrict__ out, int n)
{
  int i = (blockIdx.x * 256 + threadIdx.x) * 4;
  if (i >= n) return;
  float4 v = *(const float4*)(in + i);
  unsigned short o[4] = {f2bf(v.x), f2bf(v.y), f2bf(v.z), f2bf(v.w)};
  *(ushort4*)(out + i) = *(ushort4*)o;
}

// Conv1d k=3 pad=1 — unchanged.
__global__ __launch_bounds__(256) void conv_k(
    const float* __restrict__ X, const float* __restrict__ Wt,
    const float* __restrict__ bias, float* __restrict__ Yo, int relu)
{
  const int b = blockIdx.z;
  const int o0 = blockIdx.y * 64, t0 = blockIdx.x * 64;
  const int tid = threadIdx.x, tx = tid & 15, ty = tid >> 4;
  __shared__ float xs[16][66];
  __shared__ float ws_s[64][48];
  float acc[4][4] = {{0.f,0.f,0.f,0.f},{0.f,0.f,0.f,0.f},{0.f,0.f,0.f,0.f},{0.f,0.f,0.f,0.f}};
  for (int i0 = 0; i0 < 256; i0 += 16) {
    for (int idx = tid; idx < 16 * 66; idx += 256) {
      int ic = idx / 66, tt = idx - ic * 66;
      int t = t0 + tt - 1;
      xs[ic][tt] = (t >= 0 && t < 256) ? X[((size_t)b * 256 + (i0 + ic)) * 256 + t] : 0.f;
    }
    for (int f4 = tid; f4 < 768; f4 += 256) {
      int oo = f4 / 12, seg = f4 - oo * 12;
      float4 v = *(const float4*)(Wt + (size_t)(o0 + oo) * 768 + i0 * 3 + seg * 4);
      *(float4*)&ws_s[oo][seg * 4] = v;
    }
    __syncthreads();
#pragma unroll
    for (int ic = 0; ic < 16; ++ic) {
      float xr[6];
#pragma unroll
      for (int u = 0; u < 6; ++u) xr[u] = xs[ic][tx * 4 + u];
#pragma unroll
      for (int i = 0; i < 4; ++i) {
        const float* wr = &ws_s[ty * 4 + i][ic * 3];
        float w0 = wr[0], w1 = wr[1], w2 = wr[2];
#pragma unroll
        for (int j = 0; j < 4; ++j)
          acc[i][j] += w0 * xr[j] + w1 * xr[j + 1] + w2 * xr[j + 2];
      }
    }
    __syncthreads();
  }
#pragma unroll
  for (int i = 0; i < 4; ++i) {
    int oo = o0 + ty * 4 + i;
    float bv = bias[oo];
#pragma unroll
    for (int j = 0; j < 4; ++j) {
      float v = acc[i][j] + bv;
      if (relu) v = fmaxf(v, 0.f);
      Yo[((size_t)b * 256 + oo) * 256 + t0 + tx * 4 + j] = v;
    }
  }
}

__global__ void transp_k(const float* __restrict__ In, float* __restrict__ Out)
{
  int b = blockIdx.z, t0 = blockIdx.x * 32, d0 = blockIdx.y * 32;
  __shared__ float tile[32][33];
  int tx = threadIdx.x, ty = threadIdx.y;
#pragma unroll
  for (int q = 0; q < 4; ++q)
    tile[ty + q * 8][tx] = In[((size_t)b * 256 + t0 + ty + q * 8) * 256 + d0 + tx];
  __syncthreads();
#pragma unroll
  for (int q = 0; q < 4; ++q)
    Out[((size_t)b * 256 + d0 + ty + q * 8) * 256 + t0 + tx] = tile[tx][ty + q * 8];
}

__global__ __launch_bounds__(256) void rowdot_k(
    const float* __restrict__ H, const float* __restrict__ lw,
    const float* __restrict__ lb, float* __restrict__ of32,
    float* __restrict__ oout, int rows)
{
  int tid = threadIdx.x, wv = tid >> 6, ln = tid & 63;
  int row = blockIdx.x * 4 + wv;
  if (row >= rows) return;
  const float* hp = H + (size_t)row * 256;
  float s = 0.f;
#pragma unroll
  for (int u = 0; u < 4; ++u) s += hp[u * 64 + ln] * lw[u * 64 + ln];
#pragma unroll
  for (int off = 1; off < 64; off <<= 1) s += __shfl_xor(s, off);
  if (ln == 0) {
    float v = s + lb[0];
    of32[row] = v;
    oout[row] = v;
  }
}

__global__ void maxlen_k(const float* __restrict__ dur, int* __restrict__ ml)
{
  __shared__ float rnds[32];
  int tid = threadIdx.x, wv = tid >> 6, ln = tid & 63;
  for (int b = wv; b < 32; b += 4) {
    const float* dp = dur + (size_t)b * 256;
    float s = dp[ln] + dp[64 + ln] + dp[128 + ln] + dp[192 + ln];
#pragma unroll
    for (int off = 1; off < 64; off <<= 1) s += __shfl_xor(s, off);
    if (ln == 0) rnds[b] = rintf(s);
  }
  __syncthreads();
  if (tid == 0) {
    float m = rnds[0];
    for (int b = 1; b < 32; ++b) m = fmaxf(m, rnds[b]);
    int v = (int)m;
    v = v < 0 ? 0 : (v > MAXBUF_ ? MAXBUF_ : v);
    *ml = v;
  }
}

__global__ void reg_k(const float* __restrict__ dur, const int* __restrict__ lens,
                      const int* __restrict__ ml, int* __restrict__ tok)
{
  int b = blockIdx.x;
  __shared__ float sdur[256];
  __shared__ int ends[256];
  int tid = threadIdx.x;
  sdur[tid] = dur[(size_t)b * 256 + tid];
  __syncthreads();
  if (tid == 0) {
    int maxlen = *ml, len = lens[b], pos = 0;
    for (int t = 0; t < 256; ++t) {
      int d = (int)rintf(sdur[t]);
      bool ok = (t < len) && (d > 0) && (pos + d <= maxlen);
      if (ok) pos += d;
      ends[t] = pos;
    }
  }
  __syncthreads();
  int total = ends[255];
  for (int f = tid; f < MAXBUF_; f += 256) {
    int lo = 0, hi = 256;
    while (lo < hi) { int mid = (lo + hi) >> 1; if (ends[mid] <= f) lo = mid + 1; else hi = mid; }
    int tc = lo > 255 ? 255 : lo;
    tok[(size_t)b * MAXBUF_ + f] = (f < total) ? tc : -1;
  }
}

__global__ void gather_k(const float* __restrict__ enc, const int* __restrict__ tok,
                         float* __restrict__ Y)
{
  int rf = blockIdx.x;
  int b = rf >> 10;
  int t = tok[rf];
  float4* dst = (float4*)(Y + (size_t)rf * 256);
  int ln = threadIdx.x;
  if (t >= 0) {
    const float4* src = (const float4*)(enc + ((size_t)b * 256 + t) * 256);
    dst[ln] = src[ln];
  } else {
    dst[ln] = make_float4(0.f, 0.f, 0.f, 0.f);
  }
}

// MEL (B*1024, 80) -> out (B, 80, 1024) via LDS tile transpose
__global__ __launch_bounds__(256) void meltr_k(
    const float* __restrict__ MEL, float* __restrict__ out)
{
  int b = blockIdx.z, m0 = blockIdx.y * 16, f0 = blockIdx.x * 64;
  __shared__ float t[16][65];
  int tid = threadIdx.x;
  {
    int f_i = tid >> 4, m_i = tid & 15;
#pragma unroll
    for (int q = 0; q < 4; ++q)
      t[m_i][f_i + q * 16] = MEL[((size_t)b * 1024 + f0 + f_i + q * 16) * 80 + m0 + m_i];
  }
  __syncthreads();
  {
    int f = tid & 63, my = tid >> 6;
#pragma unroll
    for (int q = 0; q < 4; ++q) {
      int m = my * 4 + q;
      out[((size_t)b * NMEL_ + m0 + m) * MAXBUF_ + f0 + f] = t[m][f];
    }
  }
}

// ============================================================================
extern "C" void kernel_launch(void* const* d_in, const int* in_sizes, int n_in,
                              void* d_out, int out_size, void* d_ws, size_t ws_size,
                              hipStream_t stream)
{
  (void)in_sizes; (void)n_in; (void)out_size;

  const float* te   = (const float*)d_in[0];
  const int*   lens = (const int*)d_in[1];
  const float* e_qkv_w = (const float*)d_in[2];
  const float* e_qkv_b = (const float*)d_in[3];
  const float* e_out_w = (const float*)d_in[4];
  const float* e_out_b = (const float*)d_in[5];
  const float* e_ln1_w = (const float*)d_in[6];
  const float* e_ln1_b = (const float*)d_in[7];
  const float* e_ff1_w = (const float*)d_in[8];
  const float* e_ff1_b = (const float*)d_in[9];
  const float* e_ff2_w = (const float*)d_in[10];
  const float* e_ff2_b = (const float*)d_in[11];
  const float* e_ln2_w = (const float*)d_in[12];
  const float* e_ln2_b = (const float*)d_in[13];
  const float* c1w = (const float*)d_in[14];
  const float* c1b = (const float*)d_in[15];
  const float* l1w = (const float*)d_in[16];
  const float* l1b = (const float*)d_in[17];
  const float* c2w = (const float*)d_in[18];
  const float* c2b = (const float*)d_in[19];
  const float* l2w = (const float*)d_in[20];
  const float* l2b = (const float*)d_in[21];
  const float* linw = (const float*)d_in[22];
  const float* linb = (const float*)d_in[23];
  const float* d_sa_qkv_w = (const float*)d_in[24];
  const float* d_sa_qkv_b = (const float*)d_in[25];
  const float* d_sa_out_w = (const float*)d_in[26];
  const float* d_sa_out_b = (const float*)d_in[27];
  const float* d_ca_qkv_w = (const float*)d_in[28];
  const float* d_ca_qkv_b = (const float*)d_in[29];
  const float* d_ca_out_w = (const float*)d_in[30];
  const float* d_ca_out_b = (const float*)d_in[31];
  const float* d_ln1_w = (const float*)d_in[32];
  const float* d_ln1_b = (const float*)d_in[33];
  const float* d_ln2_w = (const float*)d_in[34];
  const float* d_ln2_b = (const float*)d_in[35];
  const float* d_ln3_w = (const float*)d_in[36];
  const float* d_ln3_b = (const float*)d_in[37];
  const float* d_ff1_w = (const float*)d_in[38];
  const float* d_ff1_b = (const float*)d_in[39];
  const float* d_ff2_w = (const float*)d_in[40];
  const float* d_ff2_b = (const float*)d_in[41];
  const float* melw = (const float*)d_in[42];
  const float* melb = (const float*)d_in[43];
  float* out = (float*)d_out;   // f32: mel | duration | pitch | energy

  // ---- arena ----
  char* p = (char*)d_ws;
  float* Y   = (float*)p;            p += 8388608ull * 4;    // (B,1024,256) f32
  float* ENC = (float*)p;            p += 2097152ull * 4;    // (B,256,256) f32
  unsigned short* ENCbf = (unsigned short*)p; p += 2097152ull * 2;
  unsigned short* Wsaqkv = (unsigned short*)p; p += 786432ull * 2;
  unsigned short* Wsaout = (unsigned short*)p; p += 262144ull * 2;
  unsigned short* Wcaqkv = (unsigned short*)p; p += 786432ull * 2;
  unsigned short* Wcaout = (unsigned short*)p; p += 262144ull * 2;
  unsigned short* Wff1   = (unsigned short*)p; p += 1048576ull * 2;
  unsigned short* Wff2   = (unsigned short*)p; p += 1048576ull * 2;
  float* DUR = (float*)p;            p += 24576ull * 4;
  int* TOK   = (int*)p;              p += 32768ull * 4;
  int* MAXL  = (int*)p;              p += 4096;
  size_t fixed_b = (size_t)(p - (char*)d_ws);

  int grp = 1;
  {
    const int cand[6] = {32, 16, 8, 4, 2, 1};
    for (int c = 0; c < 6; ++c) {
      if (fixed_b + (size_t)cand[c] * 1835008ull * 2 <= ws_size) { grp = cand[c]; break; }
    }
  }
  unsigned short* REG = (unsigned short*)p;            // grouped region (bf16)
  unsigned short* Ybf   = REG;
  unsigned short* ADDbf = REG + (size_t)grp * 262144;
  unsigned short* AObf  = REG + (size_t)grp * 524288;
  unsigned short* UN    = REG + (size_t)grp * 786432;
  int grp_e = grp * 2 > 32 ? 32 : grp * 2;
  float* P0e = (float*)REG;
  float* P1e = P0e + (size_t)grp_e * 262144;
  float* P2e = P1e + (size_t)grp_e * 65536;
  float* ENCT = Y;            // vpred scratch in dead Y region
  float* H1   = Y + 2097152;
  float* H2   = Y + 4194304;
  float* MEL  = ENC;          // (B*1024, 80) f32 — ENC dead at mel time

  auto gemm = [&](const float* A, const float* W, const float* bias, float* C,
                  int M, int N, int K, int epi) {
    dim3 g((M + 63) / 64, (N + 63) / 64);
    gemm_k<<<g, dim3(256), 0, stream>>>(A, W, bias, C, M, N, K, epi);
  };
  auto gemm2 = [&](const float* A, const float* W, const float* bias, float* C,
                   int M, int N, int K, int epi) {
    dim3 g(M / 128, N / 128);
    gemm2_k<<<g, dim3(256), 0, stream>>>(A, W, bias, C, M, N, K, epi);
  };
  auto gemm_bf = [&](const unsigned short* A, const unsigned short* W, const float* bias,
                     unsigned short* C, int M, int N, int K, int epi) {
    dim3 g(M / 128, N / 128);
    gemm_bf_k<<<g, dim3(256), 0, stream>>>(A, W, bias, C, M, N, K, epi);
  };
  auto addln = [&](const float* X, const float* R, const float* w, const float* b,
                   float* O, int rows) {
    addln_k<<<dim3((rows + 3) / 4), dim3(256), 0, stream>>>(X, R, w, b, O, rows);
  };
  auto addln2 = [&](const float* X, const unsigned short* Rbf, const float* w, const float* b,
                    float* O, unsigned short* Obf, int rows) {
    addln2_k<<<dim3((rows + 3) / 4), dim3(256), 0, stream>>>(X, Rbf, w, b, O, Obf, rows);
  };
  auto cvt = [&](const float* in, unsigned short* o, int n) {
    cvt_k<<<dim3(n / 1024), dim3(256), 0, stream>>>(in, o, n);
  };

  // ---- convert decoder weights to bf16 (once) ----
  cvt(d_sa_qkv_w, Wsaqkv, 786432);
  cvt(d_sa_out_w, Wsaout, 262144);
  cvt(d_ca_qkv_w, Wcaqkv, 786432);
  cvt(d_ca_out_w, Wcaout, 262144);
  cvt(d_ff1_w, Wff1, 1048576);
  cvt(d_ff2_w, Wff2, 1048576);

  // ================= encoder (fp32, gemm2) =================
  for (int i = 0; i < 4; ++i) {
    for (int g0 = 0; g0 < B_; g0 += grp_e) {
      int rows = grp_e * T_;
      const size_t off = (size_t)g0 * T_ * D_;
      const float* xin = (i == 0) ? te + off : ENC + off;
      gemm2(xin, e_qkv_w + (size_t)i * 196608, e_qkv_b + i * 768, P0e, rows, 768, 256, 0);
      attn_k<<<dim3(T_ / 64, NH_, grp_e), dim3(256), 0, stream>>>(
          P0e, 768, P0e + 256, 768, P0e + 512, 768, P1e, T_, T_, lens + g0);
      gemm2(P1e, e_out_w + (size_t)i * 65536, e_out_b + i * 256, P2e, rows, 256, 256, 0);
      addln(xin, P2e, e_ln1_w + i * 256, e_ln1_b + i * 256, ENC + off, rows);
      gemm2(ENC + off, e_ff1_w + (size_t)i * 262144, e_ff1_b + i * 1024, P0e, rows, 1024, 256, 1);
      gemm2(P0e, e_ff2_w + (size_t)i * 262144, e_ff2_b + i * 256, P2e, rows, 256, 1024, 0);
      addln(ENC + off, P2e, e_ln2_w + i * 256, e_ln2_b + i * 256, ENC + off, rows);
    }
  }
  cvt(ENC, ENCbf, 2097152);

  // ================= variance predictors (fp32) =================
  transp_k<<<dim3(8, 8, B_), dim3(32, 8), 0, stream>>>(ENC, ENCT);
  for (int j = 0; j < 3; ++j) {
    conv_k<<<dim3(4, 4, B_), dim3(256), 0, stream>>>(
        ENCT, c1w + (size_t)j * 196608, c1b + j * 256, H1, 1);
    addln(H1, nullptr, l1w + j * 256, l1b + j * 256, H1, B_ * T_);
    conv_k<<<dim3(4, 4, B_), dim3(256), 0, stream>>>(
        H1, c2w + (size_t)j * 196608, c2b + j * 256, H2, 1);
    addln(H2, nullptr, l2w + j * 256, l2b + j * 256, H2, B_ * T_);
    rowdot_k<<<dim3(B_ * T_ / 4), dim3(256), 0, stream>>>(
        H2, linw + j * 256, linb + j, DUR + (size_t)j * 8192,
        out + 2621440 + (size_t)j * 8192, B_ * T_);
  }

  // ================= length regulator =================
  maxlen_k<<<dim3(1), dim3(256), 0, stream>>>(DUR, MAXL);
  reg_k<<<dim3(B_), dim3(256), 0, stream>>>(DUR, lens, MAXL, TOK);
  gather_k<<<dim3(B_ * MAXBUF_), dim3(64), 0, stream>>>(ENC, TOK, Y);

  // ================= decoder (bf16 MFMA) =================
  for (int i = 0; i < 4; ++i) {
    for (int g0 = 0; g0 < B_; g0 += grp) {
      int rows = grp * MAXBUF_;
      float* Yg = Y + (size_t)g0 * MAXBUF_ * D_;
      if (i == 0 || grp != B_)    // Ybf stays current across layers when grp==B
        cvt(Yg, Ybf, rows * 256);
      // self-attention
      gemm_bf(Ybf, Wsaqkv + (size_t)i * 196608, d_sa_qkv_b + i * 768, UN, rows, 768, 256, 0);
      attn_bf_k<<<dim3(MAXBUF_ / 64, NH_, grp), dim3(256), 0, stream>>>(
          UN, 768, UN + 256, 768, UN + 512, 768, AObf, MAXBUF_, MAXBUF_);
      gemm_bf(AObf, Wsaout + (size_t)i * 65536, d_sa_out_b + i * 256, ADDbf, rows, 256, 256, 0);
      addln2(Yg, ADDbf, d_ln1_w + i * 256, d_ln1_b + i * 256, Yg, Ybf, rows);
      // cross-attention
      gemm_bf(Ybf, Wcaqkv + (size_t)i * 196608, d_ca_qkv_b + i * 768, UN, rows, 256, 256, 0);
      gemm_bf(ENCbf + (size_t)g0 * 65536, Wcaqkv + (size_t)i * 196608 + 65536,
              d_ca_qkv_b + i * 768 + 256, UN + (size_t)grp * 262144, grp * T_, 512, 256, 0);
      attn_bf_k<<<dim3(MAXBUF_ / 64, NH_, grp), dim3(256), 0, stream>>>(
          UN, 256, UN + (size_t)grp * 262144, 512, UN + (size_t)grp * 262144 + 256, 512,
          AObf, MAXBUF_, T_);
      gemm_bf(AObf, Wcaout + (size_t)i * 65536, d_ca_out_b + i * 256, ADDbf, rows, 256, 256, 0);
      addln2(Yg, ADDbf, d_ln2_w + i * 256, d_ln2_b + i * 256, Yg, Ybf, rows);
      // feed-forward
      gemm_bf(Ybf, Wff1 + (size_t)i * 262144, d_ff1_b + i * 1024, UN, rows, 1024, 256, 1);
      gemm_bf(UN, Wff2 + (size_t)i * 262144, d_ff2_b + i * 256, ADDbf, rows, 256, 1024, 0);
      addln2(Yg, ADDbf, d_ln3_w + i * 256, d_ln3_b + i * 256, Yg, Ybf, rows);
    }
  }

  // ================= mel head: gemm + transpose =================
  gemm(Y, melw, melb, MEL, B_ * MAXBUF_, NMEL_, 256, 0);
  meltr_k<<<dim3(16, 5, B_), dim3(256), 0, stream>>>(MEL, out);
}

// Round 7
// 3571.447 us; speedup vs baseline: 1.1037x; 1.0896x over previous
//
#include <hip/hip_runtime.h>
#include <hip/hip_bf16.h>
#include <cstdint>
#include <cstddef>

// ============================================================================
// FastSpeech2 forward on MI355X. Round 7: fix gemm2_k accumulator spill.
//  r6 evidence: gemm2_k VGPR_Count=52 < 64-float accumulator -> spilled to
//  scratch (backend targeted 8 waves/SIMD from LDS-based heuristic; 64-VGPR
//  budget). Fix: __launch_bounds__(256,2) caps occupancy target (256-VGPR
//  budget), f32x4 accumulator (gemm_bf_k style), full unroll.
//  Everything else identical to r6 (passed, absmax at fp32 floor).
// ============================================================================

#define B_ 32
#define T_ 256
#define D_ 256
#define NH_ 4
#define FF_ 1024
#define MAXBUF_ 1024
#define NMEL_ 80

typedef __attribute__((ext_vector_type(8))) short short8;
typedef __attribute__((ext_vector_type(4))) float f32x4;

__device__ __forceinline__ unsigned short f2bf(float x) {
  unsigned int u = __float_as_uint(x);
  return (unsigned short)((u + 0x7fffu + ((u >> 16) & 1u)) >> 16);
}
__device__ __forceinline__ float bf2f(unsigned short h) {
  return __uint_as_float(((unsigned int)h) << 16);
}

#define GLD16(g, s)                                                         \
  __builtin_amdgcn_global_load_lds(                                         \
      (__attribute__((address_space(1))) void*)(g),                         \
      (__attribute__((address_space(3))) void*)(s), 16, 0, 0)

// ---------------------------------------------------------------------------
// fp32 GEMM, 64x64 tile (bounds-safe; used for mel N=80).
// ---------------------------------------------------------------------------
__global__ __launch_bounds__(256) void gemm_k(
    const float* __restrict__ A, const float* __restrict__ W,
    const float* __restrict__ bias, float* __restrict__ C,
    int M, int N, int K, int epi)
{
  __shared__ float As[16][64];
  __shared__ float Ws[16][64];
  const int tid = threadIdx.x;
  const int tx = tid & 15, ty = tid >> 4;
  const int bm = blockIdx.x * 64, bn = blockIdx.y * 64;
  const int lm = tid & 63, lk = tid >> 6;
  float acc[4][4] = {{0.f,0.f,0.f,0.f},{0.f,0.f,0.f,0.f},{0.f,0.f,0.f,0.f},{0.f,0.f,0.f,0.f}};
  const bool aok = (bm + lm) < M;
  const bool wok = (bn + lm) < N;
  const float* Ap = A + (size_t)(bm + lm) * K + lk * 4;
  const float* Wp = W + (size_t)(bn + lm) * K + lk * 4;
  for (int k0 = 0; k0 < K; k0 += 16) {
    float4 av = make_float4(0.f, 0.f, 0.f, 0.f);
    float4 wv = make_float4(0.f, 0.f, 0.f, 0.f);
    if (aok) av = *(const float4*)(Ap + k0);
    if (wok) wv = *(const float4*)(Wp + k0);
    As[lk*4+0][lm] = av.x; As[lk*4+1][lm] = av.y; As[lk*4+2][lm] = av.z; As[lk*4+3][lm] = av.w;
    Ws[lk*4+0][lm] = wv.x; Ws[lk*4+1][lm] = wv.y; Ws[lk*4+2][lm] = wv.z; Ws[lk*4+3][lm] = wv.w;
    __syncthreads();
#pragma unroll
    for (int kk = 0; kk < 16; ++kk) {
      float4 a4 = *(const float4*)&As[kk][ty * 4];
      float4 b4 = *(const float4*)&Ws[kk][tx * 4];
      float aa[4] = {a4.x, a4.y, a4.z, a4.w};
      float bb[4] = {b4.x, b4.y, b4.z, b4.w};
#pragma unroll
      for (int i = 0; i < 4; ++i)
#pragma unroll
        for (int j = 0; j < 4; ++j)
          acc[i][j] += aa[i] * bb[j];
    }
    __syncthreads();
  }
#pragma unroll
  for (int i = 0; i < 4; ++i) {
    int gm = bm + ty * 4 + i;
    if (gm >= M) continue;
#pragma unroll
    for (int j = 0; j < 4; ++j) {
      int gn = bn + tx * 4 + j;
      if (gn >= N) continue;
      float v = acc[i][j] + bias[gn];
      if (epi == 1) v = 0.5f * v * (1.0f + erff(v * 0.70710678118654752f));
      C[(size_t)gm * N + gn] = v;
    }
  }
}

// ---------------------------------------------------------------------------
// fp32 GEMM, 128x128 tile, 8x8 micro with f32x4 accumulators (NO SPILL).
// __launch_bounds__(256,2): RA budget 256 VGPRs (usage ~110 -> 4 waves/SIMD).
// Requires M%128==0, N%128==0, K%16==0.
// ---------------------------------------------------------------------------
__global__ __launch_bounds__(256, 2) void gemm2_k(
    const float* __restrict__ A, const float* __restrict__ W,
    const float* __restrict__ bias, float* __restrict__ C,
    int M, int N, int K, int epi)
{
  __shared__ float As[16][128];
  __shared__ float Bs[16][128];
  const int tid = threadIdx.x;
  const int tx = tid & 15, ty = tid >> 4;
  const int bm = blockIdx.x * 128, bn = blockIdx.y * 128;
  const int r = tid & 127, ks = (tid >> 7) * 8;
  f32x4 acc[8][2];
#pragma unroll
  for (int i = 0; i < 8; ++i) {
    acc[i][0] = (f32x4){0.f, 0.f, 0.f, 0.f};
    acc[i][1] = (f32x4){0.f, 0.f, 0.f, 0.f};
  }
  const float* Ap = A + (size_t)(bm + r) * K + ks;
  const float* Wp = W + (size_t)(bn + r) * K + ks;
  for (int k0 = 0; k0 < K; k0 += 16) {
    float4 a0 = *(const float4*)(Ap + k0);
    float4 a1 = *(const float4*)(Ap + k0 + 4);
    float4 w0 = *(const float4*)(Wp + k0);
    float4 w1 = *(const float4*)(Wp + k0 + 4);
    __syncthreads();
    As[ks+0][r] = a0.x; As[ks+1][r] = a0.y; As[ks+2][r] = a0.z; As[ks+3][r] = a0.w;
    As[ks+4][r] = a1.x; As[ks+5][r] = a1.y; As[ks+6][r] = a1.z; As[ks+7][r] = a1.w;
    Bs[ks+0][r] = w0.x; Bs[ks+1][r] = w0.y; Bs[ks+2][r] = w0.z; Bs[ks+3][r] = w0.w;
    Bs[ks+4][r] = w1.x; Bs[ks+5][r] = w1.y; Bs[ks+6][r] = w1.z; Bs[ks+7][r] = w1.w;
    __syncthreads();
#pragma unroll
    for (int kk = 0; kk < 16; ++kk) {
      f32x4 bA = *(const f32x4*)&Bs[kk][tx * 4];
      f32x4 bB = *(const f32x4*)&Bs[kk][tx * 4 + 64];
      float4 aA = *(const float4*)&As[kk][ty * 4];
      float4 aB = *(const float4*)&As[kk][ty * 4 + 64];
      float av[8] = {aA.x, aA.y, aA.z, aA.w, aB.x, aB.y, aB.z, aB.w};
#pragma unroll
      for (int i = 0; i < 8; ++i) {
        acc[i][0] += bA * av[i];
        acc[i][1] += bB * av[i];
      }
    }
  }
#pragma unroll
  for (int i = 0; i < 8; ++i) {
    int gm = bm + (i >> 2) * 64 + ty * 4 + (i & 3);
#pragma unroll
    for (int half = 0; half < 2; ++half) {
      int gn = bn + half * 64 + tx * 4;
      float4 o;
      o.x = acc[i][half][0] + bias[gn + 0];
      o.y = acc[i][half][1] + bias[gn + 1];
      o.z = acc[i][half][2] + bias[gn + 2];
      o.w = acc[i][half][3] + bias[gn + 3];
      if (epi == 1) {
        o.x = 0.5f * o.x * (1.0f + erff(o.x * 0.70710678118654752f));
        o.y = 0.5f * o.y * (1.0f + erff(o.y * 0.70710678118654752f));
        o.z = 0.5f * o.z * (1.0f + erff(o.z * 0.70710678118654752f));
        o.w = 0.5f * o.w * (1.0f + erff(o.w * 0.70710678118654752f));
      }
      *(float4*)(C + (size_t)gm * N + gn) = o;
    }
  }
}

// ---------------------------------------------------------------------------
// fp32 flash attention (encoder only) — unchanged.
// ---------------------------------------------------------------------------
__global__ __launch_bounds__(256) void attn_k(
    const float* __restrict__ Qp, int qStride,
    const float* __restrict__ Kp, int kStride,
    const float* __restrict__ Vp, int vStride,
    float* __restrict__ Op, int Tq, int Tkv,
    const int* __restrict__ lengths)
{
  const int b = blockIdx.z, h = blockIdx.y, qt = blockIdx.x;
  const int tid = threadIdx.x;
  const int tx = tid & 15, ty = tid >> 4;
  const int lr = tid & 63, lq = tid >> 6;

  __shared__ float Qs[64][64];
  __shared__ float KT[64][64];
  __shared__ float Sm[64][65];

  {
    const float* q = Qp + (size_t)(b * Tq + qt * 64 + lr) * qStride + h * 64 + lq * 16;
    float4 v0 = ((const float4*)q)[0];
    float4 v1 = ((const float4*)q)[1];
    float4 v2 = ((const float4*)q)[2];
    float4 v3 = ((const float4*)q)[3];
    *(float4*)&Qs[lr][lq*16 + 0]  = v0;
    *(float4*)&Qs[lr][lq*16 + 4]  = v1;
    *(float4*)&Qs[lr][lq*16 + 8]  = v2;
    *(float4*)&Qs[lr][lq*16 + 12] = v3;
  }

  float m_reg[4], l_reg[4], o[4][4];
#pragma unroll
  for (int i = 0; i < 4; ++i) {
    m_reg[i] = -INFINITY; l_reg[i] = 0.f;
#pragma unroll
    for (int j = 0; j < 4; ++j) o[i][j] = 0.f;
  }

  const int len_b = lengths ? lengths[b] : 0x7fffffff;
  const int nkt = Tkv >> 6;

  for (int kt = 0; kt < nkt; ++kt) {
    __syncthreads();
    {
      const float* kp = Kp + (size_t)(b * Tkv + kt * 64 + lr) * kStride + h * 64 + lq * 16;
      float4 v[4];
      v[0] = ((const float4*)kp)[0]; v[1] = ((const float4*)kp)[1];
      v[2] = ((const float4*)kp)[2]; v[3] = ((const float4*)kp)[3];
#pragma unroll
      for (int u = 0; u < 4; ++u) {
        KT[lq*16 + u*4 + 0][lr] = v[u].x;
        KT[lq*16 + u*4 + 1][lr] = v[u].y;
        KT[lq*16 + u*4 + 2][lr] = v[u].z;
        KT[lq*16 + u*4 + 3][lr] = v[u].w;
      }
    }
    __syncthreads();

    float s[4][4] = {{0.f,0.f,0.f,0.f},{0.f,0.f,0.f,0.f},{0.f,0.f,0.f,0.f},{0.f,0.f,0.f,0.f}};
#pragma unroll
    for (int d4 = 0; d4 < 16; ++d4) {
      float4 qv[4], kv[4];
#pragma unroll
      for (int i = 0; i < 4; ++i) qv[i] = *(const float4*)&Qs[ty*4 + i][d4*4];
#pragma unroll
      for (int dd = 0; dd < 4; ++dd) kv[dd] = *(const float4*)&KT[d4*4 + dd][tx*4];
#pragma unroll
      for (int i = 0; i < 4; ++i) {
        s[i][0] += qv[i].x*kv[0].x + qv[i].y*kv[1].x + qv[i].z*kv[2].x + qv[i].w*kv[3].x;
        s[i][1] += qv[i].x*kv[0].y + qv[i].y*kv[1].y + qv[i].z*kv[2].y + qv[i].w*kv[3].y;
        s[i][2] += qv[i].x*kv[0].z + qv[i].y*kv[1].z + qv[i].z*kv[2].z + qv[i].w*kv[3].z;
        s[i][3] += qv[i].x*kv[0].w + qv[i].y*kv[1].w + qv[i].z*kv[2].w + qv[i].w*kv[3].w;
      }
    }

    float alpha[4];
#pragma unroll
    for (int i = 0; i < 4; ++i) {
      float pm = -INFINITY;
#pragma unroll
      for (int j = 0; j < 4; ++j) {
        int kg = kt * 64 + tx * 4 + j;
        float v = s[i][j] * 0.125f;
        if (kg >= len_b) v = -1e9f;
        s[i][j] = v;
        pm = fmaxf(pm, v);
      }
#pragma unroll
      for (int off = 1; off < 16; off <<= 1) pm = fmaxf(pm, __shfl_xor(pm, off));
      float mn = fmaxf(m_reg[i], pm);
      alpha[i] = expf(m_reg[i] - mn);
      float ls = 0.f;
#pragma unroll
      for (int j = 0; j < 4; ++j) {
        float p = expf(s[i][j] - mn);
        Sm[ty*4 + i][tx*4 + j] = p;
        ls += p;
      }
#pragma unroll
      for (int off = 1; off < 16; off <<= 1) ls += __shfl_xor(ls, off);
      l_reg[i] = l_reg[i] * alpha[i] + ls;
      m_reg[i] = mn;
    }
    __syncthreads();

    {
      const float* vp = Vp + (size_t)(b * Tkv + kt * 64 + lr) * vStride + h * 64 + lq * 16;
      float4 v0 = ((const float4*)vp)[0];
      float4 v1 = ((const float4*)vp)[1];
      float4 v2 = ((const float4*)vp)[2];
      float4 v3 = ((const float4*)vp)[3];
      *(float4*)&KT[lr][lq*16 + 0]  = v0;
      *(float4*)&KT[lr][lq*16 + 4]  = v1;
      *(float4*)&KT[lr][lq*16 + 8]  = v2;
      *(float4*)&KT[lr][lq*16 + 12] = v3;
    }
    __syncthreads();

#pragma unroll
    for (int i = 0; i < 4; ++i) {
      o[i][0] *= alpha[i]; o[i][1] *= alpha[i]; o[i][2] *= alpha[i]; o[i][3] *= alpha[i];
    }
#pragma unroll 8
    for (int c = 0; c < 64; ++c) {
      float4 vv = *(const float4*)&KT[c][tx * 4];
#pragma unroll
      for (int i = 0; i < 4; ++i) {
        float p = Sm[ty*4 + i][c];
        o[i][0] += p * vv.x; o[i][1] += p * vv.y; o[i][2] += p * vv.z; o[i][3] += p * vv.w;
      }
    }
  }

#pragma unroll
  for (int i = 0; i < 4; ++i) {
    float inv = 1.f / l_reg[i];
    float4 r;
    r.x = o[i][0] * inv; r.y = o[i][1] * inv; r.z = o[i][2] * inv; r.w = o[i][3] * inv;
    *(float4*)(Op + (size_t)(b * Tq + qt * 64 + ty * 4 + i) * 256 + h * 64 + tx * 4) = r;
  }
}

// ---------------------------------------------------------------------------
// bf16 MFMA GEMM — unchanged.
// ---------------------------------------------------------------------------
__global__ __launch_bounds__(256) void gemm_bf_k(
    const unsigned short* __restrict__ A, const unsigned short* __restrict__ W,
    const float* __restrict__ bias, unsigned short* __restrict__ C,
    int M, int N, int K, int epi)
{
  __shared__ __align__(16) short As[128 * 32];
  __shared__ __align__(16) short Bs[128 * 32];
  const int tid = threadIdx.x;
  const int lane = tid & 63, w = tid >> 6;
  const int g = lane >> 4, li = lane & 15;
  const int wr = (w >> 1) * 64, wc = (w & 1) * 64;
  const int bm = blockIdx.x * 128, bn = blockIdx.y * 128;

  f32x4 acc[4][4];
#pragma unroll
  for (int m = 0; m < 4; ++m)
#pragma unroll
    for (int n = 0; n < 4; ++n)
      acc[m][n] = (f32x4){0.f, 0.f, 0.f, 0.f};

  const int srow = tid >> 2, scol = (tid & 3) * 8;
  const unsigned short* Ag = A + (size_t)(bm + srow) * K + scol;
  const unsigned short* Wg = W + (size_t)(bn + srow) * K + scol;

  for (int k0 = 0; k0 < K; k0 += 32) {
    __syncthreads();
    GLD16(Ag + k0, &As[tid * 8]);
    GLD16(Ag + k0 + (size_t)64 * K, &As[tid * 8 + 2048]);
    GLD16(Wg + k0, &Bs[tid * 8]);
    GLD16(Wg + k0 + (size_t)64 * K, &Bs[tid * 8 + 2048]);
    __syncthreads();
    short8 af[4], bf[4];
#pragma unroll
    for (int m = 0; m < 4; ++m) af[m] = *(const short8*)&As[(wr + m * 16 + li) * 32 + g * 8];
#pragma unroll
    for (int n = 0; n < 4; ++n) bf[n] = *(const short8*)&Bs[(wc + n * 16 + li) * 32 + g * 8];
#pragma unroll
    for (int m = 0; m < 4; ++m)
#pragma unroll
      for (int n = 0; n < 4; ++n)
        acc[m][n] = __builtin_amdgcn_mfma_f32_16x16x32_bf16(af[m], bf[n], acc[m][n], 0, 0, 0);
  }

#pragma unroll
  for (int m = 0; m < 4; ++m) {
#pragma unroll
    for (int n = 0; n < 4; ++n) {
      int col = bn + wc + n * 16 + li;
      float bv = bias[col];
#pragma unroll
      for (int r = 0; r < 4; ++r) {
        int row = bm + wr + m * 16 + g * 4 + r;
        float v = acc[m][n][r] + bv;
        if (epi == 1) v = 0.5f * v * (1.0f + erff(v * 0.70710678118654752f));
        C[(size_t)row * N + col] = f2bf(v);
      }
    }
  }
}

// ---------------------------------------------------------------------------
// bf16 MFMA flash attention — unchanged from r6 (conflict-free staging,
// XCD-aware remap).
// ---------------------------------------------------------------------------
__global__ __launch_bounds__(256) void attn_bf_k(
    const unsigned short* __restrict__ Qp, int qStride,
    const unsigned short* __restrict__ Kp, int kStride,
    const unsigned short* __restrict__ Vp, int vStride,
    unsigned short* __restrict__ Op, int Tq, int Tkv)
{
  int b, h, qt;
  {
    const int nqt = gridDim.x, nh = gridDim.y, nbh = gridDim.y * gridDim.z;
    if ((nbh & 7) == 0) {
      int linear = blockIdx.x + nqt * (blockIdx.y + gridDim.y * blockIdx.z);
      int xcd = linear & 7, idx = linear >> 3;
      int bh = xcd * (nbh >> 3) + idx / nqt;
      qt = idx - (idx / nqt) * nqt;
      h = bh % nh; b = bh / nh;
    } else { qt = blockIdx.x; h = blockIdx.y; b = blockIdx.z; }
  }
  const int tid = threadIdx.x;
  const int lane = tid & 63, w = tid >> 6;
  const int g = lane >> 4, li = lane & 15;

  __shared__ __align__(16) short Qs[64 * 64];
  __shared__ __align__(16) short Ks[64 * 64];
  __shared__ __align__(16) short VT[64 * 64];
  __shared__ __align__(16) short Ps[64 * 64];

  {
    const int r0 = tid >> 3, seg = tid & 7;
#pragma unroll
    for (int i = 0; i < 2; ++i) {
      int r = r0 + i * 32;
      short8 v = *(const short8*)(Qp + (size_t)(b * Tq + qt * 64 + r) * qStride + h * 64 + seg * 8);
      *(short8*)&Qs[r * 64 + ((seg ^ (r & 7)) << 3)] = v;
    }
  }
  __syncthreads();

  short8 aq[2];
#pragma unroll
  for (int ks = 0; ks < 2; ++ks) {
    int row = w * 16 + li;
    aq[ks] = *(const short8*)&Qs[row * 64 + (((ks * 4 + g) ^ (row & 7)) << 3)];
  }

  float m_reg[4], l_reg[4];
  f32x4 o[4];
#pragma unroll
  for (int r = 0; r < 4; ++r) { m_reg[r] = -INFINITY; l_reg[r] = 0.f; }
#pragma unroll
  for (int n = 0; n < 4; ++n) o[n] = (f32x4){0.f, 0.f, 0.f, 0.f};

  const int nkt = Tkv >> 6;
  for (int kt = 0; kt < nkt; ++kt) {
    __syncthreads();
    { // K: coalesced rows
      const int r0 = tid >> 3, seg = tid & 7;
#pragma unroll
      for (int i = 0; i < 2; ++i) {
        int r = r0 + i * 32;
        short8 kv = *(const short8*)(Kp + (size_t)(b * Tkv + kt * 64 + r) * kStride + h * 64 + seg * 8);
        *(short8*)&Ks[r * 64 + ((seg ^ (r & 7)) << 3)] = kv;
      }
    }
    { // V transpose: r = lane (64 distinct rows/wave)
      const int rv = tid & 63, wv_ = tid >> 6;
#pragma unroll
      for (int i = 0; i < 2; ++i) {
        int seg = wv_ * 2 + i;
        short8 vv = *(const short8*)(Vp + (size_t)(b * Tkv + kt * 64 + rv) * vStride + h * 64 + seg * 8);
#pragma unroll
        for (int j = 0; j < 8; ++j) {
          int d = seg * 8 + j;
          VT[d * 64 + (rv ^ ((d & 7) << 3))] = vv[j];
        }
      }
    }
    __syncthreads();

    f32x4 s[4];
#pragma unroll
    for (int n = 0; n < 4; ++n) {
      f32x4 acc = (f32x4){0.f, 0.f, 0.f, 0.f};
#pragma unroll
      for (int ks = 0; ks < 2; ++ks) {
        int key = n * 16 + li;
        short8 bk = *(const short8*)&Ks[key * 64 + (((ks * 4 + g) ^ (key & 7)) << 3)];
        acc = __builtin_amdgcn_mfma_f32_16x16x32_bf16(aq[ks], bk, acc, 0, 0, 0);
      }
      s[n] = acc * 0.125f;
    }

    float alpha[4];
#pragma unroll
    for (int r = 0; r < 4; ++r) {
      float pm = fmaxf(fmaxf(s[0][r], s[1][r]), fmaxf(s[2][r], s[3][r]));
#pragma unroll
      for (int off = 1; off < 16; off <<= 1) pm = fmaxf(pm, __shfl_xor(pm, off));
      float mn = fmaxf(m_reg[r], pm);
      alpha[r] = expf(m_reg[r] - mn);
      float ls = 0.f;
      int row = w * 16 + g * 4 + r;
#pragma unroll
      for (int n = 0; n < 4; ++n) {
        float p = expf(s[n][r] - mn);
        ls += p;
        int col = n * 16 + li;
        Ps[row * 64 + (col ^ ((row & 7) << 3))] = (short)f2bf(p);
      }
#pragma unroll
      for (int off = 1; off < 16; off <<= 1) ls += __shfl_xor(ls, off);
      l_reg[r] = l_reg[r] * alpha[r] + ls;
      m_reg[r] = mn;
    }

    f32x4 al = (f32x4){alpha[0], alpha[1], alpha[2], alpha[3]};
#pragma unroll
    for (int n = 0; n < 4; ++n) o[n] *= al;
    short8 ap[2];
#pragma unroll
    for (int ks = 0; ks < 2; ++ks) {
      int row = w * 16 + li;
      ap[ks] = *(const short8*)&Ps[row * 64 + (((ks * 4 + g) ^ (row & 7)) << 3)];
    }
#pragma unroll
    for (int n = 0; n < 4; ++n) {
#pragma unroll
      for (int ks = 0; ks < 2; ++ks) {
        int d = n * 16 + li;
        short8 bv = *(const short8*)&VT[d * 64 + (((ks * 4 + g) ^ (d & 7)) << 3)];
        o[n] = __builtin_amdgcn_mfma_f32_16x16x32_bf16(ap[ks], bv, o[n], 0, 0, 0);
      }
    }
  }

#pragma unroll
  for (int n = 0; n < 4; ++n) {
#pragma unroll
    for (int r = 0; r < 4; ++r) {
      float v = o[n][r] / l_reg[r];
      Op[(size_t)(b * Tq + qt * 64 + w * 16 + g * 4 + r) * 256 + h * 64 + n * 16 + li] = f2bf(v);
    }
  }
}

// LayerNorm f32 — unchanged.
__global__ __launch_bounds__(256) void addln_k(
    const float* __restrict__ X, const float* __restrict__ R,
    const float* __restrict__ w, const float* __restrict__ bias,
    float* __restrict__ Out, int rows)
{
  int tid = threadIdx.x, wv = tid >> 6, ln = tid & 63;
  int row = blockIdx.x * 4 + wv;
  if (row >= rows) return;
  const float* xp = X + (size_t)row * 256;
  float v[4];
#pragma unroll
  for (int u = 0; u < 4; ++u) v[u] = xp[u * 64 + ln];
  if (R) {
    const float* rp = R + (size_t)row * 256;
#pragma unroll
    for (int u = 0; u < 4; ++u) v[u] += rp[u * 64 + ln];
  }
  float s = v[0] + v[1] + v[2] + v[3];
#pragma unroll
  for (int off = 1; off < 64; off <<= 1) s += __shfl_xor(s, off);
  float mean = s * (1.f / 256.f);
  float c[4], sq = 0.f;
#pragma unroll
  for (int u = 0; u < 4; ++u) { c[u] = v[u] - mean; sq += c[u] * c[u]; }
#pragma unroll
  for (int off = 1; off < 64; off <<= 1) sq += __shfl_xor(sq, off);
  float rs = 1.f / sqrtf(sq * (1.f / 256.f) + 1e-5f);
  float* op = Out + (size_t)row * 256;
#pragma unroll
  for (int u = 0; u < 4; ++u)
    op[u * 64 + ln] = c[u] * rs * w[u * 64 + ln] + bias[u * 64 + ln];
}

// LayerNorm + bf16 residual; writes f32 state + bf16 mirror — unchanged.
__global__ __launch_bounds__(256) void addln2_k(
    const float* __restrict__ X, const unsigned short* __restrict__ Rbf,
    const float* __restrict__ w, const float* __restrict__ bias,
    float* __restrict__ Out, unsigned short* __restrict__ OutBf, int rows)
{
  int tid = threadIdx.x, wv = tid >> 6, ln = tid & 63;
  int row = blockIdx.x * 4 + wv;
  if (row >= rows) return;
  const float* xp = X + (size_t)row * 256;
  const unsigned short* rp = Rbf + (size_t)row * 256;
  float v[4];
#pragma unroll
  for (int u = 0; u < 4; ++u) v[u] = xp[u * 64 + ln] + bf2f(rp[u * 64 + ln]);
  float s = v[0] + v[1] + v[2] + v[3];
#pragma unroll
  for (int off = 1; off < 64; off <<= 1) s += __shfl_xor(s, off);
  float mean = s * (1.f / 256.f);
  float c[4], sq = 0.f;
#pragma unroll
  for (int u = 0; u < 4; ++u) { c[u] = v[u] - mean; sq += c[u] * c[u]; }
#pragma unroll
  for (int off = 1; off < 64; off <<= 1) sq += __shfl_xor(sq, off);
  float rs = 1.f / sqrtf(sq * (1.f / 256.f) + 1e-5f);
  float* op = Out + (size_t)row * 256;
  unsigned short* ob = OutBf + (size_t)row * 256;
#pragma unroll
  for (int u = 0; u < 4; ++u) {
    float y = c[u] * rs * w[u * 64 + ln] + bias[u * 64 + ln];
    op[u * 64 + ln] = y;
    ob[u * 64 + ln] = f2bf(y);
  }
}

__global__ void cvt_k(const float* __restrict__ in, unsigned short* __restrict__ out, int n)
{
  int i = (blockIdx.x * 256 + threadIdx.x) * 4;
  if (i >= n) return;
  float4 v = *(const float4*)(in + i);
  unsigned short o[4] = {f2bf(v.x), f2bf(v.y), f2bf(v.z), f2bf(v.w)};
  *(ushort4*)(out + i) = *(ushort4*)o;
}

// Conv1d k=3 pad=1 — unchanged.
__global__ __launch_bounds__(256) void conv_k(
    const float* __restrict__ X, const float* __restrict__ Wt,
    const float* __restrict__ bias, float* __restrict__ Yo, int relu)
{
  const int b = blockIdx.z;
  const int o0 = blockIdx.y * 64, t0 = blockIdx.x * 64;
  const int tid = threadIdx.x, tx = tid & 15, ty = tid >> 4;
  __shared__ float xs[16][66];
  __shared__ float ws_s[64][48];
  float acc[4][4] = {{0.f,0.f,0.f,0.f},{0.f,0.f,0.f,0.f},{0.f,0.f,0.f,0.f},{0.f,0.f,0.f,0.f}};
  for (int i0 = 0; i0 < 256; i0 += 16) {
    for (int idx = tid; idx < 16 * 66; idx += 256) {
      int ic = idx / 66, tt = idx - ic * 66;
      int t = t0 + tt - 1;
      xs[ic][tt] = (t >= 0 && t < 256) ? X[((size_t)b * 256 + (i0 + ic)) * 256 + t] : 0.f;
    }
    for (int f4 = tid; f4 < 768; f4 += 256) {
      int oo = f4 / 12, seg = f4 - oo * 12;
      float4 v = *(const float4*)(Wt + (size_t)(o0 + oo) * 768 + i0 * 3 + seg * 4);
      *(float4*)&ws_s[oo][seg * 4] = v;
    }
    __syncthreads();
#pragma unroll
    for (int ic = 0; ic < 16; ++ic) {
      float xr[6];
#pragma unroll
      for (int u = 0; u < 6; ++u) xr[u] = xs[ic][tx * 4 + u];
#pragma unroll
      for (int i = 0; i < 4; ++i) {
        const float* wr = &ws_s[ty * 4 + i][ic * 3];
        float w0 = wr[0], w1 = wr[1], w2 = wr[2];
#pragma unroll
        for (int j = 0; j < 4; ++j)
          acc[i][j] += w0 * xr[j] + w1 * xr[j + 1] + w2 * xr[j + 2];
      }
    }
    __syncthreads();
  }
#pragma unroll
  for (int i = 0; i < 4; ++i) {
    int oo = o0 + ty * 4 + i;
    float bv = bias[oo];
#pragma unroll
    for (int j = 0; j < 4; ++j) {
      float v = acc[i][j] + bv;
      if (relu) v = fmaxf(v, 0.f);
      Yo[((size_t)b * 256 + oo) * 256 + t0 + tx * 4 + j] = v;
    }
  }
}

__global__ void transp_k(const float* __restrict__ In, float* __restrict__ Out)
{
  int b = blockIdx.z, t0 = blockIdx.x * 32, d0 = blockIdx.y * 32;
  __shared__ float tile[32][33];
  int tx = threadIdx.x, ty = threadIdx.y;
#pragma unroll
  for (int q = 0; q < 4; ++q)
    tile[ty + q * 8][tx] = In[((size_t)b * 256 + t0 + ty + q * 8) * 256 + d0 + tx];
  __syncthreads();
#pragma unroll
  for (int q = 0; q < 4; ++q)
    Out[((size_t)b * 256 + d0 + ty + q * 8) * 256 + t0 + tx] = tile[tx][ty + q * 8];
}

__global__ __launch_bounds__(256) void rowdot_k(
    const float* __restrict__ H, const float* __restrict__ lw,
    const float* __restrict__ lb, float* __restrict__ of32,
    float* __restrict__ oout, int rows)
{
  int tid = threadIdx.x, wv = tid >> 6, ln = tid & 63;
  int row = blockIdx.x * 4 + wv;
  if (row >= rows) return;
  const float* hp = H + (size_t)row * 256;
  float s = 0.f;
#pragma unroll
  for (int u = 0; u < 4; ++u) s += hp[u * 64 + ln] * lw[u * 64 + ln];
#pragma unroll
  for (int off = 1; off < 64; off <<= 1) s += __shfl_xor(s, off);
  if (ln == 0) {
    float v = s + lb[0];
    of32[row] = v;
    oout[row] = v;
  }
}

__global__ void maxlen_k(const float* __restrict__ dur, int* __restrict__ ml)
{
  __shared__ float rnds[32];
  int tid = threadIdx.x, wv = tid >> 6, ln = tid & 63;
  for (int b = wv; b < 32; b += 4) {
    const float* dp = dur + (size_t)b * 256;
    float s = dp[ln] + dp[64 + ln] + dp[128 + ln] + dp[192 + ln];
#pragma unroll
    for (int off = 1; off < 64; off <<= 1) s += __shfl_xor(s, off);
    if (ln == 0) rnds[b] = rintf(s);
  }
  __syncthreads();
  if (tid == 0) {
    float m = rnds[0];
    for (int b = 1; b < 32; ++b) m = fmaxf(m, rnds[b]);
    int v = (int)m;
    v = v < 0 ? 0 : (v > MAXBUF_ ? MAXBUF_ : v);
    *ml = v;
  }
}

__global__ void reg_k(const float* __restrict__ dur, const int* __restrict__ lens,
                      const int* __restrict__ ml, int* __restrict__ tok)
{
  int b = blockIdx.x;
  __shared__ float sdur[256];
  __shared__ int ends[256];
  int tid = threadIdx.x;
  sdur[tid] = dur[(size_t)b * 256 + tid];
  __syncthreads();
  if (tid == 0) {
    int maxlen = *ml, len = lens[b], pos = 0;
    for (int t = 0; t < 256; ++t) {
      int d = (int)rintf(sdur[t]);
      bool ok = (t < len) && (d > 0) && (pos + d <= maxlen);
      if (ok) pos += d;
      ends[t] = pos;
    }
  }
  __syncthreads();
  int total = ends[255];
  for (int f = tid; f < MAXBUF_; f += 256) {
    int lo = 0, hi = 256;
    while (lo < hi) { int mid = (lo + hi) >> 1; if (ends[mid] <= f) lo = mid + 1; else hi = mid; }
    int tc = lo > 255 ? 255 : lo;
    tok[(size_t)b * MAXBUF_ + f] = (f < total) ? tc : -1;
  }
}

__global__ void gather_k(const float* __restrict__ enc, const int* __restrict__ tok,
                         float* __restrict__ Y)
{
  int rf = blockIdx.x;
  int b = rf >> 10;
  int t = tok[rf];
  float4* dst = (float4*)(Y + (size_t)rf * 256);
  int ln = threadIdx.x;
  if (t >= 0) {
    const float4* src = (const float4*)(enc + ((size_t)b * 256 + t) * 256);
    dst[ln] = src[ln];
  } else {
    dst[ln] = make_float4(0.f, 0.f, 0.f, 0.f);
  }
}

// MEL (B*1024, 80) -> out (B, 80, 1024) via LDS tile transpose
__global__ __launch_bounds__(256) void meltr_k(
    const float* __restrict__ MEL, float* __restrict__ out)
{
  int b = blockIdx.z, m0 = blockIdx.y * 16, f0 = blockIdx.x * 64;
  __shared__ float t[16][65];
  int tid = threadIdx.x;
  {
    int f_i = tid >> 4, m_i = tid & 15;
#pragma unroll
    for (int q = 0; q < 4; ++q)
      t[m_i][f_i + q * 16] = MEL[((size_t)b * 1024 + f0 + f_i + q * 16) * 80 + m0 + m_i];
  }
  __syncthreads();
  {
    int f = tid & 63, my = tid >> 6;
#pragma unroll
    for (int q = 0; q < 4; ++q) {
      int m = my * 4 + q;
      out[((size_t)b * NMEL_ + m0 + m) * MAXBUF_ + f0 + f] = t[m][f];
    }
  }
}

// ============================================================================
extern "C" void kernel_launch(void* const* d_in, const int* in_sizes, int n_in,
                              void* d_out, int out_size, void* d_ws, size_t ws_size,
                              hipStream_t stream)
{
  (void)in_sizes; (void)n_in; (void)out_size;

  const float* te   = (const float*)d_in[0];
  const int*   lens = (const int*)d_in[1];
  const float* e_qkv_w = (const float*)d_in[2];
  const float* e_qkv_b = (const float*)d_in[3];
  const float* e_out_w = (const float*)d_in[4];
  const float* e_out_b = (const float*)d_in[5];
  const float* e_ln1_w = (const float*)d_in[6];
  const float* e_ln1_b = (const float*)d_in[7];
  const float* e_ff1_w = (const float*)d_in[8];
  const float* e_ff1_b = (const float*)d_in[9];
  const float* e_ff2_w = (const float*)d_in[10];
  const float* e_ff2_b = (const float*)d_in[11];
  const float* e_ln2_w = (const float*)d_in[12];
  const float* e_ln2_b = (const float*)d_in[13];
  const float* c1w = (const float*)d_in[14];
  const float* c1b = (const float*)d_in[15];
  const float* l1w = (const float*)d_in[16];
  const float* l1b = (const float*)d_in[17];
  const float* c2w = (const float*)d_in[18];
  const float* c2b = (const float*)d_in[19];
  const float* l2w = (const float*)d_in[20];
  const float* l2b = (const float*)d_in[21];
  const float* linw = (const float*)d_in[22];
  const float* linb = (const float*)d_in[23];
  const float* d_sa_qkv_w = (const float*)d_in[24];
  const float* d_sa_qkv_b = (const float*)d_in[25];
  const float* d_sa_out_w = (const float*)d_in[26];
  const float* d_sa_out_b = (const float*)d_in[27];
  const float* d_ca_qkv_w = (const float*)d_in[28];
  const float* d_ca_qkv_b = (const float*)d_in[29];
  const float* d_ca_out_w = (const float*)d_in[30];
  const float* d_ca_out_b = (const float*)d_in[31];
  const float* d_ln1_w = (const float*)d_in[32];
  const float* d_ln1_b = (const float*)d_in[33];
  const float* d_ln2_w = (const float*)d_in[34];
  const float* d_ln2_b = (const float*)d_in[35];
  const float* d_ln3_w = (const float*)d_in[36];
  const float* d_ln3_b = (const float*)d_in[37];
  const float* d_ff1_w = (const float*)d_in[38];
  const float* d_ff1_b = (const float*)d_in[39];
  const float* d_ff2_w = (const float*)d_in[40];
  const float* d_ff2_b = (const float*)d_in[41];
  const float* melw = (const float*)d_in[42];
  const float* melb = (const float*)d_in[43];
  float* out = (float*)d_out;   // f32: mel | duration | pitch | energy

  // ---- arena ----
  char* p = (char*)d_ws;
  float* Y   = (float*)p;            p += 8388608ull * 4;    // (B,1024,256) f32
  float* ENC = (float*)p;            p += 2097152ull * 4;    // (B,256,256) f32
  unsigned short* ENCbf = (unsigned short*)p; p += 2097152ull * 2;
  unsigned short* Wsaqkv = (unsigned short*)p; p += 786432ull * 2;
  unsigned short* Wsaout = (unsigned short*)p; p += 262144ull * 2;
  unsigned short* Wcaqkv = (unsigned short*)p; p += 786432ull * 2;
  unsigned short* Wcaout = (unsigned short*)p; p += 262144ull * 2;
  unsigned short* Wff1   = (unsigned short*)p; p += 1048576ull * 2;
  unsigned short* Wff2   = (unsigned short*)p; p += 1048576ull * 2;
  float* DUR = (float*)p;            p += 24576ull * 4;
  int* TOK   = (int*)p;              p += 32768ull * 4;
  int* MAXL  = (int*)p;              p += 4096;
  size_t fixed_b = (size_t)(p - (char*)d_ws);

  int grp = 1;
  {
    const int cand[6] = {32, 16, 8, 4, 2, 1};
    for (int c = 0; c < 6; ++c) {
      if (fixed_b + (size_t)cand[c] * 1835008ull * 2 <= ws_size) { grp = cand[c]; break; }
    }
  }
  unsigned short* REG = (unsigned short*)p;            // grouped region (bf16)
  unsigned short* Ybf   = REG;
  unsigned short* ADDbf = REG + (size_t)grp * 262144;
  unsigned short* AObf  = REG + (size_t)grp * 524288;
  unsigned short* UN    = REG + (size_t)grp * 786432;
  int grp_e = grp * 2 > 32 ? 32 : grp * 2;
  float* P0e = (float*)REG;
  float* P1e = P0e + (size_t)grp_e * 262144;
  float* P2e = P1e + (size_t)grp_e * 65536;
  float* ENCT = Y;            // vpred scratch in dead Y region
  float* H1   = Y + 2097152;
  float* H2   = Y + 4194304;
  float* MEL  = ENC;          // (B*1024, 80) f32 — ENC dead at mel time

  auto gemm = [&](const float* A, const float* W, const float* bias, float* C,
                  int M, int N, int K, int epi) {
    dim3 g((M + 63) / 64, (N + 63) / 64);
    gemm_k<<<g, dim3(256), 0, stream>>>(A, W, bias, C, M, N, K, epi);
  };
  auto gemm2 = [&](const float* A, const float* W, const float* bias, float* C,
                   int M, int N, int K, int epi) {
    dim3 g(M / 128, N / 128);
    gemm2_k<<<g, dim3(256), 0, stream>>>(A, W, bias, C, M, N, K, epi);
  };
  auto gemm_bf = [&](const unsigned short* A, const unsigned short* W, const float* bias,
                     unsigned short* C, int M, int N, int K, int epi) {
    dim3 g(M / 128, N / 128);
    gemm_bf_k<<<g, dim3(256), 0, stream>>>(A, W, bias, C, M, N, K, epi);
  };
  auto addln = [&](const float* X, const float* R, const float* w, const float* b,
                   float* O, int rows) {
    addln_k<<<dim3((rows + 3) / 4), dim3(256), 0, stream>>>(X, R, w, b, O, rows);
  };
  auto addln2 = [&](const float* X, const unsigned short* Rbf, const float* w, const float* b,
                    float* O, unsigned short* Obf, int rows) {
    addln2_k<<<dim3((rows + 3) / 4), dim3(256), 0, stream>>>(X, Rbf, w, b, O, Obf, rows);
  };
  auto cvt = [&](const float* in, unsigned short* o, int n) {
    cvt_k<<<dim3(n / 1024), dim3(256), 0, stream>>>(in, o, n);
  };

  // ---- convert decoder weights to bf16 (once) ----
  cvt(d_sa_qkv_w, Wsaqkv, 786432);
  cvt(d_sa_out_w, Wsaout, 262144);
  cvt(d_ca_qkv_w, Wcaqkv, 786432);
  cvt(d_ca_out_w, Wcaout, 262144);
  cvt(d_ff1_w, Wff1, 1048576);
  cvt(d_ff2_w, Wff2, 1048576);

  // ================= encoder (fp32, gemm2) =================
  for (int i = 0; i < 4; ++i) {
    for (int g0 = 0; g0 < B_; g0 += grp_e) {
      int rows = grp_e * T_;
      const size_t off = (size_t)g0 * T_ * D_;
      const float* xin = (i == 0) ? te + off : ENC + off;
      gemm2(xin, e_qkv_w + (size_t)i * 196608, e_qkv_b + i * 768, P0e, rows, 768, 256, 0);
      attn_k<<<dim3(T_ / 64, NH_, grp_e), dim3(256), 0, stream>>>(
          P0e, 768, P0e + 256, 768, P0e + 512, 768, P1e, T_, T_, lens + g0);
      gemm2(P1e, e_out_w + (size_t)i * 65536, e_out_b + i * 256, P2e, rows, 256, 256, 0);
      addln(xin, P2e, e_ln1_w + i * 256, e_ln1_b + i * 256, ENC + off, rows);
      gemm2(ENC + off, e_ff1_w + (size_t)i * 262144, e_ff1_b + i * 1024, P0e, rows, 1024, 256, 1);
      gemm2(P0e, e_ff2_w + (size_t)i * 262144, e_ff2_b + i * 256, P2e, rows, 256, 1024, 0);
      addln(ENC + off, P2e, e_ln2_w + i * 256, e_ln2_b + i * 256, ENC + off, rows);
    }
  }
  cvt(ENC, ENCbf, 2097152);

  // ================= variance predictors (fp32) =================
  transp_k<<<dim3(8, 8, B_), dim3(32, 8), 0, stream>>>(ENC, ENCT);
  for (int j = 0; j < 3; ++j) {
    conv_k<<<dim3(4, 4, B_), dim3(256), 0, stream>>>(
        ENCT, c1w + (size_t)j * 196608, c1b + j * 256, H1, 1);
    addln(H1, nullptr, l1w + j * 256, l1b + j * 256, H1, B_ * T_);
    conv_k<<<dim3(4, 4, B_), dim3(256), 0, stream>>>(
        H1, c2w + (size_t)j * 196608, c2b + j * 256, H2, 1);
    addln(H2, nullptr, l2w + j * 256, l2b + j * 256, H2, B_ * T_);
    rowdot_k<<<dim3(B_ * T_ / 4), dim3(256), 0, stream>>>(
        H2, linw + j * 256, linb + j, DUR + (size_t)j * 8192,
        out + 2621440 + (size_t)j * 8192, B_ * T_);
  }

  // ================= length regulator =================
  maxlen_k<<<dim3(1), dim3(256), 0, stream>>>(DUR, MAXL);
  reg_k<<<dim3(B_), dim3(256), 0, stream>>>(DUR, lens, MAXL, TOK);
  gather_k<<<dim3(B_ * MAXBUF_), dim3(64), 0, stream>>>(ENC, TOK, Y);

  // ================= decoder (bf16 MFMA) =================
  for (int i = 0; i < 4; ++i) {
    for (int g0 = 0; g0 < B_; g0 += grp) {
      int rows = grp * MAXBUF_;
      float* Yg = Y + (size_t)g0 * MAXBUF_ * D_;
      if (i == 0 || grp != B_)    // Ybf stays current across layers when grp==B
        cvt(Yg, Ybf, rows * 256);
      // self-attention
      gemm_bf(Ybf, Wsaqkv + (size_t)i * 196608, d_sa_qkv_b + i * 768, UN, rows, 768, 256, 0);
      attn_bf_k<<<dim3(MAXBUF_ / 64, NH_, grp), dim3(256), 0, stream>>>(
          UN, 768, UN + 256, 768, UN + 512, 768, AObf, MAXBUF_, MAXBUF_);
      gemm_bf(AObf, Wsaout + (size_t)i * 65536, d_sa_out_b + i * 256, ADDbf, rows, 256, 256, 0);
      addln2(Yg, ADDbf, d_ln1_w + i * 256, d_ln1_b + i * 256, Yg, Ybf, rows);
      // cross-attention
      gemm_bf(Ybf, Wcaqkv + (size_t)i * 196608, d_ca_qkv_b + i * 768, UN, rows, 256, 256, 0);
      gemm_bf(ENCbf + (size_t)g0 * 65536, Wcaqkv + (size_t)i * 196608 + 65536,
              d_ca_qkv_b + i * 768 + 256, UN + (size_t)grp * 262144, grp * T_, 512, 256, 0);
      attn_bf_k<<<dim3(MAXBUF_ / 64, NH_, grp), dim3(256), 0, stream>>>(
          UN, 256, UN + (size_t)grp * 262144, 512, UN + (size_t)grp * 262144 + 256, 512,
          AObf, MAXBUF_, T_);
      gemm_bf(AObf, Wcaout + (size_t)i * 65536, d_ca_out_b + i * 256, ADDbf, rows, 256, 256, 0);
      addln2(Yg, ADDbf, d_ln2_w + i * 256, d_ln2_b + i * 256, Yg, Ybf, rows);
      // feed-forward
      gemm_bf(Ybf, Wff1 + (size_t)i * 262144, d_ff1_b + i * 1024, UN, rows, 1024, 256, 1);
      gemm_bf(UN, Wff2 + (size_t)i * 262144, d_ff2_b + i * 256, ADDbf, rows, 256, 1024, 0);
      addln2(Yg, ADDbf, d_ln3_w + i * 256, d_ln3_b + i * 256, Yg, Ybf, rows);
    }
  }

  // ================= mel head: gemm + transpose =================
  gemm(Y, melw, melb, MEL, B_ * MAXBUF_, NMEL_, 256, 0);
  meltr_k<<<dim3(16, 5, B_), dim3(256), 0, stream>>>(MEL, out);
}

// Round 8
// 3452.918 us; speedup vs baseline: 1.1416x; 1.0343x over previous
//
#include <hip/hip_runtime.h>
#include <hip/hip_bf16.h>
#include <cstdint>
#include <cstddef>

// ============================================================================
// FastSpeech2 forward on MI355X. Round 8: decoder attention overhaul.
//  r7 counters: attn_bf_k VALUBusy 70%, MfmaUtil 8.8%, conflicts 0 ->
//  VALU/LDS-op bound. Root causes: (a) per-block scalar V-transpose staging
//  (16 ds_write_b16/thread/tile) re-done 16x per (b,h,kt) tile across
//  Q-blocks; (b) libm expf; (c) 64-row Q tiles re-stage K/V 16x.
//  Fixes: global V^T (trv_k, once per layer), Q-tile 128 (2x K/V reuse),
//  __expf + s_setprio(1) around MFMA (decoder only; duration path untouched).
// ============================================================================

#define B_ 32
#define T_ 256
#define D_ 256
#define NH_ 4
#define FF_ 1024
#define MAXBUF_ 1024
#define NMEL_ 80

typedef __attribute__((ext_vector_type(8))) short short8;
typedef __attribute__((ext_vector_type(4))) float f32x4;

__device__ __forceinline__ unsigned short f2bf(float x) {
  unsigned int u = __float_as_uint(x);
  return (unsigned short)((u + 0x7fffu + ((u >> 16) & 1u)) >> 16);
}
__device__ __forceinline__ float bf2f(unsigned short h) {
  return __uint_as_float(((unsigned int)h) << 16);
}

#define GLD16(g, s)                                                         \
  __builtin_amdgcn_global_load_lds(                                         \
      (__attribute__((address_space(1))) void*)(g),                         \
      (__attribute__((address_space(3))) void*)(s), 16, 0, 0)

// ---------------------------------------------------------------------------
// fp32 GEMM, 64x64 tile (bounds-safe; used for mel N=80).
// ---------------------------------------------------------------------------
__global__ __launch_bounds__(256) void gemm_k(
    const float* __restrict__ A, const float* __restrict__ W,
    const float* __restrict__ bias, float* __restrict__ C,
    int M, int N, int K, int epi)
{
  __shared__ float As[16][64];
  __shared__ float Ws[16][64];
  const int tid = threadIdx.x;
  const int tx = tid & 15, ty = tid >> 4;
  const int bm = blockIdx.x * 64, bn = blockIdx.y * 64;
  const int lm = tid & 63, lk = tid >> 6;
  float acc[4][4] = {{0.f,0.f,0.f,0.f},{0.f,0.f,0.f,0.f},{0.f,0.f,0.f,0.f},{0.f,0.f,0.f,0.f}};
  const bool aok = (bm + lm) < M;
  const bool wok = (bn + lm) < N;
  const float* Ap = A + (size_t)(bm + lm) * K + lk * 4;
  const float* Wp = W + (size_t)(bn + lm) * K + lk * 4;
  for (int k0 = 0; k0 < K; k0 += 16) {
    float4 av = make_float4(0.f, 0.f, 0.f, 0.f);
    float4 wv = make_float4(0.f, 0.f, 0.f, 0.f);
    if (aok) av = *(const float4*)(Ap + k0);
    if (wok) wv = *(const float4*)(Wp + k0);
    As[lk*4+0][lm] = av.x; As[lk*4+1][lm] = av.y; As[lk*4+2][lm] = av.z; As[lk*4+3][lm] = av.w;
    Ws[lk*4+0][lm] = wv.x; Ws[lk*4+1][lm] = wv.y; Ws[lk*4+2][lm] = wv.z; Ws[lk*4+3][lm] = wv.w;
    __syncthreads();
#pragma unroll
    for (int kk = 0; kk < 16; ++kk) {
      float4 a4 = *(const float4*)&As[kk][ty * 4];
      float4 b4 = *(const float4*)&Ws[kk][tx * 4];
      float aa[4] = {a4.x, a4.y, a4.z, a4.w};
      float bb[4] = {b4.x, b4.y, b4.z, b4.w};
#pragma unroll
      for (int i = 0; i < 4; ++i)
#pragma unroll
        for (int j = 0; j < 4; ++j)
          acc[i][j] += aa[i] * bb[j];
    }
    __syncthreads();
  }
#pragma unroll
  for (int i = 0; i < 4; ++i) {
    int gm = bm + ty * 4 + i;
    if (gm >= M) continue;
#pragma unroll
    for (int j = 0; j < 4; ++j) {
      int gn = bn + tx * 4 + j;
      if (gn >= N) continue;
      float v = acc[i][j] + bias[gn];
      if (epi == 1) v = 0.5f * v * (1.0f + erff(v * 0.70710678118654752f));
      C[(size_t)gm * N + gn] = v;
    }
  }
}

// ---------------------------------------------------------------------------
// fp32 GEMM, 128x128 tile, 8x8 micro with f32x4 accumulators (NO SPILL).
// ---------------------------------------------------------------------------
__global__ __launch_bounds__(256, 2) void gemm2_k(
    const float* __restrict__ A, const float* __restrict__ W,
    const float* __restrict__ bias, float* __restrict__ C,
    int M, int N, int K, int epi)
{
  __shared__ float As[16][128];
  __shared__ float Bs[16][128];
  const int tid = threadIdx.x;
  const int tx = tid & 15, ty = tid >> 4;
  const int bm = blockIdx.x * 128, bn = blockIdx.y * 128;
  const int r = tid & 127, ks = (tid >> 7) * 8;
  f32x4 acc[8][2];
#pragma unroll
  for (int i = 0; i < 8; ++i) {
    acc[i][0] = (f32x4){0.f, 0.f, 0.f, 0.f};
    acc[i][1] = (f32x4){0.f, 0.f, 0.f, 0.f};
  }
  const float* Ap = A + (size_t)(bm + r) * K + ks;
  const float* Wp = W + (size_t)(bn + r) * K + ks;
  for (int k0 = 0; k0 < K; k0 += 16) {
    float4 a0 = *(const float4*)(Ap + k0);
    float4 a1 = *(const float4*)(Ap + k0 + 4);
    float4 w0 = *(const float4*)(Wp + k0);
    float4 w1 = *(const float4*)(Wp + k0 + 4);
    __syncthreads();
    As[ks+0][r] = a0.x; As[ks+1][r] = a0.y; As[ks+2][r] = a0.z; As[ks+3][r] = a0.w;
    As[ks+4][r] = a1.x; As[ks+5][r] = a1.y; As[ks+6][r] = a1.z; As[ks+7][r] = a1.w;
    Bs[ks+0][r] = w0.x; Bs[ks+1][r] = w0.y; Bs[ks+2][r] = w0.z; Bs[ks+3][r] = w0.w;
    Bs[ks+4][r] = w1.x; Bs[ks+5][r] = w1.y; Bs[ks+6][r] = w1.z; Bs[ks+7][r] = w1.w;
    __syncthreads();
#pragma unroll
    for (int kk = 0; kk < 16; ++kk) {
      f32x4 bA = *(const f32x4*)&Bs[kk][tx * 4];
      f32x4 bB = *(const f32x4*)&Bs[kk][tx * 4 + 64];
      float4 aA = *(const float4*)&As[kk][ty * 4];
      float4 aB = *(const float4*)&As[kk][ty * 4 + 64];
      float av[8] = {aA.x, aA.y, aA.z, aA.w, aB.x, aB.y, aB.z, aB.w};
#pragma unroll
      for (int i = 0; i < 8; ++i) {
        acc[i][0] += bA * av[i];
        acc[i][1] += bB * av[i];
      }
    }
  }
#pragma unroll
  for (int i = 0; i < 8; ++i) {
    int gm = bm + (i >> 2) * 64 + ty * 4 + (i & 3);
#pragma unroll
    for (int half = 0; half < 2; ++half) {
      int gn = bn + half * 64 + tx * 4;
      float4 o;
      o.x = acc[i][half][0] + bias[gn + 0];
      o.y = acc[i][half][1] + bias[gn + 1];
      o.z = acc[i][half][2] + bias[gn + 2];
      o.w = acc[i][half][3] + bias[gn + 3];
      if (epi == 1) {
        o.x = 0.5f * o.x * (1.0f + erff(o.x * 0.70710678118654752f));
        o.y = 0.5f * o.y * (1.0f + erff(o.y * 0.70710678118654752f));
        o.z = 0.5f * o.z * (1.0f + erff(o.z * 0.70710678118654752f));
        o.w = 0.5f * o.w * (1.0f + erff(o.w * 0.70710678118654752f));
      }
      *(float4*)(C + (size_t)gm * N + gn) = o;
    }
  }
}

// ---------------------------------------------------------------------------
// fp32 flash attention (encoder only) — unchanged (duration path).
// ---------------------------------------------------------------------------
__global__ __launch_bounds__(256) void attn_k(
    const float* __restrict__ Qp, int qStride,
    const float* __restrict__ Kp, int kStride,
    const float* __restrict__ Vp, int vStride,
    float* __restrict__ Op, int Tq, int Tkv,
    const int* __restrict__ lengths)
{
  const int b = blockIdx.z, h = blockIdx.y, qt = blockIdx.x;
  const int tid = threadIdx.x;
  const int tx = tid & 15, ty = tid >> 4;
  const int lr = tid & 63, lq = tid >> 6;

  __shared__ float Qs[64][64];
  __shared__ float KT[64][64];
  __shared__ float Sm[64][65];

  {
    const float* q = Qp + (size_t)(b * Tq + qt * 64 + lr) * qStride + h * 64 + lq * 16;
    float4 v0 = ((const float4*)q)[0];
    float4 v1 = ((const float4*)q)[1];
    float4 v2 = ((const float4*)q)[2];
    float4 v3 = ((const float4*)q)[3];
    *(float4*)&Qs[lr][lq*16 + 0]  = v0;
    *(float4*)&Qs[lr][lq*16 + 4]  = v1;
    *(float4*)&Qs[lr][lq*16 + 8]  = v2;
    *(float4*)&Qs[lr][lq*16 + 12] = v3;
  }

  float m_reg[4], l_reg[4], o[4][4];
#pragma unroll
  for (int i = 0; i < 4; ++i) {
    m_reg[i] = -INFINITY; l_reg[i] = 0.f;
#pragma unroll
    for (int j = 0; j < 4; ++j) o[i][j] = 0.f;
  }

  const int len_b = lengths ? lengths[b] : 0x7fffffff;
  const int nkt = Tkv >> 6;

  for (int kt = 0; kt < nkt; ++kt) {
    __syncthreads();
    {
      const float* kp = Kp + (size_t)(b * Tkv + kt * 64 + lr) * kStride + h * 64 + lq * 16;
      float4 v[4];
      v[0] = ((const float4*)kp)[0]; v[1] = ((const float4*)kp)[1];
      v[2] = ((const float4*)kp)[2]; v[3] = ((const float4*)kp)[3];
#pragma unroll
      for (int u = 0; u < 4; ++u) {
        KT[lq*16 + u*4 + 0][lr] = v[u].x;
        KT[lq*16 + u*4 + 1][lr] = v[u].y;
        KT[lq*16 + u*4 + 2][lr] = v[u].z;
        KT[lq*16 + u*4 + 3][lr] = v[u].w;
      }
    }
    __syncthreads();

    float s[4][4] = {{0.f,0.f,0.f,0.f},{0.f,0.f,0.f,0.f},{0.f,0.f,0.f,0.f},{0.f,0.f,0.f,0.f}};
#pragma unroll
    for (int d4 = 0; d4 < 16; ++d4) {
      float4 qv[4], kv[4];
#pragma unroll
      for (int i = 0; i < 4; ++i) qv[i] = *(const float4*)&Qs[ty*4 + i][d4*4];
#pragma unroll
      for (int dd = 0; dd < 4; ++dd) kv[dd] = *(const float4*)&KT[d4*4 + dd][tx*4];
#pragma unroll
      for (int i = 0; i < 4; ++i) {
        s[i][0] += qv[i].x*kv[0].x + qv[i].y*kv[1].x + qv[i].z*kv[2].x + qv[i].w*kv[3].x;
        s[i][1] += qv[i].x*kv[0].y + qv[i].y*kv[1].y + qv[i].z*kv[2].y + qv[i].w*kv[3].y;
        s[i][2] += qv[i].x*kv[0].z + qv[i].y*kv[1].z + qv[i].z*kv[2].z + qv[i].w*kv[3].z;
        s[i][3] += qv[i].x*kv[0].w + qv[i].y*kv[1].w + qv[i].z*kv[2].w + qv[i].w*kv[3].w;
      }
    }

    float alpha[4];
#pragma unroll
    for (int i = 0; i < 4; ++i) {
      float pm = -INFINITY;
#pragma unroll
      for (int j = 0; j < 4; ++j) {
        int kg = kt * 64 + tx * 4 + j;
        float v = s[i][j] * 0.125f;
        if (kg >= len_b) v = -1e9f;
        s[i][j] = v;
        pm = fmaxf(pm, v);
      }
#pragma unroll
      for (int off = 1; off < 16; off <<= 1) pm = fmaxf(pm, __shfl_xor(pm, off));
      float mn = fmaxf(m_reg[i], pm);
      alpha[i] = expf(m_reg[i] - mn);
      float ls = 0.f;
#pragma unroll
      for (int j = 0; j < 4; ++j) {
        float p = expf(s[i][j] - mn);
        Sm[ty*4 + i][tx*4 + j] = p;
        ls += p;
      }
#pragma unroll
      for (int off = 1; off < 16; off <<= 1) ls += __shfl_xor(ls, off);
      l_reg[i] = l_reg[i] * alpha[i] + ls;
      m_reg[i] = mn;
    }
    __syncthreads();

    {
      const float* vp = Vp + (size_t)(b * Tkv + kt * 64 + lr) * vStride + h * 64 + lq * 16;
      float4 v0 = ((const float4*)vp)[0];
      float4 v1 = ((const float4*)vp)[1];
      float4 v2 = ((const float4*)vp)[2];
      float4 v3 = ((const float4*)vp)[3];
      *(float4*)&KT[lr][lq*16 + 0]  = v0;
      *(float4*)&KT[lr][lq*16 + 4]  = v1;
      *(float4*)&KT[lr][lq*16 + 8]  = v2;
      *(float4*)&KT[lr][lq*16 + 12] = v3;
    }
    __syncthreads();

#pragma unroll
    for (int i = 0; i < 4; ++i) {
      o[i][0] *= alpha[i]; o[i][1] *= alpha[i]; o[i][2] *= alpha[i]; o[i][3] *= alpha[i];
    }
#pragma unroll 8
    for (int c = 0; c < 64; ++c) {
      float4 vv = *(const float4*)&KT[c][tx * 4];
#pragma unroll
      for (int i = 0; i < 4; ++i) {
        float p = Sm[ty*4 + i][c];
        o[i][0] += p * vv.x; o[i][1] += p * vv.y; o[i][2] += p * vv.z; o[i][3] += p * vv.w;
      }
    }
  }

#pragma unroll
  for (int i = 0; i < 4; ++i) {
    float inv = 1.f / l_reg[i];
    float4 r;
    r.x = o[i][0] * inv; r.y = o[i][1] * inv; r.z = o[i][2] * inv; r.w = o[i][3] * inv;
    *(float4*)(Op + (size_t)(b * Tq + qt * 64 + ty * 4 + i) * 256 + h * 64 + tx * 4) = r;
  }
}

// ---------------------------------------------------------------------------
// bf16 MFMA GEMM — unchanged.
// ---------------------------------------------------------------------------
__global__ __launch_bounds__(256) void gemm_bf_k(
    const unsigned short* __restrict__ A, const unsigned short* __restrict__ W,
    const float* __restrict__ bias, unsigned short* __restrict__ C,
    int M, int N, int K, int epi)
{
  __shared__ __align__(16) short As[128 * 32];
  __shared__ __align__(16) short Bs[128 * 32];
  const int tid = threadIdx.x;
  const int lane = tid & 63, w = tid >> 6;
  const int g = lane >> 4, li = lane & 15;
  const int wr = (w >> 1) * 64, wc = (w & 1) * 64;
  const int bm = blockIdx.x * 128, bn = blockIdx.y * 128;

  f32x4 acc[4][4];
#pragma unroll
  for (int m = 0; m < 4; ++m)
#pragma unroll
    for (int n = 0; n < 4; ++n)
      acc[m][n] = (f32x4){0.f, 0.f, 0.f, 0.f};

  const int srow = tid >> 2, scol = (tid & 3) * 8;
  const unsigned short* Ag = A + (size_t)(bm + srow) * K + scol;
  const unsigned short* Wg = W + (size_t)(bn + srow) * K + scol;

  for (int k0 = 0; k0 < K; k0 += 32) {
    __syncthreads();
    GLD16(Ag + k0, &As[tid * 8]);
    GLD16(Ag + k0 + (size_t)64 * K, &As[tid * 8 + 2048]);
    GLD16(Wg + k0, &Bs[tid * 8]);
    GLD16(Wg + k0 + (size_t)64 * K, &Bs[tid * 8 + 2048]);
    __syncthreads();
    short8 af[4], bf[4];
#pragma unroll
    for (int m = 0; m < 4; ++m) af[m] = *(const short8*)&As[(wr + m * 16 + li) * 32 + g * 8];
#pragma unroll
    for (int n = 0; n < 4; ++n) bf[n] = *(const short8*)&Bs[(wc + n * 16 + li) * 32 + g * 8];
#pragma unroll
    for (int m = 0; m < 4; ++m)
#pragma unroll
      for (int n = 0; n < 4; ++n)
        acc[m][n] = __builtin_amdgcn_mfma_f32_16x16x32_bf16(af[m], bf[n], acc[m][n], 0, 0, 0);
  }

#pragma unroll
  for (int m = 0; m < 4; ++m) {
#pragma unroll
    for (int n = 0; n < 4; ++n) {
      int col = bn + wc + n * 16 + li;
      float bv = bias[col];
#pragma unroll
      for (int r = 0; r < 4; ++r) {
        int row = bm + wr + m * 16 + g * 4 + r;
        float v = acc[m][n][r] + bv;
        if (epi == 1) v = 0.5f * v * (1.0f + erff(v * 0.70710678118654752f));
        C[(size_t)row * N + col] = f2bf(v);
      }
    }
  }
}

// ---------------------------------------------------------------------------
// V transpose to global: VT[(b*NH+h)*64 + d][k] from V rows at stride.
// Done ONCE per layer (was re-done 16x inside attention blocks).
// ---------------------------------------------------------------------------
__global__ __launch_bounds__(256) void trv_k(
    const unsigned short* __restrict__ V, int vStride,
    unsigned short* __restrict__ VT, int Tkv)
{
  const int kt = blockIdx.x, h = blockIdx.y, b = blockIdx.z;
  __shared__ short t[64][65];
  const int tid = threadIdx.x;
  const int r0 = tid >> 3, seg = tid & 7;
#pragma unroll
  for (int i = 0; i < 2; ++i) {
    int r = r0 + i * 32;
    short8 v = *(const short8*)(V + (size_t)(b * Tkv + kt * 64 + r) * vStride + h * 64 + seg * 8);
    *(short8*)&t[r][seg * 8] = v;
  }
  __syncthreads();
#pragma unroll
  for (int i = 0; i < 2; ++i) {
    int d = r0 + i * 32;
    int k0 = seg * 8;
    short o[8];
#pragma unroll
    for (int j = 0; j < 8; ++j) o[j] = t[k0 + j][d];
    *(short8*)(VT + ((size_t)(b * NH_ + h) * 64 + d) * Tkv + kt * 64 + k0) = *(short8*)o;
  }
}

// ---------------------------------------------------------------------------
// bf16 MFMA flash attention. Q-tile 128 (4 waves x 32 rows). K and V^T tiles
// staged vectorized+swizzled; V^T from trv_k's global buffer. __expf, setprio.
// XCD-aware remap so blocks sharing (b,h) K/V stay on one XCD's L2.
// ---------------------------------------------------------------------------
__global__ __launch_bounds__(256, 2) void attn_bf_k(
    const unsigned short* __restrict__ Qp, int qStride,
    const unsigned short* __restrict__ Kp, int kStride,
    const unsigned short* __restrict__ VTg,   // [(b*NH+h)*64 + d][Tkv]
    unsigned short* __restrict__ Op, int Tq, int Tkv)
{
  int b, h, qt;
  {
    const int nqt = gridDim.x, nh = gridDim.y, nbh = gridDim.y * gridDim.z;
    if ((nbh & 7) == 0) {
      int linear = blockIdx.x + nqt * (blockIdx.y + gridDim.y * blockIdx.z);
      int xcd = linear & 7, idx = linear >> 3;
      int bh = xcd * (nbh >> 3) + idx / nqt;
      qt = idx - (idx / nqt) * nqt;
      h = bh % nh; b = bh / nh;
    } else { qt = blockIdx.x; h = blockIdx.y; b = blockIdx.z; }
  }
  const int tid = threadIdx.x;
  const int lane = tid & 63, w = tid >> 6;
  const int g = lane >> 4, li = lane & 15;

  __shared__ __align__(16) short Qs[128 * 64];
  __shared__ __align__(16) short Ks[64 * 64];
  __shared__ __align__(16) short VTs[64 * 64];
  __shared__ __align__(16) short Ps[128 * 64];

  { // stage Q tile (128 rows)
    const int r0 = tid >> 3, seg = tid & 7;
#pragma unroll
    for (int i = 0; i < 4; ++i) {
      int r = r0 + i * 32;
      short8 v = *(const short8*)(Qp + (size_t)(b * Tq + qt * 128 + r) * qStride + h * 64 + seg * 8);
      *(short8*)&Qs[r * 64 + ((seg ^ (r & 7)) << 3)] = v;
    }
  }
  __syncthreads();

  short8 aq[2][2];
#pragma unroll
  for (int m = 0; m < 2; ++m)
#pragma unroll
    for (int ks = 0; ks < 2; ++ks) {
      int row = w * 32 + m * 16 + li;
      aq[m][ks] = *(const short8*)&Qs[row * 64 + (((ks * 4 + g) ^ (row & 7)) << 3)];
    }

  float m_reg[2][4], l_reg[2][4];
  f32x4 o[2][4];
#pragma unroll
  for (int m = 0; m < 2; ++m)
#pragma unroll
    for (int r = 0; r < 4; ++r) { m_reg[m][r] = -INFINITY; l_reg[m][r] = 0.f; }
#pragma unroll
  for (int m = 0; m < 2; ++m)
#pragma unroll
    for (int n = 0; n < 4; ++n) o[m][n] = (f32x4){0.f, 0.f, 0.f, 0.f};

  const int nkt = Tkv >> 6;
  const unsigned short* vt = VTg + (size_t)(b * NH_ + h) * 64 * Tkv;
  for (int kt = 0; kt < nkt; ++kt) {
    __syncthreads();
    { // stage K rows + V^T rows, both vectorized + swizzled
      const int r0 = tid >> 3, seg = tid & 7;
#pragma unroll
      for (int i = 0; i < 2; ++i) {
        int r = r0 + i * 32;
        short8 kv = *(const short8*)(Kp + (size_t)(b * Tkv + kt * 64 + r) * kStride + h * 64 + seg * 8);
        *(short8*)&Ks[r * 64 + ((seg ^ (r & 7)) << 3)] = kv;
        short8 vv = *(const short8*)(vt + (size_t)r * Tkv + kt * 64 + seg * 8);
        *(short8*)&VTs[r * 64 + ((seg ^ (r & 7)) << 3)] = vv;
      }
    }
    __syncthreads();

    // S = Q K^T
    f32x4 s[2][4];
    __builtin_amdgcn_s_setprio(1);
#pragma unroll
    for (int m = 0; m < 2; ++m)
#pragma unroll
      for (int n = 0; n < 4; ++n) {
        f32x4 acc = (f32x4){0.f, 0.f, 0.f, 0.f};
#pragma unroll
        for (int ks = 0; ks < 2; ++ks) {
          int key = n * 16 + li;
          short8 bk = *(const short8*)&Ks[key * 64 + (((ks * 4 + g) ^ (key & 7)) << 3)];
          acc = __builtin_amdgcn_mfma_f32_16x16x32_bf16(aq[m][ks], bk, acc, 0, 0, 0);
        }
        s[m][n] = acc * 0.125f;
      }
    __builtin_amdgcn_s_setprio(0);

    // online softmax (own rows only -> no cross-wave hazard on Ps)
    float alpha[2][4];
#pragma unroll
    for (int m = 0; m < 2; ++m)
#pragma unroll
      for (int r = 0; r < 4; ++r) {
        float pm = fmaxf(fmaxf(s[m][0][r], s[m][1][r]), fmaxf(s[m][2][r], s[m][3][r]));
#pragma unroll
        for (int off = 1; off < 16; off <<= 1) pm = fmaxf(pm, __shfl_xor(pm, off));
        float mn = fmaxf(m_reg[m][r], pm);
        alpha[m][r] = __expf(m_reg[m][r] - mn);
        float ls = 0.f;
        int row = w * 32 + m * 16 + g * 4 + r;
#pragma unroll
        for (int n = 0; n < 4; ++n) {
          float p = __expf(s[m][n][r] - mn);
          ls += p;
          int col = n * 16 + li;
          Ps[row * 64 + (col ^ ((row & 7) << 3))] = (short)f2bf(p);
        }
#pragma unroll
        for (int off = 1; off < 16; off <<= 1) ls += __shfl_xor(ls, off);
        l_reg[m][r] = l_reg[m][r] * alpha[m][r] + ls;
        m_reg[m][r] = mn;
      }

    // PV
#pragma unroll
    for (int m = 0; m < 2; ++m) {
      f32x4 al = (f32x4){alpha[m][0], alpha[m][1], alpha[m][2], alpha[m][3]};
#pragma unroll
      for (int n = 0; n < 4; ++n) o[m][n] *= al;
    }
    short8 ap[2][2];
#pragma unroll
    for (int m = 0; m < 2; ++m)
#pragma unroll
      for (int ks = 0; ks < 2; ++ks) {
        int row = w * 32 + m * 16 + li;
        ap[m][ks] = *(const short8*)&Ps[row * 64 + (((ks * 4 + g) ^ (row & 7)) << 3)];
      }
    __builtin_amdgcn_s_setprio(1);
#pragma unroll
    for (int m = 0; m < 2; ++m)
#pragma unroll
      for (int n = 0; n < 4; ++n)
#pragma unroll
        for (int ks = 0; ks < 2; ++ks) {
          int d = n * 16 + li;
          short8 bv = *(const short8*)&VTs[d * 64 + (((ks * 4 + g) ^ (d & 7)) << 3)];
          o[m][n] = __builtin_amdgcn_mfma_f32_16x16x32_bf16(ap[m][ks], bv, o[m][n], 0, 0, 0);
        }
    __builtin_amdgcn_s_setprio(0);
  }

#pragma unroll
  for (int m = 0; m < 2; ++m)
#pragma unroll
    for (int n = 0; n < 4; ++n)
#pragma unroll
      for (int r = 0; r < 4; ++r) {
        float v = o[m][n][r] / l_reg[m][r];
        Op[(size_t)(b * Tq + qt * 128 + w * 32 + m * 16 + g * 4 + r) * 256 + h * 64 + n * 16 + li] = f2bf(v);
      }
}

// LayerNorm f32 — unchanged.
__global__ __launch_bounds__(256) void addln_k(
    const float* __restrict__ X, const float* __restrict__ R,
    const float* __restrict__ w, const float* __restrict__ bias,
    float* __restrict__ Out, int rows)
{
  int tid = threadIdx.x, wv = tid >> 6, ln = tid & 63;
  int row = blockIdx.x * 4 + wv;
  if (row >= rows) return;
  const float* xp = X + (size_t)row * 256;
  float v[4];
#pragma unroll
  for (int u = 0; u < 4; ++u) v[u] = xp[u * 64 + ln];
  if (R) {
    const float* rp = R + (size_t)row * 256;
#pragma unroll
    for (int u = 0; u < 4; ++u) v[u] += rp[u * 64 + ln];
  }
  float s = v[0] + v[1] + v[2] + v[3];
#pragma unroll
  for (int off = 1; off < 64; off <<= 1) s += __shfl_xor(s, off);
  float mean = s * (1.f / 256.f);
  float c[4], sq = 0.f;
#pragma unroll
  for (int u = 0; u < 4; ++u) { c[u] = v[u] - mean; sq += c[u] * c[u]; }
#pragma unroll
  for (int off = 1; off < 64; off <<= 1) sq += __shfl_xor(sq, off);
  float rs = 1.f / sqrtf(sq * (1.f / 256.f) + 1e-5f);
  float* op = Out + (size_t)row * 256;
#pragma unroll
  for (int u = 0; u < 4; ++u)
    op[u * 64 + ln] = c[u] * rs * w[u * 64 + ln] + bias[u * 64 + ln];
}

// LayerNorm + bf16 residual; writes f32 state + bf16 mirror — unchanged.
__global__ __launch_bounds__(256) void addln2_k(
    const float* __restrict__ X, const unsigned short* __restrict__ Rbf,
    const float* __restrict__ w, const float* __restrict__ bias,
    float* __restrict__ Out, unsigned short* __restrict__ OutBf, int rows)
{
  int tid = threadIdx.x, wv = tid >> 6, ln = tid & 63;
  int row = blockIdx.x * 4 + wv;
  if (row >= rows) return;
  const float* xp = X + (size_t)row * 256;
  const unsigned short* rp = Rbf + (size_t)row * 256;
  float v[4];
#pragma unroll
  for (int u = 0; u < 4; ++u) v[u] = xp[u * 64 + ln] + bf2f(rp[u * 64 + ln]);
  float s = v[0] + v[1] + v[2] + v[3];
#pragma unroll
  for (int off = 1; off < 64; off <<= 1) s += __shfl_xor(s, off);
  float mean = s * (1.f / 256.f);
  float c[4], sq = 0.f;
#pragma unroll
  for (int u = 0; u < 4; ++u) { c[u] = v[u] - mean; sq += c[u] * c[u]; }
#pragma unroll
  for (int off = 1; off < 64; off <<= 1) sq += __shfl_xor(sq, off);
  float rs = 1.f / sqrtf(sq * (1.f / 256.f) + 1e-5f);
  float* op = Out + (size_t)row * 256;
  unsigned short* ob = OutBf + (size_t)row * 256;
#pragma unroll
  for (int u = 0; u < 4; ++u) {
    float y = c[u] * rs * w[u * 64 + ln] + bias[u * 64 + ln];
    op[u * 64 + ln] = y;
    ob[u * 64 + ln] = f2bf(y);
  }
}

__global__ void cvt_k(const float* __restrict__ in, unsigned short* __restrict__ out, int n)
{
  int i = (blockIdx.x * 256 + threadIdx.x) * 4;
  if (i >= n) return;
  float4 v = *(const float4*)(in + i);
  unsigned short o[4] = {f2bf(v.x), f2bf(v.y), f2bf(v.z), f2bf(v.w)};
  *(ushort4*)(out + i) = *(ushort4*)o;
}

// Conv1d k=3 pad=1 — unchanged.
__global__ __launch_bounds__(256) void conv_k(
    const float* __restrict__ X, const float* __restrict__ Wt,
    const float* __restrict__ bias, float* __restrict__ Yo, int relu)
{
  const int b = blockIdx.z;
  const int o0 = blockIdx.y * 64, t0 = blockIdx.x * 64;
  const int tid = threadIdx.x, tx = tid & 15, ty = tid >> 4;
  __shared__ float xs[16][66];
  __shared__ float ws_s[64][48];
  float acc[4][4] = {{0.f,0.f,0.f,0.f},{0.f,0.f,0.f,0.f},{0.f,0.f,0.f,0.f},{0.f,0.f,0.f,0.f}};
  for (int i0 = 0; i0 < 256; i0 += 16) {
    for (int idx = tid; idx < 16 * 66; idx += 256) {
      int ic = idx / 66, tt = idx - ic * 66;
      int t = t0 + tt - 1;
      xs[ic][tt] = (t >= 0 && t < 256) ? X[((size_t)b * 256 + (i0 + ic)) * 256 + t] : 0.f;
    }
    for (int f4 = tid; f4 < 768; f4 += 256) {
      int oo = f4 / 12, seg = f4 - oo * 12;
      float4 v = *(const float4*)(Wt + (size_t)(o0 + oo) * 768 + i0 * 3 + seg * 4);
      *(float4*)&ws_s[oo][seg * 4] = v;
    }
    __syncthreads();
#pragma unroll
    for (int ic = 0; ic < 16; ++ic) {
      float xr[6];
#pragma unroll
      for (int u = 0; u < 6; ++u) xr[u] = xs[ic][tx * 4 + u];
#pragma unroll
      for (int i = 0; i < 4; ++i) {
        const float* wr = &ws_s[ty * 4 + i][ic * 3];
        float w0 = wr[0], w1 = wr[1], w2 = wr[2];
#pragma unroll
        for (int j = 0; j < 4; ++j)
          acc[i][j] += w0 * xr[j] + w1 * xr[j + 1] + w2 * xr[j + 2];
      }
    }
    __syncthreads();
  }
#pragma unroll
  for (int i = 0; i < 4; ++i) {
    int oo = o0 + ty * 4 + i;
    float bv = bias[oo];
#pragma unroll
    for (int j = 0; j < 4; ++j) {
      float v = acc[i][j] + bv;
      if (relu) v = fmaxf(v, 0.f);
      Yo[((size_t)b * 256 + oo) * 256 + t0 + tx * 4 + j] = v;
    }
  }
}

__global__ void transp_k(const float* __restrict__ In, float* __restrict__ Out)
{
  int b = blockIdx.z, t0 = blockIdx.x * 32, d0 = blockIdx.y * 32;
  __shared__ float tile[32][33];
  int tx = threadIdx.x, ty = threadIdx.y;
#pragma unroll
  for (int q = 0; q < 4; ++q)
    tile[ty + q * 8][tx] = In[((size_t)b * 256 + t0 + ty + q * 8) * 256 + d0 + tx];
  __syncthreads();
#pragma unroll
  for (int q = 0; q < 4; ++q)
    Out[((size_t)b * 256 + d0 + ty + q * 8) * 256 + t0 + tx] = tile[tx][ty + q * 8];
}

__global__ __launch_bounds__(256) void rowdot_k(
    const float* __restrict__ H, const float* __restrict__ lw,
    const float* __restrict__ lb, float* __restrict__ of32,
    float* __restrict__ oout, int rows)
{
  int tid = threadIdx.x, wv = tid >> 6, ln = tid & 63;
  int row = blockIdx.x * 4 + wv;
  if (row >= rows) return;
  const float* hp = H + (size_t)row * 256;
  float s = 0.f;
#pragma unroll
  for (int u = 0; u < 4; ++u) s += hp[u * 64 + ln] * lw[u * 64 + ln];
#pragma unroll
  for (int off = 1; off < 64; off <<= 1) s += __shfl_xor(s, off);
  if (ln == 0) {
    float v = s + lb[0];
    of32[row] = v;
    oout[row] = v;
  }
}

__global__ void maxlen_k(const float* __restrict__ dur, int* __restrict__ ml)
{
  __shared__ float rnds[32];
  int tid = threadIdx.x, wv = tid >> 6, ln = tid & 63;
  for (int b = wv; b < 32; b += 4) {
    const float* dp = dur + (size_t)b * 256;
    float s = dp[ln] + dp[64 + ln] + dp[128 + ln] + dp[192 + ln];
#pragma unroll
    for (int off = 1; off < 64; off <<= 1) s += __shfl_xor(s, off);
    if (ln == 0) rnds[b] = rintf(s);
  }
  __syncthreads();
  if (tid == 0) {
    float m = rnds[0];
    for (int b = 1; b < 32; ++b) m = fmaxf(m, rnds[b]);
    int v = (int)m;
    v = v < 0 ? 0 : (v > MAXBUF_ ? MAXBUF_ : v);
    *ml = v;
  }
}

__global__ void reg_k(const float* __restrict__ dur, const int* __restrict__ lens,
                      const int* __restrict__ ml, int* __restrict__ tok)
{
  int b = blockIdx.x;
  __shared__ float sdur[256];
  __shared__ int ends[256];
  int tid = threadIdx.x;
  sdur[tid] = dur[(size_t)b * 256 + tid];
  __syncthreads();
  if (tid == 0) {
    int maxlen = *ml, len = lens[b], pos = 0;
    for (int t = 0; t < 256; ++t) {
      int d = (int)rintf(sdur[t]);
      bool ok = (t < len) && (d > 0) && (pos + d <= maxlen);
      if (ok) pos += d;
      ends[t] = pos;
    }
  }
  __syncthreads();
  int total = ends[255];
  for (int f = tid; f < MAXBUF_; f += 256) {
    int lo = 0, hi = 256;
    while (lo < hi) { int mid = (lo + hi) >> 1; if (ends[mid] <= f) lo = mid + 1; else hi = mid; }
    int tc = lo > 255 ? 255 : lo;
    tok[(size_t)b * MAXBUF_ + f] = (f < total) ? tc : -1;
  }
}

__global__ void gather_k(const float* __restrict__ enc, const int* __restrict__ tok,
                         float* __restrict__ Y)
{
  int rf = blockIdx.x;
  int b = rf >> 10;
  int t = tok[rf];
  float4* dst = (float4*)(Y + (size_t)rf * 256);
  int ln = threadIdx.x;
  if (t >= 0) {
    const float4* src = (const float4*)(enc + ((size_t)b * 256 + t) * 256);
    dst[ln] = src[ln];
  } else {
    dst[ln] = make_float4(0.f, 0.f, 0.f, 0.f);
  }
}

// MEL (B*1024, 80) -> out (B, 80, 1024) via LDS tile transpose
__global__ __launch_bounds__(256) void meltr_k(
    const float* __restrict__ MEL, float* __restrict__ out)
{
  int b = blockIdx.z, m0 = blockIdx.y * 16, f0 = blockIdx.x * 64;
  __shared__ float t[16][65];
  int tid = threadIdx.x;
  {
    int f_i = tid >> 4, m_i = tid & 15;
#pragma unroll
    for (int q = 0; q < 4; ++q)
      t[m_i][f_i + q * 16] = MEL[((size_t)b * 1024 + f0 + f_i + q * 16) * 80 + m0 + m_i];
  }
  __syncthreads();
  {
    int f = tid & 63, my = tid >> 6;
#pragma unroll
    for (int q = 0; q < 4; ++q) {
      int m = my * 4 + q;
      out[((size_t)b * NMEL_ + m0 + m) * MAXBUF_ + f0 + f] = t[m][f];
    }
  }
}

// ============================================================================
extern "C" void kernel_launch(void* const* d_in, const int* in_sizes, int n_in,
                              void* d_out, int out_size, void* d_ws, size_t ws_size,
                              hipStream_t stream)
{
  (void)in_sizes; (void)n_in; (void)out_size;

  const float* te   = (const float*)d_in[0];
  const int*   lens = (const int*)d_in[1];
  const float* e_qkv_w = (const float*)d_in[2];
  const float* e_qkv_b = (const float*)d_in[3];
  const float* e_out_w = (const float*)d_in[4];
  const float* e_out_b = (const float*)d_in[5];
  const float* e_ln1_w = (const float*)d_in[6];
  const float* e_ln1_b = (const float*)d_in[7];
  const float* e_ff1_w = (const float*)d_in[8];
  const float* e_ff1_b = (const float*)d_in[9];
  const float* e_ff2_w = (const float*)d_in[10];
  const float* e_ff2_b = (const float*)d_in[11];
  const float* e_ln2_w = (const float*)d_in[12];
  const float* e_ln2_b = (const float*)d_in[13];
  const float* c1w = (const float*)d_in[14];
  const float* c1b = (const float*)d_in[15];
  const float* l1w = (const float*)d_in[16];
  const float* l1b = (const float*)d_in[17];
  const float* c2w = (const float*)d_in[18];
  const float* c2b = (const float*)d_in[19];
  const float* l2w = (const float*)d_in[20];
  const float* l2b = (const float*)d_in[21];
  const float* linw = (const float*)d_in[22];
  const float* linb = (const float*)d_in[23];
  const float* d_sa_qkv_w = (const float*)d_in[24];
  const float* d_sa_qkv_b = (const float*)d_in[25];
  const float* d_sa_out_w = (const float*)d_in[26];
  const float* d_sa_out_b = (const float*)d_in[27];
  const float* d_ca_qkv_w = (const float*)d_in[28];
  const float* d_ca_qkv_b = (const float*)d_in[29];
  const float* d_ca_out_w = (const float*)d_in[30];
  const float* d_ca_out_b = (const float*)d_in[31];
  const float* d_ln1_w = (const float*)d_in[32];
  const float* d_ln1_b = (const float*)d_in[33];
  const float* d_ln2_w = (const float*)d_in[34];
  const float* d_ln2_b = (const float*)d_in[35];
  const float* d_ln3_w = (const float*)d_in[36];
  const float* d_ln3_b = (const float*)d_in[37];
  const float* d_ff1_w = (const float*)d_in[38];
  const float* d_ff1_b = (const float*)d_in[39];
  const float* d_ff2_w = (const float*)d_in[40];
  const float* d_ff2_b = (const float*)d_in[41];
  const float* melw = (const float*)d_in[42];
  const float* melb = (const float*)d_in[43];
  float* out = (float*)d_out;   // f32: mel | duration | pitch | energy

  // ---- arena ----
  char* p = (char*)d_ws;
  float* Y   = (float*)p;            p += 8388608ull * 4;    // (B,1024,256) f32
  float* ENC = (float*)p;            p += 2097152ull * 4;    // (B,256,256) f32
  unsigned short* ENCbf = (unsigned short*)p; p += 2097152ull * 2;
  unsigned short* Wsaqkv = (unsigned short*)p; p += 786432ull * 2;
  unsigned short* Wsaout = (unsigned short*)p; p += 262144ull * 2;
  unsigned short* Wcaqkv = (unsigned short*)p; p += 786432ull * 2;
  unsigned short* Wcaout = (unsigned short*)p; p += 262144ull * 2;
  unsigned short* Wff1   = (unsigned short*)p; p += 1048576ull * 2;
  unsigned short* Wff2   = (unsigned short*)p; p += 1048576ull * 2;
  float* DUR = (float*)p;            p += 24576ull * 4;
  int* TOK   = (int*)p;              p += 32768ull * 4;
  int* MAXL  = (int*)p;              p += 4096;
  size_t fixed_b = (size_t)(p - (char*)d_ws);

  int grp = 1;
  {
    const int cand[6] = {32, 16, 8, 4, 2, 1};
    for (int c = 0; c < 6; ++c) {
      if (fixed_b + (size_t)cand[c] * 1835008ull * 2 <= ws_size) { grp = cand[c]; break; }
    }
  }
  unsigned short* REG = (unsigned short*)p;            // grouped region (bf16)
  unsigned short* Ybf   = REG;
  unsigned short* ADDbf = REG + (size_t)grp * 262144;
  unsigned short* AObf  = REG + (size_t)grp * 524288;
  unsigned short* UN    = REG + (size_t)grp * 786432;  // up to grp*786432
  unsigned short* VTb   = REG + (size_t)grp * 1572864; // grp*262144 (V^T)
  int grp_e = grp * 2 > 32 ? 32 : grp * 2;
  float* P0e = (float*)REG;
  float* P1e = P0e + (size_t)grp_e * 262144;
  float* P2e = P1e + (size_t)grp_e * 65536;
  float* ENCT = Y;            // vpred scratch in dead Y region
  float* H1   = Y + 2097152;
  float* H2   = Y + 4194304;
  float* MEL  = ENC;          // spills into ENCbf region (both dead at mel)

  auto gemm = [&](const float* A, const float* W, const float* bias, float* C,
                  int M, int N, int K, int epi) {
    dim3 g((M + 63) / 64, (N + 63) / 64);
    gemm_k<<<g, dim3(256), 0, stream>>>(A, W, bias, C, M, N, K, epi);
  };
  auto gemm2 = [&](const float* A, const float* W, const float* bias, float* C,
                   int M, int N, int K, int epi) {
    dim3 g(M / 128, N / 128);
    gemm2_k<<<g, dim3(256), 0, stream>>>(A, W, bias, C, M, N, K, epi);
  };
  auto gemm_bf = [&](const unsigned short* A, const unsigned short* W, const float* bias,
                     unsigned short* C, int M, int N, int K, int epi) {
    dim3 g(M / 128, N / 128);
    gemm_bf_k<<<g, dim3(256), 0, stream>>>(A, W, bias, C, M, N, K, epi);
  };
  auto addln = [&](const float* X, const float* R, const float* w, const float* b,
                   float* O, int rows) {
    addln_k<<<dim3((rows + 3) / 4), dim3(256), 0, stream>>>(X, R, w, b, O, rows);
  };
  auto addln2 = [&](const float* X, const unsigned short* Rbf, const float* w, const float* b,
                    float* O, unsigned short* Obf, int rows) {
    addln2_k<<<dim3((rows + 3) / 4), dim3(256), 0, stream>>>(X, Rbf, w, b, O, Obf, rows);
  };
  auto cvt = [&](const float* in, unsigned short* o, int n) {
    cvt_k<<<dim3(n / 1024), dim3(256), 0, stream>>>(in, o, n);
  };

  // ---- convert decoder weights to bf16 (once) ----
  cvt(d_sa_qkv_w, Wsaqkv, 786432);
  cvt(d_sa_out_w, Wsaout, 262144);
  cvt(d_ca_qkv_w, Wcaqkv, 786432);
  cvt(d_ca_out_w, Wcaout, 262144);
  cvt(d_ff1_w, Wff1, 1048576);
  cvt(d_ff2_w, Wff2, 1048576);

  // ================= encoder (fp32, gemm2) =================
  for (int i = 0; i < 4; ++i) {
    for (int g0 = 0; g0 < B_; g0 += grp_e) {
      int rows = grp_e * T_;
      const size_t off = (size_t)g0 * T_ * D_;
      const float* xin = (i == 0) ? te + off : ENC + off;
      gemm2(xin, e_qkv_w + (size_t)i * 196608, e_qkv_b + i * 768, P0e, rows, 768, 256, 0);
      attn_k<<<dim3(T_ / 64, NH_, grp_e), dim3(256), 0, stream>>>(
          P0e, 768, P0e + 256, 768, P0e + 512, 768, P1e, T_, T_, lens + g0);
      gemm2(P1e, e_out_w + (size_t)i * 65536, e_out_b + i * 256, P2e, rows, 256, 256, 0);
      addln(xin, P2e, e_ln1_w + i * 256, e_ln1_b + i * 256, ENC + off, rows);
      gemm2(ENC + off, e_ff1_w + (size_t)i * 262144, e_ff1_b + i * 1024, P0e, rows, 1024, 256, 1);
      gemm2(P0e, e_ff2_w + (size_t)i * 262144, e_ff2_b + i * 256, P2e, rows, 256, 1024, 0);
      addln(ENC + off, P2e, e_ln2_w + i * 256, e_ln2_b + i * 256, ENC + off, rows);
    }
  }
  cvt(ENC, ENCbf, 2097152);

  // ================= variance predictors (fp32) =================
  transp_k<<<dim3(8, 8, B_), dim3(32, 8), 0, stream>>>(ENC, ENCT);
  for (int j = 0; j < 3; ++j) {
    conv_k<<<dim3(4, 4, B_), dim3(256), 0, stream>>>(
        ENCT, c1w + (size_t)j * 196608, c1b + j * 256, H1, 1);
    addln(H1, nullptr, l1w + j * 256, l1b + j * 256, H1, B_ * T_);
    conv_k<<<dim3(4, 4, B_), dim3(256), 0, stream>>>(
        H1, c2w + (size_t)j * 196608, c2b + j * 256, H2, 1);
    addln(H2, nullptr, l2w + j * 256, l2b + j * 256, H2, B_ * T_);
    rowdot_k<<<dim3(B_ * T_ / 4), dim3(256), 0, stream>>>(
        H2, linw + j * 256, linb + j, DUR + (size_t)j * 8192,
        out + 2621440 + (size_t)j * 8192, B_ * T_);
  }

  // ================= length regulator =================
  maxlen_k<<<dim3(1), dim3(256), 0, stream>>>(DUR, MAXL);
  reg_k<<<dim3(B_), dim3(256), 0, stream>>>(DUR, lens, MAXL, TOK);
  gather_k<<<dim3(B_ * MAXBUF_), dim3(64), 0, stream>>>(ENC, TOK, Y);

  // ================= decoder (bf16 MFMA) =================
  for (int i = 0; i < 4; ++i) {
    for (int g0 = 0; g0 < B_; g0 += grp) {
      int rows = grp * MAXBUF_;
      float* Yg = Y + (size_t)g0 * MAXBUF_ * D_;
      if (i == 0 || grp != B_)    // Ybf stays current across layers when grp==B
        cvt(Yg, Ybf, rows * 256);
      // self-attention
      gemm_bf(Ybf, Wsaqkv + (size_t)i * 196608, d_sa_qkv_b + i * 768, UN, rows, 768, 256, 0);
      trv_k<<<dim3(MAXBUF_ / 64, NH_, grp), dim3(256), 0, stream>>>(UN + 512, 768, VTb, MAXBUF_);
      attn_bf_k<<<dim3(MAXBUF_ / 128, NH_, grp), dim3(256), 0, stream>>>(
          UN, 768, UN + 256, 768, VTb, AObf, MAXBUF_, MAXBUF_);
      gemm_bf(AObf, Wsaout + (size_t)i * 65536, d_sa_out_b + i * 256, ADDbf, rows, 256, 256, 0);
      addln2(Yg, ADDbf, d_ln1_w + i * 256, d_ln1_b + i * 256, Yg, Ybf, rows);
      // cross-attention
      gemm_bf(Ybf, Wcaqkv + (size_t)i * 196608, d_ca_qkv_b + i * 768, UN, rows, 256, 256, 0);
      gemm_bf(ENCbf + (size_t)g0 * 65536, Wcaqkv + (size_t)i * 196608 + 65536,
              d_ca_qkv_b + i * 768 + 256, UN + (size_t)grp * 262144, grp * T_, 512, 256, 0);
      trv_k<<<dim3(T_ / 64, NH_, grp), dim3(256), 0, stream>>>(
          UN + (size_t)grp * 262144 + 256, 512, VTb, T_);
      attn_bf_k<<<dim3(MAXBUF_ / 128, NH_, grp), dim3(256), 0, stream>>>(
          UN, 256, UN + (size_t)grp * 262144, 512, VTb, AObf, MAXBUF_, T_);
      gemm_bf(AObf, Wcaout + (size_t)i * 65536, d_ca_out_b + i * 256, ADDbf, rows, 256, 256, 0);
      addln2(Yg, ADDbf, d_ln2_w + i * 256, d_ln2_b + i * 256, Yg, Ybf, rows);
      // feed-forward
      gemm_bf(Ybf, Wff1 + (size_t)i * 262144, d_ff1_b + i * 1024, UN, rows, 1024, 256, 1);
      gemm_bf(UN, Wff2 + (size_t)i * 262144, d_ff2_b + i * 256, ADDbf, rows, 256, 1024, 0);
      addln2(Yg, ADDbf, d_ln3_w + i * 256, d_ln3_b + i * 256, Yg, Ybf, rows);
    }
  }

  // ================= mel head: gemm + transpose =================
  gemm(Y, melw, melb, MEL, B_ * MAXBUF_, NMEL_, 256, 0);
  meltr_k<<<dim3(16, 5, B_), dim3(256), 0, stream>>>(MEL, out);
}

// Round 9
// 3146.648 us; speedup vs baseline: 1.2527x; 1.0973x over previous
//
#include <hip/hip_runtime.h>
#include <hip/hip_bf16.h>
#include <cstdint>
#include <cstddef>

// ============================================================================
// FastSpeech2 forward on MI355X. Round 9: split-K for grid-starved GEMMs.
//  r8 counters: gemm2_k on N=256 shapes = 128 blocks on 256 CUs -> half the
//  GPU idle (Occupancy 5.8%, VALUBusy 18%). Fix: gemm2p_k with blockIdx.z
//  K-chunks (z=0 -> dest, z>0 -> partials in dead Y region) + rsum_k fixed-
//  order reduce (+bias). Deterministic (no atomics) so duration path is safe.
//  QKV S=2 (768 blk), proj S=4 (512), FF2 S=4 (512). FF1 already at the
//  ~70TF LDS ceiling at 2 blk/CU -> unchanged. Everything else = r8.
// ============================================================================

#define B_ 32
#define T_ 256
#define D_ 256
#define NH_ 4
#define FF_ 1024
#define MAXBUF_ 1024
#define NMEL_ 80

typedef __attribute__((ext_vector_type(8))) short short8;
typedef __attribute__((ext_vector_type(4))) float f32x4;

__device__ __forceinline__ unsigned short f2bf(float x) {
  unsigned int u = __float_as_uint(x);
  return (unsigned short)((u + 0x7fffu + ((u >> 16) & 1u)) >> 16);
}
__device__ __forceinline__ float bf2f(unsigned short h) {
  return __uint_as_float(((unsigned int)h) << 16);
}

#define GLD16(g, s)                                                         \
  __builtin_amdgcn_global_load_lds(                                         \
      (__attribute__((address_space(1))) void*)(g),                         \
      (__attribute__((address_space(3))) void*)(s), 16, 0, 0)

// ---------------------------------------------------------------------------
// fp32 GEMM, 64x64 tile (bounds-safe; used for mel N=80).
// ---------------------------------------------------------------------------
__global__ __launch_bounds__(256) void gemm_k(
    const float* __restrict__ A, const float* __restrict__ W,
    const float* __restrict__ bias, float* __restrict__ C,
    int M, int N, int K, int epi)
{
  __shared__ float As[16][64];
  __shared__ float Ws[16][64];
  const int tid = threadIdx.x;
  const int tx = tid & 15, ty = tid >> 4;
  const int bm = blockIdx.x * 64, bn = blockIdx.y * 64;
  const int lm = tid & 63, lk = tid >> 6;
  float acc[4][4] = {{0.f,0.f,0.f,0.f},{0.f,0.f,0.f,0.f},{0.f,0.f,0.f,0.f},{0.f,0.f,0.f,0.f}};
  const bool aok = (bm + lm) < M;
  const bool wok = (bn + lm) < N;
  const float* Ap = A + (size_t)(bm + lm) * K + lk * 4;
  const float* Wp = W + (size_t)(bn + lm) * K + lk * 4;
  for (int k0 = 0; k0 < K; k0 += 16) {
    float4 av = make_float4(0.f, 0.f, 0.f, 0.f);
    float4 wv = make_float4(0.f, 0.f, 0.f, 0.f);
    if (aok) av = *(const float4*)(Ap + k0);
    if (wok) wv = *(const float4*)(Wp + k0);
    As[lk*4+0][lm] = av.x; As[lk*4+1][lm] = av.y; As[lk*4+2][lm] = av.z; As[lk*4+3][lm] = av.w;
    Ws[lk*4+0][lm] = wv.x; Ws[lk*4+1][lm] = wv.y; Ws[lk*4+2][lm] = wv.z; Ws[lk*4+3][lm] = wv.w;
    __syncthreads();
#pragma unroll
    for (int kk = 0; kk < 16; ++kk) {
      float4 a4 = *(const float4*)&As[kk][ty * 4];
      float4 b4 = *(const float4*)&Ws[kk][tx * 4];
      float aa[4] = {a4.x, a4.y, a4.z, a4.w};
      float bb[4] = {b4.x, b4.y, b4.z, b4.w};
#pragma unroll
      for (int i = 0; i < 4; ++i)
#pragma unroll
        for (int j = 0; j < 4; ++j)
          acc[i][j] += aa[i] * bb[j];
    }
    __syncthreads();
  }
#pragma unroll
  for (int i = 0; i < 4; ++i) {
    int gm = bm + ty * 4 + i;
    if (gm >= M) continue;
#pragma unroll
    for (int j = 0; j < 4; ++j) {
      int gn = bn + tx * 4 + j;
      if (gn >= N) continue;
      float v = acc[i][j] + bias[gn];
      if (epi == 1) v = 0.5f * v * (1.0f + erff(v * 0.70710678118654752f));
      C[(size_t)gm * N + gn] = v;
    }
  }
}

// ---------------------------------------------------------------------------
// fp32 GEMM, 128x128 tile, 8x8 micro, f32x4 accumulators. Direct (bias+epi).
// ---------------------------------------------------------------------------
__global__ __launch_bounds__(256, 2) void gemm2_k(
    const float* __restrict__ A, const float* __restrict__ W,
    const float* __restrict__ bias, float* __restrict__ C,
    int M, int N, int K, int epi)
{
  __shared__ float As[16][128];
  __shared__ float Bs[16][128];
  const int tid = threadIdx.x;
  const int tx = tid & 15, ty = tid >> 4;
  const int bm = blockIdx.x * 128, bn = blockIdx.y * 128;
  const int r = tid & 127, ks = (tid >> 7) * 8;
  f32x4 acc[8][2];
#pragma unroll
  for (int i = 0; i < 8; ++i) {
    acc[i][0] = (f32x4){0.f, 0.f, 0.f, 0.f};
    acc[i][1] = (f32x4){0.f, 0.f, 0.f, 0.f};
  }
  const float* Ap = A + (size_t)(bm + r) * K + ks;
  const float* Wp = W + (size_t)(bn + r) * K + ks;
  for (int k0 = 0; k0 < K; k0 += 16) {
    float4 a0 = *(const float4*)(Ap + k0);
    float4 a1 = *(const float4*)(Ap + k0 + 4);
    float4 w0 = *(const float4*)(Wp + k0);
    float4 w1 = *(const float4*)(Wp + k0 + 4);
    __syncthreads();
    As[ks+0][r] = a0.x; As[ks+1][r] = a0.y; As[ks+2][r] = a0.z; As[ks+3][r] = a0.w;
    As[ks+4][r] = a1.x; As[ks+5][r] = a1.y; As[ks+6][r] = a1.z; As[ks+7][r] = a1.w;
    Bs[ks+0][r] = w0.x; Bs[ks+1][r] = w0.y; Bs[ks+2][r] = w0.z; Bs[ks+3][r] = w0.w;
    Bs[ks+4][r] = w1.x; Bs[ks+5][r] = w1.y; Bs[ks+6][r] = w1.z; Bs[ks+7][r] = w1.w;
    __syncthreads();
#pragma unroll
    for (int kk = 0; kk < 16; ++kk) {
      f32x4 bA = *(const f32x4*)&Bs[kk][tx * 4];
      f32x4 bB = *(const f32x4*)&Bs[kk][tx * 4 + 64];
      float4 aA = *(const float4*)&As[kk][ty * 4];
      float4 aB = *(const float4*)&As[kk][ty * 4 + 64];
      float av[8] = {aA.x, aA.y, aA.z, aA.w, aB.x, aB.y, aB.z, aB.w};
#pragma unroll
      for (int i = 0; i < 8; ++i) {
        acc[i][0] += bA * av[i];
        acc[i][1] += bB * av[i];
      }
    }
  }
#pragma unroll
  for (int i = 0; i < 8; ++i) {
    int gm = bm + (i >> 2) * 64 + ty * 4 + (i & 3);
#pragma unroll
    for (int half = 0; half < 2; ++half) {
      int gn = bn + half * 64 + tx * 4;
      float4 o;
      o.x = acc[i][half][0] + bias[gn + 0];
      o.y = acc[i][half][1] + bias[gn + 1];
      o.z = acc[i][half][2] + bias[gn + 2];
      o.w = acc[i][half][3] + bias[gn + 3];
      if (epi == 1) {
        o.x = 0.5f * o.x * (1.0f + erff(o.x * 0.70710678118654752f));
        o.y = 0.5f * o.y * (1.0f + erff(o.y * 0.70710678118654752f));
        o.z = 0.5f * o.z * (1.0f + erff(o.z * 0.70710678118654752f));
        o.w = 0.5f * o.w * (1.0f + erff(o.w * 0.70710678118654752f));
      }
      *(float4*)(C + (size_t)gm * N + gn) = o;
    }
  }
}

// ---------------------------------------------------------------------------
// Split-K partial GEMM: blockIdx.z selects K-chunk [z*kChunk, (z+1)*kChunk).
// z==0 writes Dst; z>0 writes Palt + (z-1)*M*N. No bias/epi (see rsum_k).
// ---------------------------------------------------------------------------
__global__ __launch_bounds__(256, 2) void gemm2p_k(
    const float* __restrict__ A, const float* __restrict__ W,
    float* __restrict__ Dst, float* __restrict__ Palt,
    int M, int N, int kChunk, int Ktot)
{
  __shared__ float As[16][128];
  __shared__ float Bs[16][128];
  const int tid = threadIdx.x;
  const int tx = tid & 15, ty = tid >> 4;
  const int bm = blockIdx.x * 128, bn = blockIdx.y * 128;
  const int z = blockIdx.z;
  const int r = tid & 127, ks = (tid >> 7) * 8;
  f32x4 acc[8][2];
#pragma unroll
  for (int i = 0; i < 8; ++i) {
    acc[i][0] = (f32x4){0.f, 0.f, 0.f, 0.f};
    acc[i][1] = (f32x4){0.f, 0.f, 0.f, 0.f};
  }
  const float* Ap = A + (size_t)(bm + r) * Ktot + z * kChunk + ks;
  const float* Wp = W + (size_t)(bn + r) * Ktot + z * kChunk + ks;
  for (int k0 = 0; k0 < kChunk; k0 += 16) {
    float4 a0 = *(const float4*)(Ap + k0);
    float4 a1 = *(const float4*)(Ap + k0 + 4);
    float4 w0 = *(const float4*)(Wp + k0);
    float4 w1 = *(const float4*)(Wp + k0 + 4);
    __syncthreads();
    As[ks+0][r] = a0.x; As[ks+1][r] = a0.y; As[ks+2][r] = a0.z; As[ks+3][r] = a0.w;
    As[ks+4][r] = a1.x; As[ks+5][r] = a1.y; As[ks+6][r] = a1.z; As[ks+7][r] = a1.w;
    Bs[ks+0][r] = w0.x; Bs[ks+1][r] = w0.y; Bs[ks+2][r] = w0.z; Bs[ks+3][r] = w0.w;
    Bs[ks+4][r] = w1.x; Bs[ks+5][r] = w1.y; Bs[ks+6][r] = w1.z; Bs[ks+7][r] = w1.w;
    __syncthreads();
#pragma unroll
    for (int kk = 0; kk < 16; ++kk) {
      f32x4 bA = *(const f32x4*)&Bs[kk][tx * 4];
      f32x4 bB = *(const f32x4*)&Bs[kk][tx * 4 + 64];
      float4 aA = *(const float4*)&As[kk][ty * 4];
      float4 aB = *(const float4*)&As[kk][ty * 4 + 64];
      float av[8] = {aA.x, aA.y, aA.z, aA.w, aB.x, aB.y, aB.z, aB.w};
#pragma unroll
      for (int i = 0; i < 8; ++i) {
        acc[i][0] += bA * av[i];
        acc[i][1] += bB * av[i];
      }
    }
  }
  float* Out = (z == 0) ? Dst : (Palt + (size_t)(z - 1) * ((size_t)M * N));
#pragma unroll
  for (int i = 0; i < 8; ++i) {
    int gm = bm + (i >> 2) * 64 + ty * 4 + (i & 3);
#pragma unroll
    for (int half = 0; half < 2; ++half) {
      int gn = bn + half * 64 + tx * 4;
      float4 o;
      o.x = acc[i][half][0]; o.y = acc[i][half][1];
      o.z = acc[i][half][2]; o.w = acc[i][half][3];
      *(float4*)(Out + (size_t)gm * N + gn) = o;
    }
  }
}

// C[i] = C[i] + sum_{s<Sm1} Palt[s*MN+i] + bias[i%N]   (fixed order; no epi)
__global__ __launch_bounds__(256) void rsum_k(
    float* __restrict__ C, const float* __restrict__ Palt,
    const float* __restrict__ bias, int Sm1, int N, size_t MN)
{
  size_t i = ((size_t)blockIdx.x * 256 + threadIdx.x) * 4;
  if (i >= MN) return;
  float4 a = *(const float4*)(C + i);
  for (int s = 0; s < Sm1; ++s) {
    float4 b = *(const float4*)(Palt + (size_t)s * MN + i);
    a.x += b.x; a.y += b.y; a.z += b.z; a.w += b.w;
  }
  int col = (int)(i % (size_t)N);
  a.x += bias[col + 0]; a.y += bias[col + 1];
  a.z += bias[col + 2]; a.w += bias[col + 3];
  *(float4*)(C + i) = a;
}

// ---------------------------------------------------------------------------
// fp32 flash attention (encoder only) — unchanged (duration path).
// ---------------------------------------------------------------------------
__global__ __launch_bounds__(256) void attn_k(
    const float* __restrict__ Qp, int qStride,
    const float* __restrict__ Kp, int kStride,
    const float* __restrict__ Vp, int vStride,
    float* __restrict__ Op, int Tq, int Tkv,
    const int* __restrict__ lengths)
{
  const int b = blockIdx.z, h = blockIdx.y, qt = blockIdx.x;
  const int tid = threadIdx.x;
  const int tx = tid & 15, ty = tid >> 4;
  const int lr = tid & 63, lq = tid >> 6;

  __shared__ float Qs[64][64];
  __shared__ float KT[64][64];
  __shared__ float Sm[64][65];

  {
    const float* q = Qp + (size_t)(b * Tq + qt * 64 + lr) * qStride + h * 64 + lq * 16;
    float4 v0 = ((const float4*)q)[0];
    float4 v1 = ((const float4*)q)[1];
    float4 v2 = ((const float4*)q)[2];
    float4 v3 = ((const float4*)q)[3];
    *(float4*)&Qs[lr][lq*16 + 0]  = v0;
    *(float4*)&Qs[lr][lq*16 + 4]  = v1;
    *(float4*)&Qs[lr][lq*16 + 8]  = v2;
    *(float4*)&Qs[lr][lq*16 + 12] = v3;
  }

  float m_reg[4], l_reg[4], o[4][4];
#pragma unroll
  for (int i = 0; i < 4; ++i) {
    m_reg[i] = -INFINITY; l_reg[i] = 0.f;
#pragma unroll
    for (int j = 0; j < 4; ++j) o[i][j] = 0.f;
  }

  const int len_b = lengths ? lengths[b] : 0x7fffffff;
  const int nkt = Tkv >> 6;

  for (int kt = 0; kt < nkt; ++kt) {
    __syncthreads();
    {
      const float* kp = Kp + (size_t)(b * Tkv + kt * 64 + lr) * kStride + h * 64 + lq * 16;
      float4 v[4];
      v[0] = ((const float4*)kp)[0]; v[1] = ((const float4*)kp)[1];
      v[2] = ((const float4*)kp)[2]; v[3] = ((const float4*)kp)[3];
#pragma unroll
      for (int u = 0; u < 4; ++u) {
        KT[lq*16 + u*4 + 0][lr] = v[u].x;
        KT[lq*16 + u*4 + 1][lr] = v[u].y;
        KT[lq*16 + u*4 + 2][lr] = v[u].z;
        KT[lq*16 + u*4 + 3][lr] = v[u].w;
      }
    }
    __syncthreads();

    float s[4][4] = {{0.f,0.f,0.f,0.f},{0.f,0.f,0.f,0.f},{0.f,0.f,0.f,0.f},{0.f,0.f,0.f,0.f}};
#pragma unroll
    for (int d4 = 0; d4 < 16; ++d4) {
      float4 qv[4], kv[4];
#pragma unroll
      for (int i = 0; i < 4; ++i) qv[i] = *(const float4*)&Qs[ty*4 + i][d4*4];
#pragma unroll
      for (int dd = 0; dd < 4; ++dd) kv[dd] = *(const float4*)&KT[d4*4 + dd][tx*4];
#pragma unroll
      for (int i = 0; i < 4; ++i) {
        s[i][0] += qv[i].x*kv[0].x + qv[i].y*kv[1].x + qv[i].z*kv[2].x + qv[i].w*kv[3].x;
        s[i][1] += qv[i].x*kv[0].y + qv[i].y*kv[1].y + qv[i].z*kv[2].y + qv[i].w*kv[3].y;
        s[i][2] += qv[i].x*kv[0].z + qv[i].y*kv[1].z + qv[i].z*kv[2].z + qv[i].w*kv[3].z;
        s[i][3] += qv[i].x*kv[0].w + qv[i].y*kv[1].w + qv[i].z*kv[2].w + qv[i].w*kv[3].w;
      }
    }

    float alpha[4];
#pragma unroll
    for (int i = 0; i < 4; ++i) {
      float pm = -INFINITY;
#pragma unroll
      for (int j = 0; j < 4; ++j) {
        int kg = kt * 64 + tx * 4 + j;
        float v = s[i][j] * 0.125f;
        if (kg >= len_b) v = -1e9f;
        s[i][j] = v;
        pm = fmaxf(pm, v);
      }
#pragma unroll
      for (int off = 1; off < 16; off <<= 1) pm = fmaxf(pm, __shfl_xor(pm, off));
      float mn = fmaxf(m_reg[i], pm);
      alpha[i] = expf(m_reg[i] - mn);
      float ls = 0.f;
#pragma unroll
      for (int j = 0; j < 4; ++j) {
        float p = expf(s[i][j] - mn);
        Sm[ty*4 + i][tx*4 + j] = p;
        ls += p;
      }
#pragma unroll
      for (int off = 1; off < 16; off <<= 1) ls += __shfl_xor(ls, off);
      l_reg[i] = l_reg[i] * alpha[i] + ls;
      m_reg[i] = mn;
    }
    __syncthreads();

    {
      const float* vp = Vp + (size_t)(b * Tkv + kt * 64 + lr) * vStride + h * 64 + lq * 16;
      float4 v0 = ((const float4*)vp)[0];
      float4 v1 = ((const float4*)vp)[1];
      float4 v2 = ((const float4*)vp)[2];
      float4 v3 = ((const float4*)vp)[3];
      *(float4*)&KT[lr][lq*16 + 0]  = v0;
      *(float4*)&KT[lr][lq*16 + 4]  = v1;
      *(float4*)&KT[lr][lq*16 + 8]  = v2;
      *(float4*)&KT[lr][lq*16 + 12] = v3;
    }
    __syncthreads();

#pragma unroll
    for (int i = 0; i < 4; ++i) {
      o[i][0] *= alpha[i]; o[i][1] *= alpha[i]; o[i][2] *= alpha[i]; o[i][3] *= alpha[i];
    }
#pragma unroll 8
    for (int c = 0; c < 64; ++c) {
      float4 vv = *(const float4*)&KT[c][tx * 4];
#pragma unroll
      for (int i = 0; i < 4; ++i) {
        float p = Sm[ty*4 + i][c];
        o[i][0] += p * vv.x; o[i][1] += p * vv.y; o[i][2] += p * vv.z; o[i][3] += p * vv.w;
      }
    }
  }

#pragma unroll
  for (int i = 0; i < 4; ++i) {
    float inv = 1.f / l_reg[i];
    float4 r;
    r.x = o[i][0] * inv; r.y = o[i][1] * inv; r.z = o[i][2] * inv; r.w = o[i][3] * inv;
    *(float4*)(Op + (size_t)(b * Tq + qt * 64 + ty * 4 + i) * 256 + h * 64 + tx * 4) = r;
  }
}

// ---------------------------------------------------------------------------
// bf16 MFMA GEMM — unchanged.
// ---------------------------------------------------------------------------
__global__ __launch_bounds__(256) void gemm_bf_k(
    const unsigned short* __restrict__ A, const unsigned short* __restrict__ W,
    const float* __restrict__ bias, unsigned short* __restrict__ C,
    int M, int N, int K, int epi)
{
  __shared__ __align__(16) short As[128 * 32];
  __shared__ __align__(16) short Bs[128 * 32];
  const int tid = threadIdx.x;
  const int lane = tid & 63, w = tid >> 6;
  const int g = lane >> 4, li = lane & 15;
  const int wr = (w >> 1) * 64, wc = (w & 1) * 64;
  const int bm = blockIdx.x * 128, bn = blockIdx.y * 128;

  f32x4 acc[4][4];
#pragma unroll
  for (int m = 0; m < 4; ++m)
#pragma unroll
    for (int n = 0; n < 4; ++n)
      acc[m][n] = (f32x4){0.f, 0.f, 0.f, 0.f};

  const int srow = tid >> 2, scol = (tid & 3) * 8;
  const unsigned short* Ag = A + (size_t)(bm + srow) * K + scol;
  const unsigned short* Wg = W + (size_t)(bn + srow) * K + scol;

  for (int k0 = 0; k0 < K; k0 += 32) {
    __syncthreads();
    GLD16(Ag + k0, &As[tid * 8]);
    GLD16(Ag + k0 + (size_t)64 * K, &As[tid * 8 + 2048]);
    GLD16(Wg + k0, &Bs[tid * 8]);
    GLD16(Wg + k0 + (size_t)64 * K, &Bs[tid * 8 + 2048]);
    __syncthreads();
    short8 af[4], bf[4];
#pragma unroll
    for (int m = 0; m < 4; ++m) af[m] = *(const short8*)&As[(wr + m * 16 + li) * 32 + g * 8];
#pragma unroll
    for (int n = 0; n < 4; ++n) bf[n] = *(const short8*)&Bs[(wc + n * 16 + li) * 32 + g * 8];
#pragma unroll
    for (int m = 0; m < 4; ++m)
#pragma unroll
      for (int n = 0; n < 4; ++n)
        acc[m][n] = __builtin_amdgcn_mfma_f32_16x16x32_bf16(af[m], bf[n], acc[m][n], 0, 0, 0);
  }

#pragma unroll
  for (int m = 0; m < 4; ++m) {
#pragma unroll
    for (int n = 0; n < 4; ++n) {
      int col = bn + wc + n * 16 + li;
      float bv = bias[col];
#pragma unroll
      for (int r = 0; r < 4; ++r) {
        int row = bm + wr + m * 16 + g * 4 + r;
        float v = acc[m][n][r] + bv;
        if (epi == 1) v = 0.5f * v * (1.0f + erff(v * 0.70710678118654752f));
        C[(size_t)row * N + col] = f2bf(v);
      }
    }
  }
}

// ---------------------------------------------------------------------------
// V transpose to global — unchanged from r8.
// ---------------------------------------------------------------------------
__global__ __launch_bounds__(256) void trv_k(
    const unsigned short* __restrict__ V, int vStride,
    unsigned short* __restrict__ VT, int Tkv)
{
  const int kt = blockIdx.x, h = blockIdx.y, b = blockIdx.z;
  __shared__ short t[64][65];
  const int tid = threadIdx.x;
  const int r0 = tid >> 3, seg = tid & 7;
#pragma unroll
  for (int i = 0; i < 2; ++i) {
    int r = r0 + i * 32;
    short8 v = *(const short8*)(V + (size_t)(b * Tkv + kt * 64 + r) * vStride + h * 64 + seg * 8);
    *(short8*)&t[r][seg * 8] = v;
  }
  __syncthreads();
#pragma unroll
  for (int i = 0; i < 2; ++i) {
    int d = r0 + i * 32;
    int k0 = seg * 8;
    short o[8];
#pragma unroll
    for (int j = 0; j < 8; ++j) o[j] = t[k0 + j][d];
    *(short8*)(VT + ((size_t)(b * NH_ + h) * 64 + d) * Tkv + kt * 64 + k0) = *(short8*)o;
  }
}

// ---------------------------------------------------------------------------
// bf16 MFMA flash attention — unchanged from r8.
// ---------------------------------------------------------------------------
__global__ __launch_bounds__(256, 2) void attn_bf_k(
    const unsigned short* __restrict__ Qp, int qStride,
    const unsigned short* __restrict__ Kp, int kStride,
    const unsigned short* __restrict__ VTg,
    unsigned short* __restrict__ Op, int Tq, int Tkv)
{
  int b, h, qt;
  {
    const int nqt = gridDim.x, nh = gridDim.y, nbh = gridDim.y * gridDim.z;
    if ((nbh & 7) == 0) {
      int linear = blockIdx.x + nqt * (blockIdx.y + gridDim.y * blockIdx.z);
      int xcd = linear & 7, idx = linear >> 3;
      int bh = xcd * (nbh >> 3) + idx / nqt;
      qt = idx - (idx / nqt) * nqt;
      h = bh % nh; b = bh / nh;
    } else { qt = blockIdx.x; h = blockIdx.y; b = blockIdx.z; }
  }
  const int tid = threadIdx.x;
  const int lane = tid & 63, w = tid >> 6;
  const int g = lane >> 4, li = lane & 15;

  __shared__ __align__(16) short Qs[128 * 64];
  __shared__ __align__(16) short Ks[64 * 64];
  __shared__ __align__(16) short VTs[64 * 64];
  __shared__ __align__(16) short Ps[128 * 64];

  {
    const int r0 = tid >> 3, seg = tid & 7;
#pragma unroll
    for (int i = 0; i < 4; ++i) {
      int r = r0 + i * 32;
      short8 v = *(const short8*)(Qp + (size_t)(b * Tq + qt * 128 + r) * qStride + h * 64 + seg * 8);
      *(short8*)&Qs[r * 64 + ((seg ^ (r & 7)) << 3)] = v;
    }
  }
  __syncthreads();

  short8 aq[2][2];
#pragma unroll
  for (int m = 0; m < 2; ++m)
#pragma unroll
    for (int ks = 0; ks < 2; ++ks) {
      int row = w * 32 + m * 16 + li;
      aq[m][ks] = *(const short8*)&Qs[row * 64 + (((ks * 4 + g) ^ (row & 7)) << 3)];
    }

  float m_reg[2][4], l_reg[2][4];
  f32x4 o[2][4];
#pragma unroll
  for (int m = 0; m < 2; ++m)
#pragma unroll
    for (int r = 0; r < 4; ++r) { m_reg[m][r] = -INFINITY; l_reg[m][r] = 0.f; }
#pragma unroll
  for (int m = 0; m < 2; ++m)
#pragma unroll
    for (int n = 0; n < 4; ++n) o[m][n] = (f32x4){0.f, 0.f, 0.f, 0.f};

  const int nkt = Tkv >> 6;
  const unsigned short* vt = VTg + (size_t)(b * NH_ + h) * 64 * Tkv;
  for (int kt = 0; kt < nkt; ++kt) {
    __syncthreads();
    {
      const int r0 = tid >> 3, seg = tid & 7;
#pragma unroll
      for (int i = 0; i < 2; ++i) {
        int r = r0 + i * 32;
        short8 kv = *(const short8*)(Kp + (size_t)(b * Tkv + kt * 64 + r) * kStride + h * 64 + seg * 8);
        *(short8*)&Ks[r * 64 + ((seg ^ (r & 7)) << 3)] = kv;
        short8 vv = *(const short8*)(vt + (size_t)r * Tkv + kt * 64 + seg * 8);
        *(short8*)&VTs[r * 64 + ((seg ^ (r & 7)) << 3)] = vv;
      }
    }
    __syncthreads();

    f32x4 s[2][4];
    __builtin_amdgcn_s_setprio(1);
#pragma unroll
    for (int m = 0; m < 2; ++m)
#pragma unroll
      for (int n = 0; n < 4; ++n) {
        f32x4 acc = (f32x4){0.f, 0.f, 0.f, 0.f};
#pragma unroll
        for (int ks = 0; ks < 2; ++ks) {
          int key = n * 16 + li;
          short8 bk = *(const short8*)&Ks[key * 64 + (((ks * 4 + g) ^ (key & 7)) << 3)];
          acc = __builtin_amdgcn_mfma_f32_16x16x32_bf16(aq[m][ks], bk, acc, 0, 0, 0);
        }
        s[m][n] = acc * 0.125f;
      }
    __builtin_amdgcn_s_setprio(0);

    float alpha[2][4];
#pragma unroll
    for (int m = 0; m < 2; ++m)
#pragma unroll
      for (int r = 0; r < 4; ++r) {
        float pm = fmaxf(fmaxf(s[m][0][r], s[m][1][r]), fmaxf(s[m][2][r], s[m][3][r]));
#pragma unroll
        for (int off = 1; off < 16; off <<= 1) pm = fmaxf(pm, __shfl_xor(pm, off));
        float mn = fmaxf(m_reg[m][r], pm);
        alpha[m][r] = __expf(m_reg[m][r] - mn);
        float ls = 0.f;
        int row = w * 32 + m * 16 + g * 4 + r;
#pragma unroll
        for (int n = 0; n < 4; ++n) {
          float p = __expf(s[m][n][r] - mn);
          ls += p;
          int col = n * 16 + li;
          Ps[row * 64 + (col ^ ((row & 7) << 3))] = (short)f2bf(p);
        }
#pragma unroll
        for (int off = 1; off < 16; off <<= 1) ls += __shfl_xor(ls, off);
        l_reg[m][r] = l_reg[m][r] * alpha[m][r] + ls;
        m_reg[m][r] = mn;
      }

#pragma unroll
    for (int m = 0; m < 2; ++m) {
      f32x4 al = (f32x4){alpha[m][0], alpha[m][1], alpha[m][2], alpha[m][3]};
#pragma unroll
      for (int n = 0; n < 4; ++n) o[m][n] *= al;
    }
    short8 ap[2][2];
#pragma unroll
    for (int m = 0; m < 2; ++m)
#pragma unroll
      for (int ks = 0; ks < 2; ++ks) {
        int row = w * 32 + m * 16 + li;
        ap[m][ks] = *(const short8*)&Ps[row * 64 + (((ks * 4 + g) ^ (row & 7)) << 3)];
      }
    __builtin_amdgcn_s_setprio(1);
#pragma unroll
    for (int m = 0; m < 2; ++m)
#pragma unroll
      for (int n = 0; n < 4; ++n)
#pragma unroll
        for (int ks = 0; ks < 2; ++ks) {
          int d = n * 16 + li;
          short8 bv = *(const short8*)&VTs[d * 64 + (((ks * 4 + g) ^ (d & 7)) << 3)];
          o[m][n] = __builtin_amdgcn_mfma_f32_16x16x32_bf16(ap[m][ks], bv, o[m][n], 0, 0, 0);
        }
    __builtin_amdgcn_s_setprio(0);
  }

#pragma unroll
  for (int m = 0; m < 2; ++m)
#pragma unroll
    for (int n = 0; n < 4; ++n)
#pragma unroll
      for (int r = 0; r < 4; ++r) {
        float v = o[m][n][r] / l_reg[m][r];
        Op[(size_t)(b * Tq + qt * 128 + w * 32 + m * 16 + g * 4 + r) * 256 + h * 64 + n * 16 + li] = f2bf(v);
      }
}

// LayerNorm f32 — unchanged.
__global__ __launch_bounds__(256) void addln_k(
    const float* __restrict__ X, const float* __restrict__ R,
    const float* __restrict__ w, const float* __restrict__ bias,
    float* __restrict__ Out, int rows)
{
  int tid = threadIdx.x, wv = tid >> 6, ln = tid & 63;
  int row = blockIdx.x * 4 + wv;
  if (row >= rows) return;
  const float* xp = X + (size_t)row * 256;
  float v[4];
#pragma unroll
  for (int u = 0; u < 4; ++u) v[u] = xp[u * 64 + ln];
  if (R) {
    const float* rp = R + (size_t)row * 256;
#pragma unroll
    for (int u = 0; u < 4; ++u) v[u] += rp[u * 64 + ln];
  }
  float s = v[0] + v[1] + v[2] + v[3];
#pragma unroll
  for (int off = 1; off < 64; off <<= 1) s += __shfl_xor(s, off);
  float mean = s * (1.f / 256.f);
  float c[4], sq = 0.f;
#pragma unroll
  for (int u = 0; u < 4; ++u) { c[u] = v[u] - mean; sq += c[u] * c[u]; }
#pragma unroll
  for (int off = 1; off < 64; off <<= 1) sq += __shfl_xor(sq, off);
  float rs = 1.f / sqrtf(sq * (1.f / 256.f) + 1e-5f);
  float* op = Out + (size_t)row * 256;
#pragma unroll
  for (int u = 0; u < 4; ++u)
    op[u * 64 + ln] = c[u] * rs * w[u * 64 + ln] + bias[u * 64 + ln];
}

// LayerNorm + bf16 residual — unchanged.
__global__ __launch_bounds__(256) void addln2_k(
    const float* __restrict__ X, const unsigned short* __restrict__ Rbf,
    const float* __restrict__ w, const float* __restrict__ bias,
    float* __restrict__ Out, unsigned short* __restrict__ OutBf, int rows)
{
  int tid = threadIdx.x, wv = tid >> 6, ln = tid & 63;
  int row = blockIdx.x * 4 + wv;
  if (row >= rows) return;
  const float* xp = X + (size_t)row * 256;
  const unsigned short* rp = Rbf + (size_t)row * 256;
  float v[4];
#pragma unroll
  for (int u = 0; u < 4; ++u) v[u] = xp[u * 64 + ln] + bf2f(rp[u * 64 + ln]);
  float s = v[0] + v[1] + v[2] + v[3];
#pragma unroll
  for (int off = 1; off < 64; off <<= 1) s += __shfl_xor(s, off);
  float mean = s * (1.f / 256.f);
  float c[4], sq = 0.f;
#pragma unroll
  for (int u = 0; u < 4; ++u) { c[u] = v[u] - mean; sq += c[u] * c[u]; }
#pragma unroll
  for (int off = 1; off < 64; off <<= 1) sq += __shfl_xor(sq, off);
  float rs = 1.f / sqrtf(sq * (1.f / 256.f) + 1e-5f);
  float* op = Out + (size_t)row * 256;
  unsigned short* ob = OutBf + (size_t)row * 256;
#pragma unroll
  for (int u = 0; u < 4; ++u) {
    float y = c[u] * rs * w[u * 64 + ln] + bias[u * 64 + ln];
    op[u * 64 + ln] = y;
    ob[u * 64 + ln] = f2bf(y);
  }
}

__global__ void cvt_k(const float* __restrict__ in, unsigned short* __restrict__ out, int n)
{
  int i = (blockIdx.x * 256 + threadIdx.x) * 4;
  if (i >= n) return;
  float4 v = *(const float4*)(in + i);
  unsigned short o[4] = {f2bf(v.x), f2bf(v.y), f2bf(v.z), f2bf(v.w)};
  *(ushort4*)(out + i) = *(ushort4*)o;
}

// Conv1d k=3 pad=1 — unchanged.
__global__ __launch_bounds__(256) void conv_k(
    const float* __restrict__ X, const float* __restrict__ Wt,
    const float* __restrict__ bias, float* __restrict__ Yo, int relu)
{
  const int b = blockIdx.z;
  const int o0 = blockIdx.y * 64, t0 = blockIdx.x * 64;
  const int tid = threadIdx.x, tx = tid & 15, ty = tid >> 4;
  __shared__ float xs[16][66];
  __shared__ float ws_s[64][48];
  float acc[4][4] = {{0.f,0.f,0.f,0.f},{0.f,0.f,0.f,0.f},{0.f,0.f,0.f,0.f},{0.f,0.f,0.f,0.f}};
  for (int i0 = 0; i0 < 256; i0 += 16) {
    for (int idx = tid; idx < 16 * 66; idx += 256) {
      int ic = idx / 66, tt = idx - ic * 66;
      int t = t0 + tt - 1;
      xs[ic][tt] = (t >= 0 && t < 256) ? X[((size_t)b * 256 + (i0 + ic)) * 256 + t] : 0.f;
    }
    for (int f4 = tid; f4 < 768; f4 += 256) {
      int oo = f4 / 12, seg = f4 - oo * 12;
      float4 v = *(const float4*)(Wt + (size_t)(o0 + oo) * 768 + i0 * 3 + seg * 4);
      *(float4*)&ws_s[oo][seg * 4] = v;
    }
    __syncthreads();
#pragma unroll
    for (int ic = 0; ic < 16; ++ic) {
      float xr[6];
#pragma unroll
      for (int u = 0; u < 6; ++u) xr[u] = xs[ic][tx * 4 + u];
#pragma unroll
      for (int i = 0; i < 4; ++i) {
        const float* wr = &ws_s[ty * 4 + i][ic * 3];
        float w0 = wr[0], w1 = wr[1], w2 = wr[2];
#pragma unroll
        for (int j = 0; j < 4; ++j)
          acc[i][j] += w0 * xr[j] + w1 * xr[j + 1] + w2 * xr[j + 2];
      }
    }
    __syncthreads();
  }
#pragma unroll
  for (int i = 0; i < 4; ++i) {
    int oo = o0 + ty * 4 + i;
    float bv = bias[oo];
#pragma unroll
    for (int j = 0; j < 4; ++j) {
      float v = acc[i][j] + bv;
      if (relu) v = fmaxf(v, 0.f);
      Yo[((size_t)b * 256 + oo) * 256 + t0 + tx * 4 + j] = v;
    }
  }
}

__global__ void transp_k(const float* __restrict__ In, float* __restrict__ Out)
{
  int b = blockIdx.z, t0 = blockIdx.x * 32, d0 = blockIdx.y * 32;
  __shared__ float tile[32][33];
  int tx = threadIdx.x, ty = threadIdx.y;
#pragma unroll
  for (int q = 0; q < 4; ++q)
    tile[ty + q * 8][tx] = In[((size_t)b * 256 + t0 + ty + q * 8) * 256 + d0 + tx];
  __syncthreads();
#pragma unroll
  for (int q = 0; q < 4; ++q)
    Out[((size_t)b * 256 + d0 + ty + q * 8) * 256 + t0 + tx] = tile[tx][ty + q * 8];
}

__global__ __launch_bounds__(256) void rowdot_k(
    const float* __restrict__ H, const float* __restrict__ lw,
    const float* __restrict__ lb, float* __restrict__ of32,
    float* __restrict__ oout, int rows)
{
  int tid = threadIdx.x, wv = tid >> 6, ln = tid & 63;
  int row = blockIdx.x * 4 + wv;
  if (row >= rows) return;
  const float* hp = H + (size_t)row * 256;
  float s = 0.f;
#pragma unroll
  for (int u = 0; u < 4; ++u) s += hp[u * 64 + ln] * lw[u * 64 + ln];
#pragma unroll
  for (int off = 1; off < 64; off <<= 1) s += __shfl_xor(s, off);
  if (ln == 0) {
    float v = s + lb[0];
    of32[row] = v;
    oout[row] = v;
  }
}

__global__ void maxlen_k(const float* __restrict__ dur, int* __restrict__ ml)
{
  __shared__ float rnds[32];
  int tid = threadIdx.x, wv = tid >> 6, ln = tid & 63;
  for (int b = wv; b < 32; b += 4) {
    const float* dp = dur + (size_t)b * 256;
    float s = dp[ln] + dp[64 + ln] + dp[128 + ln] + dp[192 + ln];
#pragma unroll
    for (int off = 1; off < 64; off <<= 1) s += __shfl_xor(s, off);
    if (ln == 0) rnds[b] = rintf(s);
  }
  __syncthreads();
  if (tid == 0) {
    float m = rnds[0];
    for (int b = 1; b < 32; ++b) m = fmaxf(m, rnds[b]);
    int v = (int)m;
    v = v < 0 ? 0 : (v > MAXBUF_ ? MAXBUF_ : v);
    *ml = v;
  }
}

__global__ void reg_k(const float* __restrict__ dur, const int* __restrict__ lens,
                      const int* __restrict__ ml, int* __restrict__ tok)
{
  int b = blockIdx.x;
  __shared__ float sdur[256];
  __shared__ int ends[256];
  int tid = threadIdx.x;
  sdur[tid] = dur[(size_t)b * 256 + tid];
  __syncthreads();
  if (tid == 0) {
    int maxlen = *ml, len = lens[b], pos = 0;
    for (int t = 0; t < 256; ++t) {
      int d = (int)rintf(sdur[t]);
      bool ok = (t < len) && (d > 0) && (pos + d <= maxlen);
      if (ok) pos += d;
      ends[t] = pos;
    }
  }
  __syncthreads();
  int total = ends[255];
  for (int f = tid; f < MAXBUF_; f += 256) {
    int lo = 0, hi = 256;
    while (lo < hi) { int mid = (lo + hi) >> 1; if (ends[mid] <= f) lo = mid + 1; else hi = mid; }
    int tc = lo > 255 ? 255 : lo;
    tok[(size_t)b * MAXBUF_ + f] = (f < total) ? tc : -1;
  }
}

__global__ void gather_k(const float* __restrict__ enc, const int* __restrict__ tok,
                         float* __restrict__ Y)
{
  int rf = blockIdx.x;
  int b = rf >> 10;
  int t = tok[rf];
  float4* dst = (float4*)(Y + (size_t)rf * 256);
  int ln = threadIdx.x;
  if (t >= 0) {
    const float4* src = (const float4*)(enc + ((size_t)b * 256 + t) * 256);
    dst[ln] = src[ln];
  } else {
    dst[ln] = make_float4(0.f, 0.f, 0.f, 0.f);
  }
}

// MEL (B*1024, 80) -> out (B, 80, 1024) via LDS tile transpose
__global__ __launch_bounds__(256) void meltr_k(
    const float* __restrict__ MEL, float* __restrict__ out)
{
  int b = blockIdx.z, m0 = blockIdx.y * 16, f0 = blockIdx.x * 64;
  __shared__ float t[16][65];
  int tid = threadIdx.x;
  {
    int f_i = tid >> 4, m_i = tid & 15;
#pragma unroll
    for (int q = 0; q < 4; ++q)
      t[m_i][f_i + q * 16] = MEL[((size_t)b * 1024 + f0 + f_i + q * 16) * 80 + m0 + m_i];
  }
  __syncthreads();
  {
    int f = tid & 63, my = tid >> 6;
#pragma unroll
    for (int q = 0; q < 4; ++q) {
      int m = my * 4 + q;
      out[((size_t)b * NMEL_ + m0 + m) * MAXBUF_ + f0 + f] = t[m][f];
    }
  }
}

// ============================================================================
extern "C" void kernel_launch(void* const* d_in, const int* in_sizes, int n_in,
                              void* d_out, int out_size, void* d_ws, size_t ws_size,
                              hipStream_t stream)
{
  (void)in_sizes; (void)n_in; (void)out_size;

  const float* te   = (const float*)d_in[0];
  const int*   lens = (const int*)d_in[1];
  const float* e_qkv_w = (const float*)d_in[2];
  const float* e_qkv_b = (const float*)d_in[3];
  const float* e_out_w = (const float*)d_in[4];
  const float* e_out_b = (const float*)d_in[5];
  const float* e_ln1_w = (const float*)d_in[6];
  const float* e_ln1_b = (const float*)d_in[7];
  const float* e_ff1_w = (const float*)d_in[8];
  const float* e_ff1_b = (const float*)d_in[9];
  const float* e_ff2_w = (const float*)d_in[10];
  const float* e_ff2_b = (const float*)d_in[11];
  const float* e_ln2_w = (const float*)d_in[12];
  const float* e_ln2_b = (const float*)d_in[13];
  const float* c1w = (const float*)d_in[14];
  const float* c1b = (const float*)d_in[15];
  const float* l1w = (const float*)d_in[16];
  const float* l1b = (const float*)d_in[17];
  const float* c2w = (const float*)d_in[18];
  const float* c2b = (const float*)d_in[19];
  const float* l2w = (const float*)d_in[20];
  const float* l2b = (const float*)d_in[21];
  const float* linw = (const float*)d_in[22];
  const float* linb = (const float*)d_in[23];
  const float* d_sa_qkv_w = (const float*)d_in[24];
  const float* d_sa_qkv_b = (const float*)d_in[25];
  const float* d_sa_out_w = (const float*)d_in[26];
  const float* d_sa_out_b = (const float*)d_in[27];
  const float* d_ca_qkv_w = (const float*)d_in[28];
  const float* d_ca_qkv_b = (const float*)d_in[29];
  const float* d_ca_out_w = (const float*)d_in[30];
  const float* d_ca_out_b = (const float*)d_in[31];
  const float* d_ln1_w = (const float*)d_in[32];
  const float* d_ln1_b = (const float*)d_in[33];
  const float* d_ln2_w = (const float*)d_in[34];
  const float* d_ln2_b = (const float*)d_in[35];
  const float* d_ln3_w = (const float*)d_in[36];
  const float* d_ln3_b = (const float*)d_in[37];
  const float* d_ff1_w = (const float*)d_in[38];
  const float* d_ff1_b = (const float*)d_in[39];
  const float* d_ff2_w = (const float*)d_in[40];
  const float* d_ff2_b = (const float*)d_in[41];
  const float* melw = (const float*)d_in[42];
  const float* melb = (const float*)d_in[43];
  float* out = (float*)d_out;   // f32: mel | duration | pitch | energy

  // ---- arena ----
  char* p = (char*)d_ws;
  float* Y   = (float*)p;            p += 8388608ull * 4;    // (B,1024,256) f32
  float* ENC = (float*)p;            p += 2097152ull * 4;    // (B,256,256) f32
  unsigned short* ENCbf = (unsigned short*)p; p += 2097152ull * 2;
  unsigned short* Wsaqkv = (unsigned short*)p; p += 786432ull * 2;
  unsigned short* Wsaout = (unsigned short*)p; p += 262144ull * 2;
  unsigned short* Wcaqkv = (unsigned short*)p; p += 786432ull * 2;
  unsigned short* Wcaout = (unsigned short*)p; p += 262144ull * 2;
  unsigned short* Wff1   = (unsigned short*)p; p += 1048576ull * 2;
  unsigned short* Wff2   = (unsigned short*)p; p += 1048576ull * 2;
  float* DUR = (float*)p;            p += 24576ull * 4;
  int* TOK   = (int*)p;              p += 32768ull * 4;
  int* MAXL  = (int*)p;              p += 4096;
  size_t fixed_b = (size_t)(p - (char*)d_ws);

  int grp = 1;
  {
    const int cand[6] = {32, 16, 8, 4, 2, 1};
    for (int c = 0; c < 6; ++c) {
      if (fixed_b + (size_t)cand[c] * 1835008ull * 2 <= ws_size) { grp = cand[c]; break; }
    }
  }
  unsigned short* REG = (unsigned short*)p;            // grouped region (bf16)
  unsigned short* Ybf   = REG;
  unsigned short* ADDbf = REG + (size_t)grp * 262144;
  unsigned short* AObf  = REG + (size_t)grp * 524288;
  unsigned short* UN    = REG + (size_t)grp * 786432;
  unsigned short* VTb   = REG + (size_t)grp * 1572864; // grp*262144 (V^T)
  int grp_e = grp * 2 > 32 ? 32 : grp * 2;
  float* P0e = (float*)REG;
  float* P1e = P0e + (size_t)grp_e * 262144;
  float* P2e = P1e + (size_t)grp_e * 65536;
  float* ENCT = Y;            // vpred scratch in dead Y region
  float* H1   = Y + 2097152;
  float* H2   = Y + 4194304;
  float* MEL  = ENC;

  auto gemm = [&](const float* A, const float* W, const float* bias, float* C,
                  int M, int N, int K, int epi) {
    dim3 g((M + 63) / 64, (N + 63) / 64);
    gemm_k<<<g, dim3(256), 0, stream>>>(A, W, bias, C, M, N, K, epi);
  };
  auto gemm2 = [&](const float* A, const float* W, const float* bias, float* C,
                   int M, int N, int K, int epi) {
    dim3 g(M / 128, N / 128);
    gemm2_k<<<g, dim3(256), 0, stream>>>(A, W, bias, C, M, N, K, epi);
  };
  // split-K: z=0 -> Dst, z>0 -> Y partials; then rsum adds partials + bias
  auto gemm2s = [&](const float* A, const float* W, const float* bias, float* C,
                    int M, int N, int K, int S) {
    int kChunk = K / S;
    gemm2p_k<<<dim3(M / 128, N / 128, S), dim3(256), 0, stream>>>(
        A, W, C, Y, M, N, kChunk, K);
    size_t MN = (size_t)M * N;
    rsum_k<<<dim3((unsigned)(MN / 1024)), dim3(256), 0, stream>>>(
        C, Y, bias, S - 1, N, MN);
  };
  auto gemm_bf = [&](const unsigned short* A, const unsigned short* W, const float* bias,
                     unsigned short* C, int M, int N, int K, int epi) {
    dim3 g(M / 128, N / 128);
    gemm_bf_k<<<g, dim3(256), 0, stream>>>(A, W, bias, C, M, N, K, epi);
  };
  auto addln = [&](const float* X, const float* R, const float* w, const float* b,
                   float* O, int rows) {
    addln_k<<<dim3((rows + 3) / 4), dim3(256), 0, stream>>>(X, R, w, b, O, rows);
  };
  auto addln2 = [&](const float* X, const unsigned short* Rbf, const float* w, const float* b,
                    float* O, unsigned short* Obf, int rows) {
    addln2_k<<<dim3((rows + 3) / 4), dim3(256), 0, stream>>>(X, Rbf, w, b, O, Obf, rows);
  };
  auto cvt = [&](const float* in, unsigned short* o, int n) {
    cvt_k<<<dim3(n / 1024), dim3(256), 0, stream>>>(in, o, n);
  };

  // ---- convert decoder weights to bf16 (once) ----
  cvt(d_sa_qkv_w, Wsaqkv, 786432);
  cvt(d_sa_out_w, Wsaout, 262144);
  cvt(d_ca_qkv_w, Wcaqkv, 786432);
  cvt(d_ca_out_w, Wcaout, 262144);
  cvt(d_ff1_w, Wff1, 1048576);
  cvt(d_ff2_w, Wff2, 1048576);

  // ================= encoder (fp32; split-K on grid-starved GEMMs) ==========
  for (int i = 0; i < 4; ++i) {
    for (int g0 = 0; g0 < B_; g0 += grp_e) {
      int rows = grp_e * T_;
      const size_t off = (size_t)g0 * T_ * D_;
      const float* xin = (i == 0) ? te + off : ENC + off;
      // QKV: S=2 -> 2x blocks
      gemm2s(xin, e_qkv_w + (size_t)i * 196608, e_qkv_b + i * 768, P0e, rows, 768, 256, 2);
      attn_k<<<dim3(T_ / 64, NH_, grp_e), dim3(256), 0, stream>>>(
          P0e, 768, P0e + 256, 768, P0e + 512, 768, P1e, T_, T_, lens + g0);
      // proj: S=4 (N=256 starved) -> 4x blocks
      gemm2s(P1e, e_out_w + (size_t)i * 65536, e_out_b + i * 256, P2e, rows, 256, 256, 4);
      addln(xin, P2e, e_ln1_w + i * 256, e_ln1_b + i * 256, ENC + off, rows);
      // FF1: already 2 blocks/CU, at LDS ceiling -> direct
      gemm2(ENC + off, e_ff1_w + (size_t)i * 262144, e_ff1_b + i * 1024, P0e, rows, 1024, 256, 1);
      // FF2: S=4 (N=256 starved) -> 4x blocks
      gemm2s(P0e, e_ff2_w + (size_t)i * 262144, e_ff2_b + i * 256, P2e, rows, 256, 1024, 4);
      addln(ENC + off, P2e, e_ln2_w + i * 256, e_ln2_b + i * 256, ENC + off, rows);
    }
  }
  cvt(ENC, ENCbf, 2097152);

  // ================= variance predictors (fp32) =================
  transp_k<<<dim3(8, 8, B_), dim3(32, 8), 0, stream>>>(ENC, ENCT);
  for (int j = 0; j < 3; ++j) {
    conv_k<<<dim3(4, 4, B_), dim3(256), 0, stream>>>(
        ENCT, c1w + (size_t)j * 196608, c1b + j * 256, H1, 1);
    addln(H1, nullptr, l1w + j * 256, l1b + j * 256, H1, B_ * T_);
    conv_k<<<dim3(4, 4, B_), dim3(256), 0, stream>>>(
        H1, c2w + (size_t)j * 196608, c2b + j * 256, H2, 1);
    addln(H2, nullptr, l2w + j * 256, l2b + j * 256, H2, B_ * T_);
    rowdot_k<<<dim3(B_ * T_ / 4), dim3(256), 0, stream>>>(
        H2, linw + j * 256, linb + j, DUR + (size_t)j * 8192,
        out + 2621440 + (size_t)j * 8192, B_ * T_);
  }

  // ================= length regulator =================
  maxlen_k<<<dim3(1), dim3(256), 0, stream>>>(DUR, MAXL);
  reg_k<<<dim3(B_), dim3(256), 0, stream>>>(DUR, lens, MAXL, TOK);
  gather_k<<<dim3(B_ * MAXBUF_), dim3(64), 0, stream>>>(ENC, TOK, Y);

  // ================= decoder (bf16 MFMA) =================
  for (int i = 0; i < 4; ++i) {
    for (int g0 = 0; g0 < B_; g0 += grp) {
      int rows = grp * MAXBUF_;
      float* Yg = Y + (size_t)g0 * MAXBUF_ * D_;
      if (i == 0 || grp != B_)
        cvt(Yg, Ybf, rows * 256);
      // self-attention
      gemm_bf(Ybf, Wsaqkv + (size_t)i * 196608, d_sa_qkv_b + i * 768, UN, rows, 768, 256, 0);
      trv_k<<<dim3(MAXBUF_ / 64, NH_, grp), dim3(256), 0, stream>>>(UN + 512, 768, VTb, MAXBUF_);
      attn_bf_k<<<dim3(MAXBUF_ / 128, NH_, grp), dim3(256), 0, stream>>>(
          UN, 768, UN + 256, 768, VTb, AObf, MAXBUF_, MAXBUF_);
      gemm_bf(AObf, Wsaout + (size_t)i * 65536, d_sa_out_b + i * 256, ADDbf, rows, 256, 256, 0);
      addln2(Yg, ADDbf, d_ln1_w + i * 256, d_ln1_b + i * 256, Yg, Ybf, rows);
      // cross-attention
      gemm_bf(Ybf, Wcaqkv + (size_t)i * 196608, d_ca_qkv_b + i * 768, UN, rows, 256, 256, 0);
      gemm_bf(ENCbf + (size_t)g0 * 65536, Wcaqkv + (size_t)i * 196608 + 65536,
              d_ca_qkv_b + i * 768 + 256, UN + (size_t)grp * 262144, grp * T_, 512, 256, 0);
      trv_k<<<dim3(T_ / 64, NH_, grp), dim3(256), 0, stream>>>(
          UN + (size_t)grp * 262144 + 256, 512, VTb, T_);
      attn_bf_k<<<dim3(MAXBUF_ / 128, NH_, grp), dim3(256), 0, stream>>>(
          UN, 256, UN + (size_t)grp * 262144, 512, VTb, AObf, MAXBUF_, T_);
      gemm_bf(AObf, Wcaout + (size_t)i * 65536, d_ca_out_b + i * 256, ADDbf, rows, 256, 256, 0);
      addln2(Yg, ADDbf, d_ln2_w + i * 256, d_ln2_b + i * 256, Yg, Ybf, rows);
      // feed-forward
      gemm_bf(Ybf, Wff1 + (size_t)i * 262144, d_ff1_b + i * 1024, UN, rows, 1024, 256, 1);
      gemm_bf(UN, Wff2 + (size_t)i * 262144, d_ff2_b + i * 256, ADDbf, rows, 256, 1024, 0);
      addln2(Yg, ADDbf, d_ln3_w + i * 256, d_ln3_b + i * 256, Yg, Ybf, rows);
    }
  }

  // ================= mel head: gemm + transpose =================
  gemm(Y, melw, melb, MEL, B_ * MAXBUF_, NMEL_, 256, 0);
  meltr_k<<<dim3(16, 5, B_), dim3(256), 0, stream>>>(MEL, out);
}